// Round 1
// baseline (9196.265 us; speedup 1.0000x reference)
//
#include <hip/hip_runtime.h>
#include <cmath>

constexpr int B = 128, L = 100, CIN = 55, COUT = 55;
constexpr int D = 512, H = 8, DFF = 512, MODES = 32, E = 64;
constexpr int NK = 2;
constexpr int M_ROWS = B * L; // 12800
constexpr size_t BLD  = (size_t)B * L * D;        // 6,553,600
constexpr size_t BHEM = (size_t)B * H * E * MODES; // 2,097,152
constexpr size_t BHLL = (size_t)B * H * L * L;     // 10,240,000
constexpr float INV_SQRT_2PI = 0.3989422804014327f;

static inline int cdiv(int a, int b) { return (a + b - 1) / b; }

// ---------------- constants: positional emb + DFT twiddles ----------------
__global__ void init_consts(float* __restrict__ pe, float* __restrict__ twc, float* __restrict__ tws)
{
    int idx = blockIdx.x * 256 + threadIdx.x;
    if (idx < L * D) {
        int l = idx / D, d = idx % D;
        int i2 = d & ~1;
        float div = expf((float)i2 * (-logf(10000.f) / (float)D));
        float ang = (float)l * div;
        pe[idx] = (d & 1) ? cosf(ang) : sinf(ang);
    }
    if (idx < L * MODES) {
        int t = idx / MODES, m = idx % MODES;
        float th = 2.f * 3.14159265358979323846f * (float)m * (float)t / (float)L;
        twc[idx] = cosf(th);
        tws[idx] = sinf(th);
    }
}

__global__ void xmean_kernel(const float* __restrict__ x, float* __restrict__ xm)
{
    int idx = blockIdx.x * 256 + threadIdx.x;
    if (idx >= B * CIN) return;
    int b = idx / CIN, c = idx % CIN;
    float s = 0.f;
    for (int l = 0; l < L; ++l) s += x[((size_t)b * L + l) * CIN + c];
    xm[idx] = s * (1.f / (float)L);
}

// out[b,l,o] = sum_c sum_j in_eff[b,(l+j-1)%L,c]*W[o,c,j] (+pe[l,o]) (+xmean_out[b,o])
// in_eff = in - xmean_in (broadcast over l) if xmean_in != null
__global__ void circ_conv(const float* __restrict__ in, const float* __restrict__ W,
                          const float* __restrict__ pe, const float* __restrict__ xmean_in,
                          const float* __restrict__ xmean_out, float* __restrict__ out,
                          int Cin, int Cout)
{
    int idx = blockIdx.x * 256 + threadIdx.x;
    if (idx >= B * L * Cout) return;
    int o = idx % Cout; int l = (idx / Cout) % L; int b = idx / (Cout * L);
    int lm = (l + L - 1) % L, lp = (l + 1) % L;
    const float* r0 = in + ((size_t)b * L + lm) * Cin;
    const float* r1 = in + ((size_t)b * L + l ) * Cin;
    const float* r2 = in + ((size_t)b * L + lp) * Cin;
    const float* wp = W + (size_t)o * Cin * 3;
    float acc = 0.f;
    if (xmean_in) {
        const float* xm = xmean_in + (size_t)b * Cin;
        for (int c = 0; c < Cin; ++c) {
            float m = xm[c];
            acc += (r0[c] - m) * wp[c * 3] + (r1[c] - m) * wp[c * 3 + 1] + (r2[c] - m) * wp[c * 3 + 2];
        }
    } else {
        for (int c = 0; c < Cin; ++c)
            acc += r0[c] * wp[c * 3] + r1[c] * wp[c * 3 + 1] + r2[c] * wp[c * 3 + 2];
    }
    if (pe) acc += pe[(size_t)l * Cout + o];
    if (xmean_out) acc += xmean_out[(size_t)b * Cout + o];
    out[idx] = acc;
}

// ---------------- tiled fp32 GEMM: C[m,n] = sum_k A[m,k]*W[n,k] + bias[n], opt exact-GELU ----------------
__global__ __launch_bounds__(256) void gemm_bt(const float* __restrict__ A, const float* __restrict__ W,
                                               const float* __restrict__ bias, float* __restrict__ C,
                                               int M, int N, int K, int act)
{
    __shared__ float As[16][65];
    __shared__ float Ws[16][65];
    int tid = threadIdx.x;
    int tx = tid % 16, ty = tid / 16;
    int row0 = blockIdx.y * 64, col0 = blockIdx.x * 64;
    float acc[4][4] = {};
    for (int k0 = 0; k0 < K; k0 += 16) {
        for (int i = tid; i < 64 * 16; i += 256) {
            int r = i / 16, kk = i % 16;
            As[kk][r] = A[(size_t)(row0 + r) * K + k0 + kk];
            Ws[kk][r] = W[(size_t)(col0 + r) * K + k0 + kk];
        }
        __syncthreads();
#pragma unroll
        for (int kk = 0; kk < 16; ++kk) {
            float a[4], b[4];
#pragma unroll
            for (int i = 0; i < 4; ++i) a[i] = As[kk][ty * 4 + i];
#pragma unroll
            for (int j = 0; j < 4; ++j) b[j] = Ws[kk][tx * 4 + j];
#pragma unroll
            for (int i = 0; i < 4; ++i)
#pragma unroll
                for (int j = 0; j < 4; ++j) acc[i][j] += a[i] * b[j];
        }
        __syncthreads();
    }
#pragma unroll
    for (int i = 0; i < 4; ++i) {
        int r = row0 + ty * 4 + i;
#pragma unroll
        for (int j = 0; j < 4; ++j) {
            int c = col0 + tx * 4 + j;
            float v = acc[i][j] + (bias ? bias[c] : 0.f);
            if (act) v = 0.5f * v * (1.f + erff(v * 0.70710678118654752f));
            C[(size_t)r * N + c] = v;
        }
    }
}

// ---------------- forward DFT: X (B,L,D) head-sliced -> xf (B,H,E,MODES) ----------------
__global__ __launch_bounds__(256) void dft_fwd(const float* __restrict__ X,
                                               const float* __restrict__ twc, const float* __restrict__ tws,
                                               float* __restrict__ xr, float* __restrict__ xi)
{
    int b = blockIdx.x / H, h = blockIdx.x % H;
    __shared__ float xs[L][E];
    __shared__ float c[L][MODES], s[L][MODES];
    for (int i = threadIdx.x; i < L * E; i += 256) {
        int t = i / E, e = i % E;
        xs[t][e] = X[((size_t)b * L + t) * D + h * E + e];
    }
    for (int i = threadIdx.x; i < L * MODES; i += 256) { c[i / MODES][i % MODES] = twc[i]; s[i / MODES][i % MODES] = tws[i]; }
    __syncthreads();
    for (int o = threadIdx.x; o < E * MODES; o += 256) {
        int e = o / MODES, m = o % MODES;
        float re = 0.f, im = 0.f;
        for (int t = 0; t < L; ++t) {
            float v = xs[t][e];
            re += v * c[t][m];
            im -= v * s[t][m];
        }
        size_t idx = (((size_t)b * H + h) * E + e) * MODES + m;
        xr[idx] = re; xi[idx] = im;
    }
}

// sel[b,h,o,m] = sum_e xf[b,h,e,m] * Wc[h,e,o,m]   (complex)
__global__ __launch_bounds__(256) void mode_gemm(const float* __restrict__ xr, const float* __restrict__ xi,
                                                 const float* __restrict__ wr, const float* __restrict__ wi,
                                                 float* __restrict__ sr, float* __restrict__ si)
{
    int b = blockIdx.x / H, h = blockIdx.x % H;
    __shared__ float xre[E][MODES + 1], xim[E][MODES + 1];
    for (int i = threadIdx.x; i < E * MODES; i += 256) {
        int e = i / MODES, m = i % MODES;
        size_t idx = (((size_t)b * H + h) * E + e) * MODES + m;
        xre[e][m] = xr[idx]; xim[e][m] = xi[idx];
    }
    __syncthreads();
    for (int o = threadIdx.x; o < E * MODES; o += 256) {
        int oo = o / MODES, m = o % MODES;
        float re = 0.f, im = 0.f;
        for (int e = 0; e < E; ++e) {
            size_t widx = (((size_t)h * E + e) * E + oo) * MODES + m;
            float a = xre[e][m], bb = xim[e][m];
            float cr = wr[widx], ci = wi[widx];
            re += a * cr - bb * ci;
            im += a * ci + bb * cr;
        }
        size_t idx = (((size_t)b * H + h) * E + oo) * MODES + m;
        sr[idx] = re; si[idx] = im;
    }
}

// iDFT (irfft with modes>=MODES zero, DC imag ignored): out (B,L,D) head-sliced, scaled
__global__ __launch_bounds__(256) void idft(const float* __restrict__ sr, const float* __restrict__ si,
                                            const float* __restrict__ twc, const float* __restrict__ tws,
                                            float* __restrict__ out, float scale)
{
    int b = blockIdx.x / H, h = blockIdx.x % H;
    __shared__ float re[E][MODES + 1], im[E][MODES + 1];
    __shared__ float c[L][MODES], s[L][MODES];
    for (int i = threadIdx.x; i < E * MODES; i += 256) {
        int e = i / MODES, m = i % MODES;
        size_t idx = (((size_t)b * H + h) * E + e) * MODES + m;
        re[e][m] = sr[idx]; im[e][m] = si[idx];
    }
    for (int i = threadIdx.x; i < L * MODES; i += 256) { c[i / MODES][i % MODES] = twc[i]; s[i / MODES][i % MODES] = tws[i]; }
    __syncthreads();
    for (int o = threadIdx.x; o < L * E; o += 256) {
        int t = o / E, e = o % E;
        float acc = re[e][0];
        for (int m = 1; m < MODES; ++m)
            acc += 2.f * (re[e][m] * c[t][m] - im[e][m] * s[t][m]);
        out[((size_t)b * L + t) * D + h * E + e] = acc * scale;
    }
}

// scores[b,h,l,s] = (1/8) sum_e q[b,l,h,e]*k[b,s,h,e]
__global__ __launch_bounds__(256) void scores_kernel(const float* __restrict__ Q, const float* __restrict__ Kk,
                                                     float* __restrict__ out)
{
    int b = blockIdx.x / H, h = blockIdx.x % H;
    __shared__ float qs[L][E + 1], ks[L][E + 1];
    for (int i = threadIdx.x; i < L * E; i += 256) {
        int t = i / E, e = i % E;
        qs[t][e] = Q[((size_t)b * L + t) * D + h * E + e];
        ks[t][e] = Kk[((size_t)b * L + t) * D + h * E + e];
    }
    __syncthreads();
    for (int o = threadIdx.x; o < L * L; o += 256) {
        int l = o / L, ss = o % L;
        float acc = 0.f;
        for (int e = 0; e < E; ++e) acc += qs[l][e] * ks[ss][e];
        out[(((size_t)b * H + h) * L + l) * L + ss] = acc * 0.125f;
    }
}

__global__ __launch_bounds__(256) void softmax_rows(float* __restrict__ data, int nrows)
{
    int row = blockIdx.x * 4 + threadIdx.x / 64;
    int lane = threadIdx.x % 64;
    if (row >= nrows) return;
    float* p = data + (size_t)row * L;
    float v0 = (lane < L) ? p[lane] : -1e30f;
    float v1 = (lane + 64 < L) ? p[lane + 64] : -1e30f;
    float mx = fmaxf(v0, v1);
    for (int off = 32; off; off >>= 1) mx = fmaxf(mx, __shfl_xor(mx, off));
    float e0 = (lane < L) ? expf(v0 - mx) : 0.f;
    float e1 = (lane + 64 < L) ? expf(v1 - mx) : 0.f;
    float sum = e0 + e1;
    for (int off = 32; off; off >>= 1) sum += __shfl_xor(sum, off);
    float inv = 1.f / sum;
    if (lane < L) p[lane] = e0 * inv;
    if (lane + 64 < L) p[lane + 64] = e1 * inv;
}

// sigma: (B,H,L) = 3^(sigmoid(5*(enc@w.T+b))+1e-5)-1, stored transposed
__global__ void sigma_kernel(const float* __restrict__ enc, const float* __restrict__ w,
                             const float* __restrict__ bias, float* __restrict__ sig_out)
{
    int idx = blockIdx.x * 256 + threadIdx.x;
    if (idx >= B * L * H) return;
    int h = idx % H; int l = (idx / H) % L; int b = idx / (H * L);
    const float* row = enc + ((size_t)b * L + l) * D;
    const float* wr = w + (size_t)h * D;
    float acc = bias[h];
    for (int d = 0; d < D; ++d) acc += row[d] * wr[d];
    float sg = 1.f / (1.f + expf(-5.f * acc));
    float val = expf((sg + 1e-5f) * 1.0986122886681098f) - 1.f; // 3^u - 1
    sig_out[((size_t)b * H + h) * L + l] = val;
}

__global__ void prior_kernel(const float* __restrict__ sig, float* __restrict__ prior)
{
    int idx = blockIdx.x * 256 + threadIdx.x;
    if (idx >= (int)(B * H * L * L)) return;
    int s = idx % L; int l = (idx / L) % L; int bh = idx / (L * L);
    float sg = sig[(size_t)bh * L + l];
    float d = (float)abs(l - s);
    prior[idx] = expf(-d * d / (2.f * sg * sg)) * INV_SQRT_2PI / sg;
}

// series_decomp_multi: res = x - mean, mean = mix-weighted moving averages (k=12,24)
// tmode: 0 none, 1 trend = mean, 2 trend += mean
__global__ __launch_bounds__(256) void decomp_kernel(const float* __restrict__ in1, const float* __restrict__ in2,
                                                     const float* __restrict__ w, const float* __restrict__ bc,
                                                     float* __restrict__ res, float* __restrict__ trend, int tmode)
{
    int b = blockIdx.x / (D / 64);
    int d0 = (blockIdx.x % (D / 64)) * 64;
    __shared__ float xs[L][64];
    for (int i = threadIdx.x; i < L * 64; i += 256) {
        int t = i / 64, dd = i % 64;
        size_t g = ((size_t)b * L + t) * D + d0 + dd;
        float v = in1[g];
        if (in2) v += in2[g];
        xs[t][dd] = v;
    }
    __syncthreads();
    float w0 = w[0], w1 = w[1], b0 = bc[0], b1 = bc[1];
    for (int i = threadIdx.x; i < L * 64; i += 256) {
        int l = i / 64, dd = i % 64;
        float s12 = 0.f;
        for (int j = l - 5; j <= l + 6; ++j) s12 += xs[min(max(j, 0), L - 1)][dd];
        float s24 = 0.f;
        for (int j = l - 11; j <= l + 12; ++j) s24 += xs[min(max(j, 0), L - 1)][dd];
        float m0 = s12 * (1.f / 12.f), m1 = s24 * (1.f / 24.f);
        float x = xs[l][dd];
        float z0 = x * w0 + b0, z1 = x * w1 + b1;
        float zm = fmaxf(z0, z1);
        float e0 = expf(z0 - zm), e1 = expf(z1 - zm);
        float p0 = e0 / (e0 + e1);
        float mean = m0 * p0 + m1 * (1.f - p0);
        size_t g = ((size_t)b * L + l) * D + d0 + dd;
        res[g] = x - mean;
        if (tmode == 1) trend[g] = mean;
        else if (tmode == 2) trend[g] += mean;
    }
}

__global__ __launch_bounds__(256) void ln_row(const float* __restrict__ x, const float* __restrict__ g,
                                              const float* __restrict__ bb, float* __restrict__ out)
{
    int row = blockIdx.x;
    const float* p = x + (size_t)row * D;
    float s = 0.f, s2 = 0.f;
    for (int d = threadIdx.x; d < D; d += 256) { float v = p[d]; s += v; s2 += v * v; }
    for (int off = 32; off; off >>= 1) { s += __shfl_xor(s, off); s2 += __shfl_xor(s2, off); }
    __shared__ float red[8];
    int wid = threadIdx.x / 64, lane = threadIdx.x % 64;
    if (lane == 0) { red[wid] = s; red[4 + wid] = s2; }
    __syncthreads();
    if (threadIdx.x == 0) {
        red[0] = red[0] + red[1] + red[2] + red[3];
        red[4] = red[4] + red[5] + red[6] + red[7];
    }
    __syncthreads();
    float mu = red[0] / (float)D;
    float var = red[4] / (float)D - mu * mu;
    float rstd = rsqrtf(var + 1e-5f);
    for (int d = threadIdx.x; d < D; d += 256)
        out[(size_t)row * D + d] = (p[d] - mu) * rstd * g[d] + bb[d];
}

__global__ void col_sub(const float* __restrict__ xh, float* __restrict__ out)
{
    int idx = blockIdx.x * 256 + threadIdx.x;
    if (idx >= B * D) return;
    int b = idx / D, d = idx % D;
    float s = 0.f;
    for (int l = 0; l < L; ++l) s += xh[((size_t)b * L + l) * D + d];
    s *= (1.f / (float)L);
    for (int l = 0; l < L; ++l) {
        size_t g = ((size_t)b * L + l) * D + d;
        out[g] = xh[g] - s;
    }
}

// FourierCrossAttention core: qf,kf (B,H,E,MODES) -> sel (B,H,E,MODES)
__global__ __launch_bounds__(256) void fourier_cross_kernel(const float* __restrict__ qr, const float* __restrict__ qi,
                                                            const float* __restrict__ kr, const float* __restrict__ ki,
                                                            const float* __restrict__ wr, const float* __restrict__ wi,
                                                            float* __restrict__ sr, float* __restrict__ si)
{
    int b = blockIdx.x / H, h = blockIdx.x % H;
    __shared__ float qre[E][MODES + 1], qim[E][MODES + 1], kre[E][MODES + 1], kim[E][MODES + 1];
    __shared__ float tr[MODES][MODES + 1], ti[MODES][MODES + 1];
    __shared__ float vr[E][MODES + 1], vi[E][MODES + 1];
    for (int i = threadIdx.x; i < E * MODES; i += 256) {
        int e = i / MODES, m = i % MODES;
        size_t idx = (((size_t)b * H + h) * E + e) * MODES + m;
        qre[e][m] = qr[idx]; qim[e][m] = qi[idx];
        kre[e][m] = kr[idx]; kim[e][m] = ki[idx];
    }
    __syncthreads();
    // qk[x][y] = ctanh(sum_e qf[e][x]*kf[e][y])
    for (int i = threadIdx.x; i < MODES * MODES; i += 256) {
        int x = i / MODES, y = i % MODES;
        float re = 0.f, im = 0.f;
        for (int e = 0; e < E; ++e) {
            float ar = qre[e][x], ai = qim[e][x], br = kre[e][y], bi = kim[e][y];
            re += ar * br - ai * bi;
            im += ar * bi + ai * br;
        }
        float a = fminf(fmaxf(2.f * re, -30.f), 30.f);
        float b2 = 2.f * im;
        float den = coshf(a) + cosf(b2);
        tr[x][y] = sinhf(a) / den;
        ti[x][y] = sinf(b2) / den;
    }
    __syncthreads();
    // qkv[e][x] = sum_y qk[x][y]*kf[e][y]
    for (int i = threadIdx.x; i < E * MODES; i += 256) {
        int e = i / MODES, x = i % MODES;
        float re = 0.f, im = 0.f;
        for (int y = 0; y < MODES; ++y) {
            float ar = tr[x][y], ai = ti[x][y], br = kre[e][y], bi = kim[e][y];
            re += ar * br - ai * bi;
            im += ar * bi + ai * br;
        }
        vr[e][x] = re; vi[e][x] = im;
    }
    __syncthreads();
    // w[o][x] = sum_e qkv[e][x]*Wc[h,e,o,x]
    for (int i = threadIdx.x; i < E * MODES; i += 256) {
        int o = i / MODES, x = i % MODES;
        float re = 0.f, im = 0.f;
        for (int e = 0; e < E; ++e) {
            size_t widx = (((size_t)h * E + e) * E + o) * MODES + x;
            float ar = vr[e][x], ai = vi[e][x], br = wr[widx], bi = wi[widx];
            re += ar * br - ai * bi;
            im += ar * bi + ai * br;
        }
        size_t idx = (((size_t)b * H + h) * E + o) * MODES + x;
        sr[idx] = re; si[idx] = im;
    }
}

// dec_out[b,l,o] += hln[b,l,:] . out_proj_w[o,:] + bias[o]
__global__ void seasonal_add(const float* __restrict__ hln, const float* __restrict__ W,
                             const float* __restrict__ bias, float* __restrict__ out)
{
    int idx = blockIdx.x * 256 + threadIdx.x;
    if (idx >= B * L * COUT) return;
    int o = idx % COUT; int row = idx / COUT;
    const float* p = hln + (size_t)row * D;
    const float* wrow = W + (size_t)o * D;
    float acc = bias[o];
    for (int d = 0; d < D; ++d) acc += p[d] * wrow[d];
    out[idx] += acc;
}

extern "C" void kernel_launch(void* const* d_in, const int* in_sizes, int n_in,
                              void* d_out, int out_size, void* d_ws, size_t ws_size,
                              hipStream_t stream)
{
    const float* x           = (const float*)d_in[0];
    const float* emb_enc_w   = (const float*)d_in[1];
    const float* emb_dec_w   = (const float*)d_in[2];
    const float* enc_proj_w  = (const float*)d_in[3];
    const float* enc_proj_b  = (const float*)d_in[4];
    const float* enc_sig_w   = (const float*)d_in[5];
    const float* enc_sig_b   = (const float*)d_in[6];
    const float* enc_four_wr = (const float*)d_in[7];
    const float* enc_four_wi = (const float*)d_in[8];
    const float* enc_ffn_w1  = (const float*)d_in[9];
    const float* enc_ffn_w2  = (const float*)d_in[10];
    const float* enc_dcmp_w  = (const float*)d_in[11];
    const float* enc_dcmp_b  = (const float*)d_in[12];
    const float* enc_norm_g  = (const float*)d_in[13];
    const float* enc_norm_b  = (const float*)d_in[14];
    const float* dec_proj_w  = (const float*)d_in[15];
    const float* dec_proj_b  = (const float*)d_in[16];
    const float* dec_four_wr = (const float*)d_in[17];
    const float* dec_four_wi = (const float*)d_in[18];
    const float* crs_proj_w  = (const float*)d_in[19];
    const float* crs_proj_b  = (const float*)d_in[20];
    const float* crs_four_wr = (const float*)d_in[21];
    const float* crs_four_wi = (const float*)d_in[22];
    const float* dec_ffn_w1  = (const float*)d_in[23];
    const float* dec_ffn_w2  = (const float*)d_in[24];
    const float* dec_dcmp_w  = (const float*)d_in[25];
    const float* dec_dcmp_b  = (const float*)d_in[26];
    const float* dec_trend_w = (const float*)d_in[27];
    const float* dec_norm_g  = (const float*)d_in[28];
    const float* dec_norm_b  = (const float*)d_in[29];
    const float* out_proj_w  = (const float*)d_in[30];
    const float* out_proj_b  = (const float*)d_in[31];

    float* ws = (float*)d_ws;
    size_t off = 0;
    float* pe    = ws + off; off += (size_t)L * D;
    float* twc   = ws + off; off += (size_t)L * MODES;
    float* tws_  = ws + off; off += (size_t)L * MODES;
    float* xmean = ws + off; off += (size_t)B * CIN;
    float* enc   = ws + off; off += BLD;
    float* bufA  = ws + off; off += BLD;
    float* bufB  = ws + off; off += BLD;
    float* bufC  = ws + off; off += BLD;
    float* bufD  = ws + off; off += BLD;
    float* bufH  = ws + off; off += BLD;
    float* tacc  = ws + off; off += BLD;
    float* xf_re = ws + off; off += BHEM;
    float* xf_im = ws + off; off += BHEM;
    float* sel_re= ws + off; off += BHEM;
    float* sel_im= ws + off; off += BHEM;
    float* kf_re = ws + off; off += BHEM;
    float* kf_im = ws + off; off += BHEM;

    float* out       = (float*)d_out;
    float* dec_out   = out;                                   // B*L*COUT
    float* series_out= out + (size_t)B * L * COUT;            // 2*BHLL
    float* prior_out = series_out + 2 * BHLL;                 // 2*BHLL
    float* sigma_out = prior_out + 2 * BHLL;                  // 2*B*H*L

    const int BH = B * H;

    init_consts<<<200, 256, 0, stream>>>(pe, twc, tws_);
    xmean_kernel<<<cdiv(B * CIN, 256), 256, 0, stream>>>(x, xmean);

    // encoder embedding
    circ_conv<<<cdiv(B * L * D, 256), 256, 0, stream>>>(x, emb_enc_w, pe, nullptr, nullptr, enc, CIN, D);

    auto gemm = [&](const float* A, const float* W, const float* bias, float* C, int N, int K, int act) {
        dim3 grid(N / 64, M_ROWS / 64);
        gemm_bt<<<grid, 256, 0, stream>>>(A, W, bias, C, M_ROWS, N, K, act);
    };

    for (int i = 0; i < 2; ++i) {
        const float* Wp = enc_proj_w + (size_t)i * 4 * D * D;
        const float* bp = enc_proj_b + (size_t)i * 4 * D;
        float* series_i = series_out + (size_t)i * BHLL;
        float* prior_i  = prior_out  + (size_t)i * BHLL;
        float* sigma_i  = sigma_out  + (size_t)i * B * H * L;

        gemm(enc, Wp,             bp,         bufA, D, D, 0);   // q
        gemm(enc, Wp + D * D,     bp + D,     bufB, D, D, 0);   // k
        dft_fwd<<<BH, 256, 0, stream>>>(bufA, twc, tws_, xf_re, xf_im);
        mode_gemm<<<BH, 256, 0, stream>>>(xf_re, xf_im, enc_four_wr, enc_four_wi, sel_re, sel_im);
        idft<<<BH, 256, 0, stream>>>(sel_re, sel_im, twc, tws_, bufC, 1.f / (float)L);
        gemm(bufC, Wp + 3 * D * D, bp + 3 * D, bufD, D, D, 0);  // attn_out
        scores_kernel<<<BH, 256, 0, stream>>>(bufA, bufB, series_i);
        softmax_rows<<<B * H * L / 4, 256, 0, stream>>>(series_i, B * H * L);
        sigma_kernel<<<cdiv(B * L * H, 256), 256, 0, stream>>>(enc, enc_sig_w + (size_t)i * H * D,
                                                               enc_sig_b + (size_t)i * H, sigma_i);
        prior_kernel<<<cdiv((int)BHLL, 256), 256, 0, stream>>>(sigma_i, prior_i);
        decomp_kernel<<<B * (D / 64), 256, 0, stream>>>(enc, bufD, enc_dcmp_w + (size_t)(i * 2 + 0) * NK,
                                                        enc_dcmp_b + (size_t)(i * 2 + 0) * NK, bufH, nullptr, 0);
        gemm(bufH, enc_ffn_w1 + (size_t)i * DFF * D, nullptr, bufC, DFF, D, 1);
        gemm(bufC, enc_ffn_w2 + (size_t)i * D * DFF, nullptr, bufD, D, DFF, 0);
        decomp_kernel<<<B * (D / 64), 256, 0, stream>>>(bufH, bufD, enc_dcmp_w + (size_t)(i * 2 + 1) * NK,
                                                        enc_dcmp_b + (size_t)(i * 2 + 1) * NK, enc, nullptr, 0);
    }
    // encoder final my_layernorm
    ln_row<<<M_ROWS, 256, 0, stream>>>(enc, enc_norm_g, enc_norm_b, bufC);
    col_sub<<<cdiv(B * D, 256), 256, 0, stream>>>(bufC, enc);

    // ---------------- decoder ----------------
    circ_conv<<<cdiv(B * L * D, 256), 256, 0, stream>>>(x, emb_dec_w, pe, xmean, nullptr, bufA, CIN, D); // dec
    gemm(bufA, dec_proj_w, dec_proj_b, bufB, D, D, 0);                       // q
    dft_fwd<<<BH, 256, 0, stream>>>(bufB, twc, tws_, xf_re, xf_im);
    mode_gemm<<<BH, 256, 0, stream>>>(xf_re, xf_im, dec_four_wr, dec_four_wi, sel_re, sel_im);
    idft<<<BH, 256, 0, stream>>>(sel_re, sel_im, twc, tws_, bufC, 1.f / (float)L);
    gemm(bufC, dec_proj_w + 3 * D * D, dec_proj_b + 3 * D, bufD, D, D, 0);   // sa
    decomp_kernel<<<B * (D / 64), 256, 0, stream>>>(bufA, bufD, dec_dcmp_w, dec_dcmp_b, bufH, tacc, 1); // h, t1

    gemm(bufH, crs_proj_w, crs_proj_b, bufB, D, D, 0);                       // qc
    dft_fwd<<<BH, 256, 0, stream>>>(bufB, twc, tws_, xf_re, xf_im);          // qf
    gemm(enc, crs_proj_w + D * D, crs_proj_b + D, bufB, D, D, 0);            // kc
    dft_fwd<<<BH, 256, 0, stream>>>(bufB, twc, tws_, kf_re, kf_im);          // kf
    fourier_cross_kernel<<<BH, 256, 0, stream>>>(xf_re, xf_im, kf_re, kf_im, crs_four_wr, crs_four_wi, sel_re, sel_im);
    idft<<<BH, 256, 0, stream>>>(sel_re, sel_im, twc, tws_, bufC, 1.f / ((float)L * (float)D * (float)D));
    gemm(bufC, crs_proj_w + 3 * D * D, crs_proj_b + 3 * D, bufD, D, D, 0);   // ca
    decomp_kernel<<<B * (D / 64), 256, 0, stream>>>(bufH, bufD, dec_dcmp_w + NK, dec_dcmp_b + NK, bufA, tacc, 2); // h2, t2

    gemm(bufA, dec_ffn_w1, nullptr, bufC, DFF, D, 1);
    gemm(bufC, dec_ffn_w2, nullptr, bufD, D, DFF, 0);
    decomp_kernel<<<B * (D / 64), 256, 0, stream>>>(bufA, bufD, dec_dcmp_w + 2 * NK, dec_dcmp_b + 2 * NK, bufB, tacc, 2); // h3, t3

    // trend conv + trend_init -> dec_out
    circ_conv<<<cdiv(B * L * COUT, 256), 256, 0, stream>>>(tacc, dec_trend_w, nullptr, nullptr, xmean, dec_out, D, COUT);
    // final layernorm + seasonal projection added into dec_out
    ln_row<<<M_ROWS, 256, 0, stream>>>(bufB, dec_norm_g, dec_norm_b, bufC);
    col_sub<<<cdiv(B * D, 256), 256, 0, stream>>>(bufC, bufA);
    seasonal_add<<<cdiv(B * L * COUT, 256), 256, 0, stream>>>(bufA, out_proj_w, out_proj_b, dec_out);
}

// Round 3
// 5559.739 us; speedup vs baseline: 1.6541x; 1.6541x over previous
//
#include <hip/hip_runtime.h>
#include <cmath>

constexpr int B = 128, L = 100, CIN = 55, COUT = 55;
constexpr int D = 512, H = 8, DFF = 512, MODES = 32, E = 64;
constexpr int NK = 2;
constexpr int M_ROWS = B * L; // 12800
constexpr int KEMB = 176;     // 55*3=165 padded to 16x11
constexpr int KTRD = 1536;    // 512*3
constexpr size_t BLD  = (size_t)B * L * D;         // 6,553,600
constexpr size_t BHEM = (size_t)B * H * E * MODES; // 2,097,152
constexpr size_t BHLL = (size_t)B * H * L * L;     // 10,240,000
constexpr float INV_SQRT_2PI = 0.3989422804014327f;

static inline int cdiv(int a, int b) { return (a + b - 1) / b; }

// ---------------- constants: positional emb + DFT twiddles ----------------
__global__ void init_consts(float* __restrict__ pe, float* __restrict__ twc, float* __restrict__ tws)
{
    int idx = blockIdx.x * 256 + threadIdx.x;
    if (idx < L * D) {
        int l = idx / D, d = idx % D;
        int i2 = d & ~1;
        float div = expf((float)i2 * (-logf(10000.f) / (float)D));
        float ang = (float)l * div;
        pe[idx] = (d & 1) ? cosf(ang) : sinf(ang);
    }
    if (idx < L * MODES) {
        int t = idx / MODES, m = idx % MODES;
        float th = 2.f * 3.14159265358979323846f * (float)m * (float)t / (float)L;
        twc[idx] = cosf(th);
        tws[idx] = sinf(th);
    }
}

__global__ void xmean_kernel(const float* __restrict__ x, float* __restrict__ xm)
{
    int idx = blockIdx.x * 256 + threadIdx.x;
    if (idx >= B * CIN) return;
    int b = idx / CIN, c = idx % CIN;
    float s = 0.f;
    for (int l = 0; l < L; ++l) s += x[((size_t)b * L + l) * CIN + c];
    xm[idx] = s * (1.f / (float)L);
}

// pad src (rows_src x k_src) into dst (rows_dst x k_dst), zero-filled
__global__ void pad_rows(const float* __restrict__ src, float* __restrict__ dst,
                         int rows_src, int rows_dst, int k_src, int k_dst)
{
    int idx = blockIdx.x * 256 + threadIdx.x;
    if (idx >= rows_dst * k_dst) return;
    int r = idx / k_dst, k = idx % k_dst;
    dst[idx] = (r < rows_src && k < k_src) ? src[(size_t)r * k_src + k] : 0.f;
}

// trend weight: src (COUT,D,3) flat o*1536+d*3+j  ->  dst[o][j*D+d], rows padded to 64
__global__ void pad_trend_w(const float* __restrict__ src, float* __restrict__ dst)
{
    int idx = blockIdx.x * 256 + threadIdx.x;
    if (idx >= 64 * KTRD) return;
    int o = idx / KTRD, k = idx % KTRD;
    int j = k / D, d = k % D;
    dst[idx] = (o < COUT) ? src[(size_t)o * KTRD + d * 3 + j] : 0.f;
}

// im2col for kernel-3 circular conv on (B,L,CIN): A2[m][k], k=c*3+j, padded to KEMB
__global__ void im2col_emb(const float* __restrict__ x, const float* __restrict__ xmean,
                           float* __restrict__ A2)
{
    int idx = blockIdx.x * 256 + threadIdx.x;
    if (idx >= M_ROWS * KEMB) return;
    int k = idx % KEMB, m = idx / KEMB;
    float v = 0.f;
    if (k < CIN * 3) {
        int c = k / 3, j = k % 3;
        int l = m % L, b = m / L;
        int ls = l + j - 1; ls = (ls + L) % L;
        v = x[((size_t)b * L + ls) * CIN + c];
        if (xmean) v -= xmean[(size_t)b * CIN + c];
    }
    A2[idx] = v;
}

// im2col for trend conv: A2[m][k], k=j*512+d
__global__ void im2col_trend(const float* __restrict__ t, float* __restrict__ A2)
{
    int idx = blockIdx.x * 256 + threadIdx.x;
    if (idx >= (int)(M_ROWS * (size_t)KTRD)) return;
    int k = idx % KTRD, m = idx / KTRD;
    int j = k / D, d = k % D;
    int l = m % L, b = m / L;
    int ls = l + j - 1; ls = (ls + L) % L;
    A2[idx] = t[((size_t)b * L + ls) * D + d];
}

// ---------------- tiled fp32 GEMM: C[m,n<Nout] = sum_k A[m,k]*W[n,k] (+bias)(+pe[r%L])(+rowbias[r/L]) ----------------
__global__ __launch_bounds__(256) void gemm_bt(const float* __restrict__ A, const float* __restrict__ W,
                                               const float* __restrict__ bias, const float* __restrict__ pe,
                                               const float* __restrict__ rowbias, float* __restrict__ C,
                                               int M, int N, int Nout, int K, int act, int accum)
{
    __shared__ float As[16][65];
    __shared__ float Ws[16][65];
    int tid = threadIdx.x;
    int tx = tid % 16, ty = tid / 16;
    int row0 = blockIdx.y * 64, col0 = blockIdx.x * 64;
    float acc[4][4] = {};
    for (int k0 = 0; k0 < K; k0 += 16) {
        for (int i = tid; i < 64 * 16; i += 256) {
            int r = i / 16, kk = i % 16;
            As[kk][r] = A[(size_t)(row0 + r) * K + k0 + kk];
            Ws[kk][r] = W[(size_t)(col0 + r) * K + k0 + kk];
        }
        __syncthreads();
#pragma unroll
        for (int kk = 0; kk < 16; ++kk) {
            float a[4], b[4];
#pragma unroll
            for (int i = 0; i < 4; ++i) a[i] = As[kk][ty * 4 + i];
#pragma unroll
            for (int j = 0; j < 4; ++j) b[j] = Ws[kk][tx * 4 + j];
#pragma unroll
            for (int i = 0; i < 4; ++i)
#pragma unroll
                for (int j = 0; j < 4; ++j) acc[i][j] += a[i] * b[j];
        }
        __syncthreads();
    }
#pragma unroll
    for (int i = 0; i < 4; ++i) {
        int r = row0 + ty * 4 + i;
#pragma unroll
        for (int j = 0; j < 4; ++j) {
            int c = col0 + tx * 4 + j;
            if (c >= Nout) continue;
            float v = acc[i][j];
            if (bias) v += bias[c];
            if (pe) v += pe[(size_t)(r % L) * Nout + c];
            if (rowbias) v += rowbias[(size_t)(r / L) * Nout + c];
            if (act) v = 0.5f * v * (1.f + erff(v * 0.70710678118654752f));
            size_t o = (size_t)r * Nout + c;
            if (accum) C[o] += v; else C[o] = v;
        }
    }
}

// ---------------- forward DFT: X (B,L,D) head-sliced -> xf (B,H,E,MODES) ----------------
__global__ __launch_bounds__(256) void dft_fwd(const float* __restrict__ X,
                                               const float* __restrict__ twc, const float* __restrict__ tws,
                                               float* __restrict__ xr, float* __restrict__ xi)
{
    int b = blockIdx.x / H, h = blockIdx.x % H;
    __shared__ float xs[L][E];
    __shared__ float c[L][MODES], s[L][MODES];
    for (int i = threadIdx.x; i < L * E; i += 256) {
        int t = i / E, e = i % E;
        xs[t][e] = X[((size_t)b * L + t) * D + h * E + e];
    }
    for (int i = threadIdx.x; i < L * MODES; i += 256) { c[i / MODES][i % MODES] = twc[i]; s[i / MODES][i % MODES] = tws[i]; }
    __syncthreads();
    for (int o = threadIdx.x; o < E * MODES; o += 256) {
        int e = o / MODES, m = o % MODES;
        float re = 0.f, im = 0.f;
        for (int t = 0; t < L; ++t) {
            float v = xs[t][e];
            re += v * c[t][m];
            im -= v * s[t][m];
        }
        size_t idx = (((size_t)b * H + h) * E + e) * MODES + m;
        xr[idx] = re; xi[idx] = im;
    }
}

// sel[b,h,o,m] = sum_e xf[b,h,e,m] * Wc[h,e,o,m]   (complex)
__global__ __launch_bounds__(256) void mode_gemm(const float* __restrict__ xr, const float* __restrict__ xi,
                                                 const float* __restrict__ wr, const float* __restrict__ wi,
                                                 float* __restrict__ sr, float* __restrict__ si)
{
    int b = blockIdx.x / H, h = blockIdx.x % H;
    __shared__ float xre[E][MODES + 1], xim[E][MODES + 1];
    for (int i = threadIdx.x; i < E * MODES; i += 256) {
        int e = i / MODES, m = i % MODES;
        size_t idx = (((size_t)b * H + h) * E + e) * MODES + m;
        xre[e][m] = xr[idx]; xim[e][m] = xi[idx];
    }
    __syncthreads();
    for (int o = threadIdx.x; o < E * MODES; o += 256) {
        int oo = o / MODES, m = o % MODES;
        float re = 0.f, im = 0.f;
        for (int e = 0; e < E; ++e) {
            size_t widx = (((size_t)h * E + e) * E + oo) * MODES + m;
            float a = xre[e][m], bb = xim[e][m];
            float cr = wr[widx], ci = wi[widx];
            re += a * cr - bb * ci;
            im += a * ci + bb * cr;
        }
        size_t idx = (((size_t)b * H + h) * E + oo) * MODES + m;
        sr[idx] = re; si[idx] = im;
    }
}

// iDFT (irfft with modes>=MODES zero, DC imag ignored): out (B,L,D) head-sliced, scaled
__global__ __launch_bounds__(256) void idft(const float* __restrict__ sr, const float* __restrict__ si,
                                            const float* __restrict__ twc, const float* __restrict__ tws,
                                            float* __restrict__ out, float scale)
{
    int b = blockIdx.x / H, h = blockIdx.x % H;
    __shared__ float re[E][MODES + 1], im[E][MODES + 1];
    __shared__ float c[L][MODES], s[L][MODES];
    for (int i = threadIdx.x; i < E * MODES; i += 256) {
        int e = i / MODES, m = i % MODES;
        size_t idx = (((size_t)b * H + h) * E + e) * MODES + m;
        re[e][m] = sr[idx]; im[e][m] = si[idx];
    }
    for (int i = threadIdx.x; i < L * MODES; i += 256) { c[i / MODES][i % MODES] = twc[i]; s[i / MODES][i % MODES] = tws[i]; }
    __syncthreads();
    for (int o = threadIdx.x; o < L * E; o += 256) {
        int t = o / E, e = o % E;
        float acc = re[e][0];
        for (int m = 1; m < MODES; ++m)
            acc += 2.f * (re[e][m] * c[t][m] - im[e][m] * s[t][m]);
        out[((size_t)b * L + t) * D + h * E + e] = acc * scale;
    }
}

// scores[b,h,l,s] = (1/8) sum_e q[b,l,h,e]*k[b,s,h,e]
__global__ __launch_bounds__(256) void scores_kernel(const float* __restrict__ Q, const float* __restrict__ Kk,
                                                     float* __restrict__ out)
{
    int b = blockIdx.x / H, h = blockIdx.x % H;
    __shared__ float qs[L][E + 1], ks[L][E + 1];
    for (int i = threadIdx.x; i < L * E; i += 256) {
        int t = i / E, e = i % E;
        qs[t][e] = Q[((size_t)b * L + t) * D + h * E + e];
        ks[t][e] = Kk[((size_t)b * L + t) * D + h * E + e];
    }
    __syncthreads();
    for (int o = threadIdx.x; o < L * L; o += 256) {
        int l = o / L, ss = o % L;
        float acc = 0.f;
        for (int e = 0; e < E; ++e) acc += qs[l][e] * ks[ss][e];
        out[(((size_t)b * H + h) * L + l) * L + ss] = acc * 0.125f;
    }
}

__global__ __launch_bounds__(256) void softmax_rows(float* __restrict__ data, int nrows)
{
    int row = blockIdx.x * 4 + threadIdx.x / 64;
    int lane = threadIdx.x % 64;
    if (row >= nrows) return;
    float* p = data + (size_t)row * L;
    float v0 = (lane < L) ? p[lane] : -1e30f;
    float v1 = (lane + 64 < L) ? p[lane + 64] : -1e30f;
    float mx = fmaxf(v0, v1);
    for (int off = 32; off; off >>= 1) mx = fmaxf(mx, __shfl_xor(mx, off));
    float e0 = (lane < L) ? expf(v0 - mx) : 0.f;
    float e1 = (lane + 64 < L) ? expf(v1 - mx) : 0.f;
    float sum = e0 + e1;
    for (int off = 32; off; off >>= 1) sum += __shfl_xor(sum, off);
    float inv = 1.f / sum;
    if (lane < L) p[lane] = e0 * inv;
    if (lane + 64 < L) p[lane + 64] = e1 * inv;
}

// sigma: (B,H,L) = 3^(sigmoid(5*(enc@w.T+b))+1e-5)-1, stored transposed. One wave per row.
__global__ __launch_bounds__(256) void sigma_kernel(const float* __restrict__ enc, const float* __restrict__ w,
                                                    const float* __restrict__ bias, float* __restrict__ sig_out)
{
    __shared__ float wsh[H][D];
    for (int i = threadIdx.x; i < H * D; i += 256) wsh[i / D][i % D] = w[i];
    __syncthreads();
    int wid = threadIdx.x / 64, lane = threadIdx.x % 64;
    int row = blockIdx.x * 4 + wid;
    const float* p = enc + (size_t)row * D;
    float xv[8];
#pragma unroll
    for (int i = 0; i < 8; ++i) xv[i] = p[lane + i * 64];
    int b = row / L, l = row % L;
#pragma unroll
    for (int h = 0; h < H; ++h) {
        float s = 0.f;
#pragma unroll
        for (int i = 0; i < 8; ++i) s += xv[i] * wsh[h][lane + i * 64];
        for (int off = 32; off; off >>= 1) s += __shfl_xor(s, off);
        if (lane == 0) {
            float acc = s + bias[h];
            float sg = 1.f / (1.f + expf(-5.f * acc));
            float val = expf((sg + 1e-5f) * 1.0986122886681098f) - 1.f; // 3^u - 1
            sig_out[((size_t)b * H + h) * L + l] = val;
        }
    }
}

__global__ void prior_kernel(const float* __restrict__ sig, float* __restrict__ prior)
{
    int idx = blockIdx.x * 256 + threadIdx.x;
    if (idx >= (int)(B * H * L * L)) return;
    int s = idx % L; int l = (idx / L) % L; int bh = idx / (L * L);
    float sg = sig[(size_t)bh * L + l];
    float d = (float)abs(l - s);
    prior[idx] = expf(-d * d / (2.f * sg * sg)) * INV_SQRT_2PI / sg;
}

// series_decomp_multi: res = x - mean, mean = mix-weighted moving averages (k=12,24)
// tmode: 0 none, 1 trend = mean, 2 trend += mean
__global__ __launch_bounds__(256) void decomp_kernel(const float* __restrict__ in1, const float* __restrict__ in2,
                                                     const float* __restrict__ w, const float* __restrict__ bc,
                                                     float* __restrict__ res, float* __restrict__ trend, int tmode)
{
    int b = blockIdx.x / (D / 64);
    int d0 = (blockIdx.x % (D / 64)) * 64;
    __shared__ float xs[L][64];
    for (int i = threadIdx.x; i < L * 64; i += 256) {
        int t = i / 64, dd = i % 64;
        size_t g = ((size_t)b * L + t) * D + d0 + dd;
        float v = in1[g];
        if (in2) v += in2[g];
        xs[t][dd] = v;
    }
    __syncthreads();
    float w0 = w[0], w1 = w[1], b0 = bc[0], b1 = bc[1];
    for (int i = threadIdx.x; i < L * 64; i += 256) {
        int l = i / 64, dd = i % 64;
        float s12 = 0.f;
        for (int j = l - 5; j <= l + 6; ++j) s12 += xs[min(max(j, 0), L - 1)][dd];
        float s24 = 0.f;
        for (int j = l - 11; j <= l + 12; ++j) s24 += xs[min(max(j, 0), L - 1)][dd];
        float m0 = s12 * (1.f / 12.f), m1 = s24 * (1.f / 24.f);
        float x = xs[l][dd];
        float z0 = x * w0 + b0, z1 = x * w1 + b1;
        float zm = fmaxf(z0, z1);
        float e0 = expf(z0 - zm), e1 = expf(z1 - zm);
        float p0 = e0 / (e0 + e1);
        float mean = m0 * p0 + m1 * (1.f - p0);
        size_t g = ((size_t)b * L + l) * D + d0 + dd;
        res[g] = x - mean;
        if (tmode == 1) trend[g] = mean;
        else if (tmode == 2) trend[g] += mean;
    }
}

__global__ __launch_bounds__(256) void ln_row(const float* __restrict__ x, const float* __restrict__ g,
                                              const float* __restrict__ bb, float* __restrict__ out)
{
    int row = blockIdx.x;
    const float* p = x + (size_t)row * D;
    float s = 0.f, s2 = 0.f;
    for (int d = threadIdx.x; d < D; d += 256) { float v = p[d]; s += v; s2 += v * v; }
    for (int off = 32; off; off >>= 1) { s += __shfl_xor(s, off); s2 += __shfl_xor(s2, off); }
    __shared__ float red[8];
    int wid = threadIdx.x / 64, lane = threadIdx.x % 64;
    if (lane == 0) { red[wid] = s; red[4 + wid] = s2; }
    __syncthreads();
    if (threadIdx.x == 0) {
        red[0] = red[0] + red[1] + red[2] + red[3];
        red[4] = red[4] + red[5] + red[6] + red[7];
    }
    __syncthreads();
    float mu = red[0] / (float)D;
    float var = red[4] / (float)D - mu * mu;
    float rstd = rsqrtf(var + 1e-5f);
    for (int d = threadIdx.x; d < D; d += 256)
        out[(size_t)row * D + d] = (p[d] - mu) * rstd * g[d] + bb[d];
}

__global__ void col_sub(const float* __restrict__ xh, float* __restrict__ out)
{
    int idx = blockIdx.x * 256 + threadIdx.x;
    if (idx >= B * D) return;
    int b = idx / D, d = idx % D;
    float s = 0.f;
    for (int l = 0; l < L; ++l) s += xh[((size_t)b * L + l) * D + d];
    s *= (1.f / (float)L);
    for (int l = 0; l < L; ++l) {
        size_t g = ((size_t)b * L + l) * D + d;
        out[g] = xh[g] - s;
    }
}

// FourierCrossAttention core: qf,kf (B,H,E,MODES) -> sel (B,H,E,MODES)
__global__ __launch_bounds__(256) void fourier_cross_kernel(const float* __restrict__ qr, const float* __restrict__ qi,
                                                            const float* __restrict__ kr, const float* __restrict__ ki,
                                                            const float* __restrict__ wr, const float* __restrict__ wi,
                                                            float* __restrict__ sr, float* __restrict__ si)
{
    int b = blockIdx.x / H, h = blockIdx.x % H;
    __shared__ float qre[E][MODES + 1], qim[E][MODES + 1], kre[E][MODES + 1], kim[E][MODES + 1];
    __shared__ float tr[MODES][MODES + 1], ti[MODES][MODES + 1];
    __shared__ float vr[E][MODES + 1], vi[E][MODES + 1];
    for (int i = threadIdx.x; i < E * MODES; i += 256) {
        int e = i / MODES, m = i % MODES;
        size_t idx = (((size_t)b * H + h) * E + e) * MODES + m;
        qre[e][m] = qr[idx]; qim[e][m] = qi[idx];
        kre[e][m] = kr[idx]; kim[e][m] = ki[idx];
    }
    __syncthreads();
    for (int i = threadIdx.x; i < MODES * MODES; i += 256) {
        int x = i / MODES, y = i % MODES;
        float re = 0.f, im = 0.f;
        for (int e = 0; e < E; ++e) {
            float ar = qre[e][x], ai = qim[e][x], br = kre[e][y], bi = kim[e][y];
            re += ar * br - ai * bi;
            im += ar * bi + ai * br;
        }
        float a = fminf(fmaxf(2.f * re, -30.f), 30.f);
        float b2 = 2.f * im;
        float den = coshf(a) + cosf(b2);
        tr[x][y] = sinhf(a) / den;
        ti[x][y] = sinf(b2) / den;
    }
    __syncthreads();
    for (int i = threadIdx.x; i < E * MODES; i += 256) {
        int e = i / MODES, x = i % MODES;
        float re = 0.f, im = 0.f;
        for (int y = 0; y < MODES; ++y) {
            float ar = tr[x][y], ai = ti[x][y], br = kre[e][y], bi = kim[e][y];
            re += ar * br - ai * bi;
            im += ar * bi + ai * br;
        }
        vr[e][x] = re; vi[e][x] = im;
    }
    __syncthreads();
    for (int i = threadIdx.x; i < E * MODES; i += 256) {
        int o = i / MODES, x = i % MODES;
        float re = 0.f, im = 0.f;
        for (int e = 0; e < E; ++e) {
            size_t widx = (((size_t)h * E + e) * E + o) * MODES + x;
            float ar = vr[e][x], ai = vi[e][x], br = wr[widx], bi = wi[widx];
            re += ar * br - ai * bi;
            im += ar * bi + ai * br;
        }
        size_t idx = (((size_t)b * H + h) * E + o) * MODES + x;
        sr[idx] = re; si[idx] = im;
    }
}

extern "C" void kernel_launch(void* const* d_in, const int* in_sizes, int n_in,
                              void* d_out, int out_size, void* d_ws, size_t ws_size,
                              hipStream_t stream)
{
    const float* x           = (const float*)d_in[0];
    const float* emb_enc_w   = (const float*)d_in[1];
    const float* emb_dec_w   = (const float*)d_in[2];
    const float* enc_proj_w  = (const float*)d_in[3];
    const float* enc_proj_b  = (const float*)d_in[4];
    const float* enc_sig_w   = (const float*)d_in[5];
    const float* enc_sig_b   = (const float*)d_in[6];
    const float* enc_four_wr = (const float*)d_in[7];
    const float* enc_four_wi = (const float*)d_in[8];
    const float* enc_ffn_w1  = (const float*)d_in[9];
    const float* enc_ffn_w2  = (const float*)d_in[10];
    const float* enc_dcmp_w  = (const float*)d_in[11];
    const float* enc_dcmp_b  = (const float*)d_in[12];
    const float* enc_norm_g  = (const float*)d_in[13];
    const float* enc_norm_b  = (const float*)d_in[14];
    const float* dec_proj_w  = (const float*)d_in[15];
    const float* dec_proj_b  = (const float*)d_in[16];
    const float* dec_four_wr = (const float*)d_in[17];
    const float* dec_four_wi = (const float*)d_in[18];
    const float* crs_proj_w  = (const float*)d_in[19];
    const float* crs_proj_b  = (const float*)d_in[20];
    const float* crs_four_wr = (const float*)d_in[21];
    const float* crs_four_wi = (const float*)d_in[22];
    const float* dec_ffn_w1  = (const float*)d_in[23];
    const float* dec_ffn_w2  = (const float*)d_in[24];
    const float* dec_dcmp_w  = (const float*)d_in[25];
    const float* dec_dcmp_b  = (const float*)d_in[26];
    const float* dec_trend_w = (const float*)d_in[27];
    const float* dec_norm_g  = (const float*)d_in[28];
    const float* dec_norm_b  = (const float*)d_in[29];
    const float* out_proj_w  = (const float*)d_in[30];
    const float* out_proj_b  = (const float*)d_in[31];

    float* ws = (float*)d_ws;
    size_t off = 0;
    float* pe    = ws + off; off += (size_t)L * D;
    float* twc   = ws + off; off += (size_t)L * MODES;
    float* tws_  = ws + off; off += (size_t)L * MODES;
    float* xmean = ws + off; off += (size_t)B * CIN;
    float* enc   = ws + off; off += BLD;
    float* bufA  = ws + off; off += BLD;
    float* bufB  = ws + off; off += BLD;
    float* bufC  = ws + off; off += BLD;   // bufC..bufH contiguous = 3*BLD = M_ROWS*KTRD (trend im2col)
    float* bufD  = ws + off; off += BLD;
    float* bufH  = ws + off; off += BLD;
    float* tacc  = ws + off; off += BLD;
    float* xf_re = ws + off; off += BHEM;
    float* xf_im = ws + off; off += BHEM;
    float* sel_re= ws + off; off += BHEM;
    float* sel_im= ws + off; off += BHEM;
    float* kf_re = ws + off; off += BHEM;
    float* kf_im = ws + off; off += BHEM;
    float* wp_enc  = ws + off; off += (size_t)D * KEMB;   // padded emb weights
    float* wp_dec  = ws + off; off += (size_t)D * KEMB;
    float* wp_trd  = ws + off; off += (size_t)64 * KTRD;  // padded+permuted trend weight (55->64 rows)
    float* wp_seas = ws + off; off += (size_t)64 * D;     // padded out_proj_w

    float* out       = (float*)d_out;
    float* dec_out   = out;                                   // B*L*COUT
    float* series_out= out + (size_t)B * L * COUT;            // 2*BHLL
    float* prior_out = series_out + 2 * BHLL;                 // 2*BHLL
    float* sigma_out = prior_out + 2 * BHLL;                  // 2*B*H*L

    const int BH = B * H;

    init_consts<<<200, 256, 0, stream>>>(pe, twc, tws_);
    xmean_kernel<<<cdiv(B * CIN, 256), 256, 0, stream>>>(x, xmean);
    pad_rows<<<cdiv(D * KEMB, 256), 256, 0, stream>>>(emb_enc_w, wp_enc, D, D, CIN * 3, KEMB);
    pad_rows<<<cdiv(D * KEMB, 256), 256, 0, stream>>>(emb_dec_w, wp_dec, D, D, CIN * 3, KEMB);
    pad_trend_w<<<cdiv(64 * KTRD, 256), 256, 0, stream>>>(dec_trend_w, wp_trd);
    pad_rows<<<cdiv(64 * D, 256), 256, 0, stream>>>(out_proj_w, wp_seas, COUT, 64, D, D);

    auto gemm = [&](const float* A, const float* W, const float* bias, const float* pe_, const float* rowb,
                    float* C, int N, int Nout, int K, int act, int accum) {
        dim3 grid(N / 64, M_ROWS / 64);
        gemm_bt<<<grid, 256, 0, stream>>>(A, W, bias, pe_, rowb, C, M_ROWS, N, Nout, K, act, accum);
    };

    // encoder embedding: im2col + GEMM (+pe fused)
    im2col_emb<<<cdiv(M_ROWS * KEMB, 256), 256, 0, stream>>>(x, nullptr, bufA);
    gemm(bufA, wp_enc, nullptr, pe, nullptr, enc, D, D, KEMB, 0, 0);

    for (int i = 0; i < 2; ++i) {
        const float* Wp = enc_proj_w + (size_t)i * 4 * D * D;
        const float* bp = enc_proj_b + (size_t)i * 4 * D;
        float* series_i = series_out + (size_t)i * BHLL;
        float* prior_i  = prior_out  + (size_t)i * BHLL;
        float* sigma_i  = sigma_out  + (size_t)i * B * H * L;

        gemm(enc, Wp,             bp,         nullptr, nullptr, bufA, D, D, D, 0, 0);   // q
        gemm(enc, Wp + D * D,     bp + D,     nullptr, nullptr, bufB, D, D, D, 0, 0);   // k
        dft_fwd<<<BH, 256, 0, stream>>>(bufA, twc, tws_, xf_re, xf_im);
        mode_gemm<<<BH, 256, 0, stream>>>(xf_re, xf_im, enc_four_wr, enc_four_wi, sel_re, sel_im);
        idft<<<BH, 256, 0, stream>>>(sel_re, sel_im, twc, tws_, bufC, 1.f / (float)L);
        gemm(bufC, Wp + 3 * D * D, bp + 3 * D, nullptr, nullptr, bufD, D, D, D, 0, 0);  // attn_out
        scores_kernel<<<BH, 256, 0, stream>>>(bufA, bufB, series_i);
        softmax_rows<<<B * H * L / 4, 256, 0, stream>>>(series_i, B * H * L);
        sigma_kernel<<<M_ROWS / 4, 256, 0, stream>>>(enc, enc_sig_w + (size_t)i * H * D,
                                                     enc_sig_b + (size_t)i * H, sigma_i);
        prior_kernel<<<cdiv((int)BHLL, 256), 256, 0, stream>>>(sigma_i, prior_i);
        decomp_kernel<<<B * (D / 64), 256, 0, stream>>>(enc, bufD, enc_dcmp_w + (size_t)(i * 2 + 0) * NK,
                                                        enc_dcmp_b + (size_t)(i * 2 + 0) * NK, bufH, nullptr, 0);
        gemm(bufH, enc_ffn_w1 + (size_t)i * DFF * D, nullptr, nullptr, nullptr, bufC, DFF, DFF, D, 1, 0);
        gemm(bufC, enc_ffn_w2 + (size_t)i * D * DFF, nullptr, nullptr, nullptr, bufD, D, D, DFF, 0, 0);
        decomp_kernel<<<B * (D / 64), 256, 0, stream>>>(bufH, bufD, enc_dcmp_w + (size_t)(i * 2 + 1) * NK,
                                                        enc_dcmp_b + (size_t)(i * 2 + 1) * NK, enc, nullptr, 0);
    }
    // encoder final my_layernorm
    ln_row<<<M_ROWS, 256, 0, stream>>>(enc, enc_norm_g, enc_norm_b, bufC);
    col_sub<<<cdiv(B * D, 256), 256, 0, stream>>>(bufC, enc);

    // ---------------- decoder ----------------
    im2col_emb<<<cdiv(M_ROWS * KEMB, 256), 256, 0, stream>>>(x, xmean, bufB);
    gemm(bufB, wp_dec, nullptr, pe, nullptr, bufA, D, D, KEMB, 0, 0);        // dec
    gemm(bufA, dec_proj_w, dec_proj_b, nullptr, nullptr, bufB, D, D, D, 0, 0); // q
    dft_fwd<<<BH, 256, 0, stream>>>(bufB, twc, tws_, xf_re, xf_im);
    mode_gemm<<<BH, 256, 0, stream>>>(xf_re, xf_im, dec_four_wr, dec_four_wi, sel_re, sel_im);
    idft<<<BH, 256, 0, stream>>>(sel_re, sel_im, twc, tws_, bufC, 1.f / (float)L);
    gemm(bufC, dec_proj_w + 3 * D * D, dec_proj_b + 3 * D, nullptr, nullptr, bufD, D, D, D, 0, 0); // sa
    decomp_kernel<<<B * (D / 64), 256, 0, stream>>>(bufA, bufD, dec_dcmp_w, dec_dcmp_b, bufH, tacc, 1); // h, t1

    gemm(bufH, crs_proj_w, crs_proj_b, nullptr, nullptr, bufB, D, D, D, 0, 0);   // qc
    dft_fwd<<<BH, 256, 0, stream>>>(bufB, twc, tws_, xf_re, xf_im);              // qf
    gemm(enc, crs_proj_w + D * D, crs_proj_b + D, nullptr, nullptr, bufB, D, D, D, 0, 0); // kc
    dft_fwd<<<BH, 256, 0, stream>>>(bufB, twc, tws_, kf_re, kf_im);              // kf
    fourier_cross_kernel<<<BH, 256, 0, stream>>>(xf_re, xf_im, kf_re, kf_im, crs_four_wr, crs_four_wi, sel_re, sel_im);
    idft<<<BH, 256, 0, stream>>>(sel_re, sel_im, twc, tws_, bufC, 1.f / ((float)L * (float)D * (float)D));
    gemm(bufC, crs_proj_w + 3 * D * D, crs_proj_b + 3 * D, nullptr, nullptr, bufD, D, D, D, 0, 0); // ca
    decomp_kernel<<<B * (D / 64), 256, 0, stream>>>(bufH, bufD, dec_dcmp_w + NK, dec_dcmp_b + NK, bufA, tacc, 2); // h2, t2

    gemm(bufA, dec_ffn_w1, nullptr, nullptr, nullptr, bufC, DFF, DFF, D, 1, 0);
    gemm(bufC, dec_ffn_w2, nullptr, nullptr, nullptr, bufD, D, D, DFF, 0, 0);
    decomp_kernel<<<B * (D / 64), 256, 0, stream>>>(bufA, bufD, dec_dcmp_w + 2 * NK, dec_dcmp_b + 2 * NK, bufB, tacc, 2); // h3, t3

    // trend conv as im2col + GEMM (trend_init xmean fused as rowbias); A2 = bufC..bufH (3*BLD)
    im2col_trend<<<cdiv((int)(M_ROWS * (size_t)KTRD), 256), 256, 0, stream>>>(tacc, bufC);
    gemm(bufC, wp_trd, nullptr, nullptr, xmean, dec_out, 64, COUT, KTRD, 0, 0);

    // final layernorm + seasonal projection accumulated into dec_out
    ln_row<<<M_ROWS, 256, 0, stream>>>(bufB, dec_norm_g, dec_norm_b, bufC);
    col_sub<<<cdiv(B * D, 256), 256, 0, stream>>>(bufC, bufD);
    gemm(bufD, wp_seas, out_proj_b, nullptr, nullptr, dec_out, 64, COUT, D, 0, 1);
}

// Round 4
// 2709.079 us; speedup vs baseline: 3.3946x; 2.0523x over previous
//
#include <hip/hip_runtime.h>
#include <cmath>

constexpr int B = 128, L = 100, CIN = 55, COUT = 55;
constexpr int D = 512, H = 8, DFF = 512, MODES = 32, E = 64;
constexpr int NK = 2;
constexpr int M_ROWS = B * L; // 12800
constexpr int KEMB = 192;     // 55*3=165 padded to 32*6
constexpr int KTRD = 1536;    // 512*3
constexpr size_t BLD  = (size_t)B * L * D;         // 6,553,600
constexpr size_t BHEM = (size_t)B * H * E * MODES; // 2,097,152 complex elems
constexpr size_t BHLL = (size_t)B * H * L * L;     // 10,240,000
constexpr float INV_SQRT_2PI = 0.3989422804014327f;

static inline int cdiv(int a, int b) { return (a + b - 1) / b; }

typedef short shortx8 __attribute__((ext_vector_type(8)));
typedef float f32x4 __attribute__((ext_vector_type(4)));

__device__ inline unsigned short f2bf(float f)
{
    unsigned int u = __float_as_uint(f);
    unsigned int r = (u + 0x7FFFu + ((u >> 16) & 1u)) >> 16;
    return (unsigned short)r;
}

// ---------------- constants: positional emb + DFT twiddles ----------------
__global__ void init_consts(float* __restrict__ pe, float* __restrict__ twc, float* __restrict__ tws)
{
    int idx = blockIdx.x * 256 + threadIdx.x;
    if (idx < L * D) {
        int l = idx / D, d = idx % D;
        int i2 = d & ~1;
        float div = expf((float)i2 * (-logf(10000.f) / (float)D));
        float ang = (float)l * div;
        pe[idx] = (d & 1) ? cosf(ang) : sinf(ang);
    }
    if (idx < L * MODES) {
        int t = idx / MODES, m = idx % MODES;
        float th = 2.f * 3.14159265358979323846f * (float)m * (float)t / (float)L;
        twc[idx] = cosf(th);
        tws[idx] = sinf(th);
    }
}

__global__ void xmean_kernel(const float* __restrict__ x, float* __restrict__ xm)
{
    int idx = blockIdx.x * 256 + threadIdx.x;
    if (idx >= B * CIN) return;
    int b = idx / CIN, c = idx % CIN;
    float s = 0.f;
    for (int l = 0; l < L; ++l) s += x[((size_t)b * L + l) * CIN + c];
    xm[idx] = s * (1.f / (float)L);
}

// pad src (rows_src x k_src) into dst (rows_dst x k_dst), zero-filled
__global__ void pad_rows(const float* __restrict__ src, float* __restrict__ dst,
                         int rows_src, int rows_dst, int k_src, int k_dst)
{
    int idx = blockIdx.x * 256 + threadIdx.x;
    if (idx >= rows_dst * k_dst) return;
    int r = idx / k_dst, k = idx % k_dst;
    dst[idx] = (r < rows_src && k < k_src) ? src[(size_t)r * k_src + k] : 0.f;
}

// trend weight: src (COUT,D,3) flat o*1536+d*3+j  ->  dst[o][j*D+d], rows padded to 64
__global__ void pad_trend_w(const float* __restrict__ src, float* __restrict__ dst)
{
    int idx = blockIdx.x * 256 + threadIdx.x;
    if (idx >= 64 * KTRD) return;
    int o = idx / KTRD, k = idx % KTRD;
    int j = k / D, d = k % D;
    dst[idx] = (o < COUT) ? src[(size_t)o * KTRD + d * 3 + j] : 0.f;
}

// Fourier weight transpose: wt[((h*M+m)*E + e)*E + o] = {wr,wi}[((h*E+e)*E+o)*M + m]
__global__ __launch_bounds__(256) void transpose_w(const float* __restrict__ wr, const float* __restrict__ wi,
                                                   float2* __restrict__ wt)
{
    int h = blockIdx.x / E, e = blockIdx.x % E;
    __shared__ float tr[64][33], ti[64][33];
    for (int i = threadIdx.x; i < E * MODES; i += 256) {
        int o = i / MODES, m = i % MODES;
        size_t s = (((size_t)h * E + e) * E + o) * MODES + m;
        tr[o][m] = wr[s]; ti[o][m] = wi[s];
    }
    __syncthreads();
    for (int i = threadIdx.x; i < MODES * E; i += 256) {
        int m = i / E, o = i % E;
        wt[(((size_t)h * MODES + m) * E + e) * E + o] = make_float2(tr[o][m], ti[o][m]);
    }
}

// im2col for kernel-3 circular conv on (B,L,CIN): A2[m][k], k=c*3+j, padded to KEMB
__global__ void im2col_emb(const float* __restrict__ x, const float* __restrict__ xmean,
                           float* __restrict__ A2)
{
    int idx = blockIdx.x * 256 + threadIdx.x;
    if (idx >= M_ROWS * KEMB) return;
    int k = idx % KEMB, m = idx / KEMB;
    float v = 0.f;
    if (k < CIN * 3) {
        int c = k / 3, j = k % 3;
        int l = m % L, b = m / L;
        int ls = l + j - 1; ls = (ls + L) % L;
        v = x[((size_t)b * L + ls) * CIN + c];
        if (xmean) v -= xmean[(size_t)b * CIN + c];
    }
    A2[idx] = v;
}

// im2col for trend conv: A2[m][k], k=j*512+d
__global__ void im2col_trend(const float* __restrict__ t, float* __restrict__ A2)
{
    int idx = blockIdx.x * 256 + threadIdx.x;
    if (idx >= (int)(M_ROWS * (size_t)KTRD)) return;
    int k = idx % KTRD, m = idx / KTRD;
    int j = k / D, d = k % D;
    int l = m % L, b = m / L;
    int ls = l + j - 1; ls = (ls + L) % L;
    A2[idx] = t[((size_t)b * L + ls) * D + d];
}

// ---------------- bf16 MFMA GEMM: C[m,n<Nout] = sum_k A[m,k]*W[n,k] (+bias)(+pe[r%L])(+rowbias[r/L]) ----------------
// tile 128x64, 4 waves (2x2), wave = 64x32 via 4x2 frags of 16x16, K-step 32
__global__ __launch_bounds__(256) void gemm_mfma(const float* __restrict__ A, const float* __restrict__ W,
                                                 const float* __restrict__ bias, const float* __restrict__ pe,
                                                 const float* __restrict__ rowbias, float* __restrict__ C,
                                                 int Nout, int K, int act, int accum)
{
    __shared__ unsigned short As[128][40];
    __shared__ unsigned short Bs[64][40];
    int tid = threadIdx.x;
    int row0 = blockIdx.y * 128, col0 = blockIdx.x * 64;
    int wid = tid >> 6, lane = tid & 63;
    int wm = wid >> 1, wn = wid & 1;
    int lrow = lane & 15, kg = lane >> 4;
    f32x4 acc[4][2] = {};
    int sr = tid >> 3, sc4 = (tid & 7) * 4;
    for (int k0 = 0; k0 < K; k0 += 32) {
#pragma unroll
        for (int p = 0; p < 4; ++p) {
            float4 v = *(const float4*)&A[(size_t)(row0 + p * 32 + sr) * K + k0 + sc4];
            ushort4 hh;
            hh.x = f2bf(v.x); hh.y = f2bf(v.y); hh.z = f2bf(v.z); hh.w = f2bf(v.w);
            *(ushort4*)&As[p * 32 + sr][sc4] = hh;
        }
#pragma unroll
        for (int p = 0; p < 2; ++p) {
            float4 v = *(const float4*)&W[(size_t)(col0 + p * 32 + sr) * K + k0 + sc4];
            ushort4 hh;
            hh.x = f2bf(v.x); hh.y = f2bf(v.y); hh.z = f2bf(v.z); hh.w = f2bf(v.w);
            *(ushort4*)&Bs[p * 32 + sr][sc4] = hh;
        }
        __syncthreads();
        shortx8 av[4], bv[2];
#pragma unroll
        for (int mi = 0; mi < 4; ++mi)
            av[mi] = *(const shortx8*)&As[wm * 64 + mi * 16 + lrow][kg * 8];
#pragma unroll
        for (int ni = 0; ni < 2; ++ni)
            bv[ni] = *(const shortx8*)&Bs[wn * 32 + ni * 16 + lrow][kg * 8];
#pragma unroll
        for (int mi = 0; mi < 4; ++mi)
#pragma unroll
            for (int ni = 0; ni < 2; ++ni)
                acc[mi][ni] = __builtin_amdgcn_mfma_f32_16x16x32_bf16(av[mi], bv[ni], acc[mi][ni], 0, 0, 0);
        __syncthreads();
    }
#pragma unroll
    for (int mi = 0; mi < 4; ++mi) {
#pragma unroll
        for (int ni = 0; ni < 2; ++ni) {
            int col = col0 + wn * 32 + ni * 16 + lrow;
            if (col >= Nout) continue;
#pragma unroll
            for (int r = 0; r < 4; ++r) {
                int row = row0 + wm * 64 + mi * 16 + kg * 4 + r;
                float v = acc[mi][ni][r];
                if (bias) v += bias[col];
                if (pe) v += pe[(size_t)(row % L) * Nout + col];
                if (rowbias) v += rowbias[(size_t)(row / L) * Nout + col];
                if (act) v = 0.5f * v * (1.f + erff(v * 0.70710678118654752f));
                size_t o = (size_t)row * Nout + col;
                if (accum) C[o] += v; else C[o] = v;
            }
        }
    }
}

// ---------------- forward DFT: X (B,L,D) head-sliced -> xf (H,MODES,B,E) float2 ----------------
__global__ __launch_bounds__(256) void dft_fwd(const float* __restrict__ X,
                                               const float* __restrict__ twc, const float* __restrict__ tws,
                                               float2* __restrict__ xf)
{
    int b = blockIdx.x / H, h = blockIdx.x % H;
    __shared__ float xs[L][E];
    __shared__ float c[L][MODES], s[L][MODES];
    for (int i = threadIdx.x; i < L * E; i += 256) {
        int t = i / E, e = i % E;
        xs[t][e] = X[((size_t)b * L + t) * D + h * E + e];
    }
    for (int i = threadIdx.x; i < L * MODES; i += 256) { c[i / MODES][i % MODES] = twc[i]; s[i / MODES][i % MODES] = tws[i]; }
    __syncthreads();
    for (int o = threadIdx.x; o < E * MODES; o += 256) {
        int m = o / E, e = o % E;
        float re = 0.f, im = 0.f;
        for (int t = 0; t < L; ++t) {
            float v = xs[t][e];
            re += v * c[t][m];
            im -= v * s[t][m];
        }
        xf[((size_t)(h * MODES + m) * B + b) * E + e] = make_float2(re, im);
    }
}

// ---------------- per-(h,m) complex GEMM, in place: X[b][o] = sum_e X[b][e]*W[e][o] ----------------
__global__ __launch_bounds__(256) void mode_gemm2(float2* __restrict__ xf, const float2* __restrict__ wt)
{
    int hm = blockIdx.x;
    int bt = blockIdx.y;
    __shared__ float2 Wc[E][E];
    __shared__ float2 Ac[32][E];
    for (int i = threadIdx.x; i < E * E; i += 256) Wc[i / E][i % E] = wt[(size_t)hm * (E * E) + i];
    for (int i = threadIdx.x; i < 32 * E; i += 256)
        Ac[i / E][i % E] = xf[((size_t)hm * B + bt * 32 + i / E) * E + i % E];
    __syncthreads();
    int o = threadIdx.x & 63, bb = threadIdx.x >> 6;
    float2 acc[8];
#pragma unroll
    for (int j = 0; j < 8; ++j) acc[j] = make_float2(0.f, 0.f);
    for (int e = 0; e < E; ++e) {
        float2 w = Wc[e][o];
#pragma unroll
        for (int j = 0; j < 8; ++j) {
            float2 a = Ac[bb * 8 + j][e];
            acc[j].x += a.x * w.x - a.y * w.y;
            acc[j].y += a.x * w.y + a.y * w.x;
        }
    }
#pragma unroll
    for (int j = 0; j < 8; ++j)
        xf[((size_t)hm * B + bt * 32 + bb * 8 + j) * E + o] = acc[j];
}

// iDFT: sel (H,MODES,B,E) float2 -> out (B,L,D) head-sliced, scaled (DC imag ignored)
__global__ __launch_bounds__(256) void idft(const float2* __restrict__ sel,
                                            const float* __restrict__ twc, const float* __restrict__ tws,
                                            float* __restrict__ out, float scale)
{
    int b = blockIdx.x / H, h = blockIdx.x % H;
    __shared__ float2 sc[MODES][E];
    __shared__ float c[L][MODES], s[L][MODES];
    for (int i = threadIdx.x; i < MODES * E; i += 256) {
        int m = i / E, e = i % E;
        sc[m][e] = sel[((size_t)(h * MODES + m) * B + b) * E + e];
    }
    for (int i = threadIdx.x; i < L * MODES; i += 256) { c[i / MODES][i % MODES] = twc[i]; s[i / MODES][i % MODES] = tws[i]; }
    __syncthreads();
    for (int o = threadIdx.x; o < L * E; o += 256) {
        int t = o / E, e = o % E;
        float acc = sc[0][e].x;
        for (int m = 1; m < MODES; ++m)
            acc += 2.f * (sc[m][e].x * c[t][m] - sc[m][e].y * s[t][m]);
        out[((size_t)b * L + t) * D + h * E + e] = acc * scale;
    }
}

// FourierCross steps 1-2: qk = ctanh(qf^T kf), qkv = qk * kf; writes qkv over kf (same layout)
__global__ __launch_bounds__(256) void fourier_qk(const float2* __restrict__ qf, float2* __restrict__ kf)
{
    int b = blockIdx.x / H, h = blockIdx.x % H;
    __shared__ float2 qm[MODES][E + 1], km[MODES][E + 1], vm[MODES][E + 1];
    __shared__ float tr[MODES][MODES + 1], ti[MODES][MODES + 1];
    for (int i = threadIdx.x; i < MODES * E; i += 256) {
        int m = i / E, e = i % E;
        size_t idx = ((size_t)(h * MODES + m) * B + b) * E + e;
        qm[m][e] = qf[idx];
        km[m][e] = kf[idx];
    }
    __syncthreads();
    for (int i = threadIdx.x; i < MODES * MODES; i += 256) {
        int x = i / MODES, y = i % MODES;
        float re = 0.f, im = 0.f;
        for (int e = 0; e < E; ++e) {
            float2 a = qm[x][e], k2 = km[y][e];
            re += a.x * k2.x - a.y * k2.y;
            im += a.x * k2.y + a.y * k2.x;
        }
        float aa = fminf(fmaxf(2.f * re, -30.f), 30.f);
        float b2 = 2.f * im;
        float den = coshf(aa) + cosf(b2);
        tr[x][y] = sinhf(aa) / den;
        ti[x][y] = sinf(b2) / den;
    }
    __syncthreads();
    for (int i = threadIdx.x; i < MODES * E; i += 256) {
        int x = i / E, e = i % E;
        float re = 0.f, im = 0.f;
        for (int y = 0; y < MODES; ++y) {
            float ar = tr[x][y], ai = ti[x][y];
            float2 kk = km[y][e];
            re += ar * kk.x - ai * kk.y;
            im += ar * kk.y + ai * kk.x;
        }
        vm[x][e] = make_float2(re, im);
    }
    __syncthreads();
    for (int i = threadIdx.x; i < MODES * E; i += 256) {
        int m = i / E, e = i % E;
        kf[((size_t)(h * MODES + m) * B + b) * E + e] = vm[m][e];
    }
}

// scores[b,h,l,s] = (1/8) sum_e q[b,l,h,e]*k[b,s,h,e]
__global__ __launch_bounds__(256) void scores_kernel(const float* __restrict__ Q, const float* __restrict__ Kk,
                                                     float* __restrict__ out)
{
    int b = blockIdx.x / H, h = blockIdx.x % H;
    __shared__ float qs[L][E + 1], ks[L][E + 1];
    for (int i = threadIdx.x; i < L * E; i += 256) {
        int t = i / E, e = i % E;
        qs[t][e] = Q[((size_t)b * L + t) * D + h * E + e];
        ks[t][e] = Kk[((size_t)b * L + t) * D + h * E + e];
    }
    __syncthreads();
    for (int o = threadIdx.x; o < L * L; o += 256) {
        int l = o / L, ss = o % L;
        float acc = 0.f;
        for (int e = 0; e < E; ++e) acc += qs[l][e] * ks[ss][e];
        out[(((size_t)b * H + h) * L + l) * L + ss] = acc * 0.125f;
    }
}

__global__ __launch_bounds__(256) void softmax_rows(float* __restrict__ data, int nrows)
{
    int row = blockIdx.x * 4 + threadIdx.x / 64;
    int lane = threadIdx.x % 64;
    if (row >= nrows) return;
    float* p = data + (size_t)row * L;
    float v0 = (lane < L) ? p[lane] : -1e30f;
    float v1 = (lane + 64 < L) ? p[lane + 64] : -1e30f;
    float mx = fmaxf(v0, v1);
    for (int off = 32; off; off >>= 1) mx = fmaxf(mx, __shfl_xor(mx, off));
    float e0 = (lane < L) ? expf(v0 - mx) : 0.f;
    float e1 = (lane + 64 < L) ? expf(v1 - mx) : 0.f;
    float sum = e0 + e1;
    for (int off = 32; off; off >>= 1) sum += __shfl_xor(sum, off);
    float inv = 1.f / sum;
    if (lane < L) p[lane] = e0 * inv;
    if (lane + 64 < L) p[lane + 64] = e1 * inv;
}

// sigma: (B,H,L) = 3^(sigmoid(5*(enc@w.T+b))+1e-5)-1, stored transposed. One wave per row.
__global__ __launch_bounds__(256) void sigma_kernel(const float* __restrict__ enc, const float* __restrict__ w,
                                                    const float* __restrict__ bias, float* __restrict__ sig_out)
{
    __shared__ float wsh[H][D];
    for (int i = threadIdx.x; i < H * D; i += 256) wsh[i / D][i % D] = w[i];
    __syncthreads();
    int wid = threadIdx.x / 64, lane = threadIdx.x % 64;
    int row = blockIdx.x * 4 + wid;
    const float* p = enc + (size_t)row * D;
    float xv[8];
#pragma unroll
    for (int i = 0; i < 8; ++i) xv[i] = p[lane + i * 64];
    int b = row / L, l = row % L;
#pragma unroll
    for (int h = 0; h < H; ++h) {
        float s = 0.f;
#pragma unroll
        for (int i = 0; i < 8; ++i) s += xv[i] * wsh[h][lane + i * 64];
        for (int off = 32; off; off >>= 1) s += __shfl_xor(s, off);
        if (lane == 0) {
            float acc = s + bias[h];
            float sg = 1.f / (1.f + expf(-5.f * acc));
            float val = expf((sg + 1e-5f) * 1.0986122886681098f) - 1.f; // 3^u - 1
            sig_out[((size_t)b * H + h) * L + l] = val;
        }
    }
}

__global__ void prior_kernel(const float* __restrict__ sig, float* __restrict__ prior)
{
    int idx = blockIdx.x * 256 + threadIdx.x;
    if (idx >= (int)(B * H * L * L)) return;
    int s = idx % L; int l = (idx / L) % L; int bh = idx / (L * L);
    float sg = sig[(size_t)bh * L + l];
    float d = (float)abs(l - s);
    prior[idx] = expf(-d * d / (2.f * sg * sg)) * INV_SQRT_2PI / sg;
}

// series_decomp_multi: res = x - mean; tmode: 0 none, 1 trend = mean, 2 trend += mean
__global__ __launch_bounds__(256) void decomp_kernel(const float* __restrict__ in1, const float* __restrict__ in2,
                                                     const float* __restrict__ w, const float* __restrict__ bc,
                                                     float* __restrict__ res, float* __restrict__ trend, int tmode)
{
    int b = blockIdx.x / (D / 64);
    int d0 = (blockIdx.x % (D / 64)) * 64;
    __shared__ float xs[L][64];
    for (int i = threadIdx.x; i < L * 64; i += 256) {
        int t = i / 64, dd = i % 64;
        size_t g = ((size_t)b * L + t) * D + d0 + dd;
        float v = in1[g];
        if (in2) v += in2[g];
        xs[t][dd] = v;
    }
    __syncthreads();
    float w0 = w[0], w1 = w[1], b0 = bc[0], b1 = bc[1];
    for (int i = threadIdx.x; i < L * 64; i += 256) {
        int l = i / 64, dd = i % 64;
        float s12 = 0.f;
        for (int j = l - 5; j <= l + 6; ++j) s12 += xs[min(max(j, 0), L - 1)][dd];
        float s24 = 0.f;
        for (int j = l - 11; j <= l + 12; ++j) s24 += xs[min(max(j, 0), L - 1)][dd];
        float m0 = s12 * (1.f / 12.f), m1 = s24 * (1.f / 24.f);
        float x = xs[l][dd];
        float z0 = x * w0 + b0, z1 = x * w1 + b1;
        float zm = fmaxf(z0, z1);
        float e0 = expf(z0 - zm), e1 = expf(z1 - zm);
        float p0 = e0 / (e0 + e1);
        float mean = m0 * p0 + m1 * (1.f - p0);
        size_t g = ((size_t)b * L + l) * D + d0 + dd;
        res[g] = x - mean;
        if (tmode == 1) trend[g] = mean;
        else if (tmode == 2) trend[g] += mean;
    }
}

__global__ __launch_bounds__(256) void ln_row(const float* __restrict__ x, const float* __restrict__ g,
                                              const float* __restrict__ bb, float* __restrict__ out)
{
    int row = blockIdx.x;
    const float* p = x + (size_t)row * D;
    float s = 0.f, s2 = 0.f;
    for (int d = threadIdx.x; d < D; d += 256) { float v = p[d]; s += v; s2 += v * v; }
    for (int off = 32; off; off >>= 1) { s += __shfl_xor(s, off); s2 += __shfl_xor(s2, off); }
    __shared__ float red[8];
    int wid = threadIdx.x / 64, lane = threadIdx.x % 64;
    if (lane == 0) { red[wid] = s; red[4 + wid] = s2; }
    __syncthreads();
    if (threadIdx.x == 0) {
        red[0] = red[0] + red[1] + red[2] + red[3];
        red[4] = red[4] + red[5] + red[6] + red[7];
    }
    __syncthreads();
    float mu = red[0] / (float)D;
    float var = red[4] / (float)D - mu * mu;
    float rstd = rsqrtf(var + 1e-5f);
    for (int d = threadIdx.x; d < D; d += 256)
        out[(size_t)row * D + d] = (p[d] - mu) * rstd * g[d] + bb[d];
}

__global__ void col_sub(const float* __restrict__ xh, float* __restrict__ out)
{
    int idx = blockIdx.x * 256 + threadIdx.x;
    if (idx >= B * D) return;
    int b = idx / D, d = idx % D;
    float s = 0.f;
    for (int l = 0; l < L; ++l) s += xh[((size_t)b * L + l) * D + d];
    s *= (1.f / (float)L);
    for (int l = 0; l < L; ++l) {
        size_t g = ((size_t)b * L + l) * D + d;
        out[g] = xh[g] - s;
    }
}

extern "C" void kernel_launch(void* const* d_in, const int* in_sizes, int n_in,
                              void* d_out, int out_size, void* d_ws, size_t ws_size,
                              hipStream_t stream)
{
    const float* x           = (const float*)d_in[0];
    const float* emb_enc_w   = (const float*)d_in[1];
    const float* emb_dec_w   = (const float*)d_in[2];
    const float* enc_proj_w  = (const float*)d_in[3];
    const float* enc_proj_b  = (const float*)d_in[4];
    const float* enc_sig_w   = (const float*)d_in[5];
    const float* enc_sig_b   = (const float*)d_in[6];
    const float* enc_four_wr = (const float*)d_in[7];
    const float* enc_four_wi = (const float*)d_in[8];
    const float* enc_ffn_w1  = (const float*)d_in[9];
    const float* enc_ffn_w2  = (const float*)d_in[10];
    const float* enc_dcmp_w  = (const float*)d_in[11];
    const float* enc_dcmp_b  = (const float*)d_in[12];
    const float* enc_norm_g  = (const float*)d_in[13];
    const float* enc_norm_b  = (const float*)d_in[14];
    const float* dec_proj_w  = (const float*)d_in[15];
    const float* dec_proj_b  = (const float*)d_in[16];
    const float* dec_four_wr = (const float*)d_in[17];
    const float* dec_four_wi = (const float*)d_in[18];
    const float* crs_proj_w  = (const float*)d_in[19];
    const float* crs_proj_b  = (const float*)d_in[20];
    const float* crs_four_wr = (const float*)d_in[21];
    const float* crs_four_wi = (const float*)d_in[22];
    const float* dec_ffn_w1  = (const float*)d_in[23];
    const float* dec_ffn_w2  = (const float*)d_in[24];
    const float* dec_dcmp_w  = (const float*)d_in[25];
    const float* dec_dcmp_b  = (const float*)d_in[26];
    const float* dec_trend_w = (const float*)d_in[27];
    const float* dec_norm_g  = (const float*)d_in[28];
    const float* dec_norm_b  = (const float*)d_in[29];
    const float* out_proj_w  = (const float*)d_in[30];
    const float* out_proj_b  = (const float*)d_in[31];

    float* ws = (float*)d_ws;
    size_t off = 0;
    float* pe    = ws + off; off += (size_t)L * D;
    float* twc   = ws + off; off += (size_t)L * MODES;
    float* tws_  = ws + off; off += (size_t)L * MODES;
    float* xmean = ws + off; off += (size_t)B * CIN;
    float* enc   = ws + off; off += BLD;
    float* bufA  = ws + off; off += BLD;
    float* bufB  = ws + off; off += BLD;
    float* bufC  = ws + off; off += BLD;   // bufC..bufH contiguous = 3*BLD = M_ROWS*KTRD (trend im2col)
    float* bufD  = ws + off; off += BLD;
    float* bufH  = ws + off; off += BLD;
    float* tacc  = ws + off; off += BLD;
    float2* xfc  = (float2*)(ws + off); off += 2 * BHEM;   // (H,MODES,B,E) complex
    float2* kfc  = (float2*)(ws + off); off += 2 * BHEM;
    float2* wtb  = (float2*)(ws + off); off += 2 * (size_t)H * MODES * E * E / 1; // 2,097,152 floats
    float* wp_enc  = ws + off; off += (size_t)D * KEMB;
    float* wp_dec  = ws + off; off += (size_t)D * KEMB;
    float* wp_trd  = ws + off; off += (size_t)64 * KTRD;
    float* wp_seas = ws + off; off += (size_t)64 * D;

    float* out       = (float*)d_out;
    float* dec_out   = out;                                   // B*L*COUT
    float* series_out= out + (size_t)B * L * COUT;            // 2*BHLL
    float* prior_out = series_out + 2 * BHLL;                 // 2*BHLL
    float* sigma_out = prior_out + 2 * BHLL;                  // 2*B*H*L

    const int BH = B * H;

    init_consts<<<200, 256, 0, stream>>>(pe, twc, tws_);
    xmean_kernel<<<cdiv(B * CIN, 256), 256, 0, stream>>>(x, xmean);
    pad_rows<<<cdiv(D * KEMB, 256), 256, 0, stream>>>(emb_enc_w, wp_enc, D, D, CIN * 3, KEMB);
    pad_rows<<<cdiv(D * KEMB, 256), 256, 0, stream>>>(emb_dec_w, wp_dec, D, D, CIN * 3, KEMB);
    pad_trend_w<<<cdiv(64 * KTRD, 256), 256, 0, stream>>>(dec_trend_w, wp_trd);
    pad_rows<<<cdiv(64 * D, 256), 256, 0, stream>>>(out_proj_w, wp_seas, COUT, 64, D, D);
    transpose_w<<<H * E, 256, 0, stream>>>(enc_four_wr, enc_four_wi, wtb);

    auto gemm = [&](const float* A, const float* W, const float* bias, const float* pe_, const float* rowb,
                    float* C, int N, int Nout, int K, int act, int accum) {
        dim3 grid(N / 64, M_ROWS / 128);
        gemm_mfma<<<grid, 256, 0, stream>>>(A, W, bias, pe_, rowb, C, Nout, K, act, accum);
    };
    dim3 mg_grid(H * MODES, B / 32);

    // encoder embedding: im2col + GEMM (+pe fused)
    im2col_emb<<<cdiv(M_ROWS * KEMB, 256), 256, 0, stream>>>(x, nullptr, bufA);
    gemm(bufA, wp_enc, nullptr, pe, nullptr, enc, D, D, KEMB, 0, 0);

    for (int i = 0; i < 2; ++i) {
        const float* Wp = enc_proj_w + (size_t)i * 4 * D * D;
        const float* bp = enc_proj_b + (size_t)i * 4 * D;
        float* series_i = series_out + (size_t)i * BHLL;
        float* prior_i  = prior_out  + (size_t)i * BHLL;
        float* sigma_i  = sigma_out  + (size_t)i * B * H * L;

        gemm(enc, Wp,             bp,         nullptr, nullptr, bufA, D, D, D, 0, 0);   // q
        gemm(enc, Wp + D * D,     bp + D,     nullptr, nullptr, bufB, D, D, D, 0, 0);   // k
        dft_fwd<<<BH, 256, 0, stream>>>(bufA, twc, tws_, xfc);
        mode_gemm2<<<mg_grid, 256, 0, stream>>>(xfc, wtb);
        idft<<<BH, 256, 0, stream>>>(xfc, twc, tws_, bufC, 1.f / (float)L);
        gemm(bufC, Wp + 3 * D * D, bp + 3 * D, nullptr, nullptr, bufD, D, D, D, 0, 0);  // attn_out
        scores_kernel<<<BH, 256, 0, stream>>>(bufA, bufB, series_i);
        softmax_rows<<<B * H * L / 4, 256, 0, stream>>>(series_i, B * H * L);
        sigma_kernel<<<M_ROWS / 4, 256, 0, stream>>>(enc, enc_sig_w + (size_t)i * H * D,
                                                     enc_sig_b + (size_t)i * H, sigma_i);
        prior_kernel<<<cdiv((int)BHLL, 256), 256, 0, stream>>>(sigma_i, prior_i);
        decomp_kernel<<<B * (D / 64), 256, 0, stream>>>(enc, bufD, enc_dcmp_w + (size_t)(i * 2 + 0) * NK,
                                                        enc_dcmp_b + (size_t)(i * 2 + 0) * NK, bufH, nullptr, 0);
        gemm(bufH, enc_ffn_w1 + (size_t)i * DFF * D, nullptr, nullptr, nullptr, bufC, DFF, DFF, D, 1, 0);
        gemm(bufC, enc_ffn_w2 + (size_t)i * D * DFF, nullptr, nullptr, nullptr, bufD, D, D, DFF, 0, 0);
        decomp_kernel<<<B * (D / 64), 256, 0, stream>>>(bufH, bufD, enc_dcmp_w + (size_t)(i * 2 + 1) * NK,
                                                        enc_dcmp_b + (size_t)(i * 2 + 1) * NK, enc, nullptr, 0);
    }
    // encoder final my_layernorm
    ln_row<<<M_ROWS, 256, 0, stream>>>(enc, enc_norm_g, enc_norm_b, bufC);
    col_sub<<<cdiv(B * D, 256), 256, 0, stream>>>(bufC, enc);

    // ---------------- decoder ----------------
    transpose_w<<<H * E, 256, 0, stream>>>(dec_four_wr, dec_four_wi, wtb);
    im2col_emb<<<cdiv(M_ROWS * KEMB, 256), 256, 0, stream>>>(x, xmean, bufB);
    gemm(bufB, wp_dec, nullptr, pe, nullptr, bufA, D, D, KEMB, 0, 0);          // dec
    gemm(bufA, dec_proj_w, dec_proj_b, nullptr, nullptr, bufB, D, D, D, 0, 0); // q
    dft_fwd<<<BH, 256, 0, stream>>>(bufB, twc, tws_, xfc);
    mode_gemm2<<<mg_grid, 256, 0, stream>>>(xfc, wtb);
    idft<<<BH, 256, 0, stream>>>(xfc, twc, tws_, bufC, 1.f / (float)L);
    gemm(bufC, dec_proj_w + 3 * D * D, dec_proj_b + 3 * D, nullptr, nullptr, bufD, D, D, D, 0, 0); // sa
    decomp_kernel<<<B * (D / 64), 256, 0, stream>>>(bufA, bufD, dec_dcmp_w, dec_dcmp_b, bufH, tacc, 1); // h, t1

    gemm(bufH, crs_proj_w, crs_proj_b, nullptr, nullptr, bufB, D, D, D, 0, 0);   // qc
    dft_fwd<<<BH, 256, 0, stream>>>(bufB, twc, tws_, xfc);                       // qf
    gemm(enc, crs_proj_w + D * D, crs_proj_b + D, nullptr, nullptr, bufB, D, D, D, 0, 0); // kc
    dft_fwd<<<BH, 256, 0, stream>>>(bufB, twc, tws_, kfc);                       // kf
    transpose_w<<<H * E, 256, 0, stream>>>(crs_four_wr, crs_four_wi, (float2*)enc); // enc is dead now
    fourier_qk<<<BH, 256, 0, stream>>>(xfc, kfc);                                // kfc := qkv
    mode_gemm2<<<mg_grid, 256, 0, stream>>>(kfc, (float2*)enc);
    idft<<<BH, 256, 0, stream>>>(kfc, twc, tws_, bufC, 1.f / ((float)L * (float)D * (float)D));
    gemm(bufC, crs_proj_w + 3 * D * D, crs_proj_b + 3 * D, nullptr, nullptr, bufD, D, D, D, 0, 0); // ca
    decomp_kernel<<<B * (D / 64), 256, 0, stream>>>(bufH, bufD, dec_dcmp_w + NK, dec_dcmp_b + NK, bufA, tacc, 2); // h2, t2

    gemm(bufA, dec_ffn_w1, nullptr, nullptr, nullptr, bufC, DFF, DFF, D, 1, 0);
    gemm(bufC, dec_ffn_w2, nullptr, nullptr, nullptr, bufD, D, D, DFF, 0, 0);
    decomp_kernel<<<B * (D / 64), 256, 0, stream>>>(bufA, bufD, dec_dcmp_w + 2 * NK, dec_dcmp_b + 2 * NK, bufB, tacc, 2); // h3, t3

    // trend conv as im2col + GEMM (trend_init xmean fused as rowbias); A2 = bufC..bufH (3*BLD)
    im2col_trend<<<cdiv((int)(M_ROWS * (size_t)KTRD), 256), 256, 0, stream>>>(tacc, bufC);
    gemm(bufC, wp_trd, nullptr, nullptr, xmean, dec_out, 64, COUT, KTRD, 0, 0);

    // final layernorm + seasonal projection accumulated into dec_out
    ln_row<<<M_ROWS, 256, 0, stream>>>(bufB, dec_norm_g, dec_norm_b, bufC);
    col_sub<<<cdiv(B * D, 256), 256, 0, stream>>>(bufC, bufD);
    gemm(bufD, wp_seas, out_proj_b, nullptr, nullptr, dec_out, 64, COUT, D, 0, 1);
}

// Round 5
// 2223.070 us; speedup vs baseline: 4.1367x; 1.2186x over previous
//
#include <hip/hip_runtime.h>
#include <cmath>

constexpr int B = 128, L = 100, CIN = 55, COUT = 55;
constexpr int D = 512, H = 8, DFF = 512, MODES = 32, E = 64;
constexpr int NK = 2;
constexpr int M_ROWS = B * L; // 12800
constexpr int KEMB = 192;     // 55*3=165 padded to 32*6
constexpr size_t BLD  = (size_t)B * L * D;         // 6,553,600
constexpr size_t BHEM = (size_t)B * H * E * MODES; // 2,097,152 complex elems
constexpr size_t BHLL = (size_t)B * H * L * L;     // 10,240,000
constexpr float INV_SQRT_2PI = 0.3989422804014327f;

static inline int cdiv(int a, int b) { return (a + b - 1) / b; }

typedef short shortx8 __attribute__((ext_vector_type(8)));
typedef float f32x4 __attribute__((ext_vector_type(4)));

__device__ inline unsigned short f2bf(float f)
{
    unsigned int u = __float_as_uint(f);
    unsigned int r = (u + 0x7FFFu + ((u >> 16) & 1u)) >> 16;
    return (unsigned short)r;
}

// ---------------- constants: positional emb + DFT twiddles ----------------
__global__ void init_consts(float* __restrict__ pe, float* __restrict__ twc, float* __restrict__ tws)
{
    int idx = blockIdx.x * 256 + threadIdx.x;
    if (idx < L * D) {
        int l = idx / D, d = idx % D;
        int i2 = d & ~1;
        float div = expf((float)i2 * (-logf(10000.f) / (float)D));
        float ang = (float)l * div;
        pe[idx] = (d & 1) ? cosf(ang) : sinf(ang);
    }
    if (idx < L * MODES) {
        int t = idx / MODES, m = idx % MODES;
        float th = 2.f * 3.14159265358979323846f * (float)m * (float)t / (float)L;
        twc[idx] = cosf(th);
        tws[idx] = sinf(th);
    }
}

__global__ void xmean_kernel(const float* __restrict__ x, float* __restrict__ xm)
{
    int idx = blockIdx.x * 256 + threadIdx.x;
    if (idx >= B * CIN) return;
    int b = idx / CIN, c = idx % CIN;
    float s = 0.f;
    for (int l = 0; l < L; ++l) s += x[((size_t)b * L + l) * CIN + c];
    xm[idx] = s * (1.f / (float)L);
}

// pad src (rows_src x k_src) into dst (rows_dst x k_dst), zero-filled
__global__ void pad_rows(const float* __restrict__ src, float* __restrict__ dst,
                         int rows_src, int rows_dst, int k_src, int k_dst)
{
    int idx = blockIdx.x * 256 + threadIdx.x;
    if (idx >= rows_dst * k_dst) return;
    int r = idx / k_dst, k = idx % k_dst;
    dst[idx] = (r < rows_src && k < k_src) ? src[(size_t)r * k_src + k] : 0.f;
}

// trend weight reshaped for stacked-tap GEMM: dst[(j*64+o)][d] = W[o,d,j] (o>=COUT -> 0)
__global__ void pad_trend_w2(const float* __restrict__ src, float* __restrict__ dst)
{
    int idx = blockIdx.x * 256 + threadIdx.x;
    if (idx >= 192 * D) return;
    int n = idx / D, d = idx % D;
    int j = n / 64, o = n % 64;
    dst[idx] = (o < COUT) ? src[(size_t)o * (D * 3) + d * 3 + j] : 0.f;
}

// Fourier weight transpose: wt[((h*M+m)*E + e)*E + o] = {wr,wi}[((h*E+e)*E+o)*M + m]
__global__ __launch_bounds__(256) void transpose_w(const float* __restrict__ wr, const float* __restrict__ wi,
                                                   float2* __restrict__ wt)
{
    int h = blockIdx.x / E, e = blockIdx.x % E;
    __shared__ float tr[64][33], ti[64][33];
    for (int i = threadIdx.x; i < E * MODES; i += 256) {
        int o = i / MODES, m = i % MODES;
        size_t s = (((size_t)h * E + e) * E + o) * MODES + m;
        tr[o][m] = wr[s]; ti[o][m] = wi[s];
    }
    __syncthreads();
    for (int i = threadIdx.x; i < MODES * E; i += 256) {
        int m = i / E, o = i % E;
        wt[(((size_t)h * MODES + m) * E + e) * E + o] = make_float2(tr[o][m], ti[o][m]);
    }
}

// im2col for kernel-3 circular conv on (B,L,CIN): A2[m][k], k=c*3+j, padded to KEMB
__global__ void im2col_emb(const float* __restrict__ x, const float* __restrict__ xmean,
                           float* __restrict__ A2)
{
    int idx = blockIdx.x * 256 + threadIdx.x;
    if (idx >= M_ROWS * KEMB) return;
    int k = idx % KEMB, m = idx / KEMB;
    float v = 0.f;
    if (k < CIN * 3) {
        int c = k / 3, j = k % 3;
        int l = m % L, b = m / L;
        int ls = l + j - 1; ls = (ls + L) % L;
        v = x[((size_t)b * L + ls) * CIN + c];
        if (xmean) v -= xmean[(size_t)b * CIN + c];
    }
    A2[idx] = v;
}

// ---------------- bf16 MFMA GEMM, reg-prefetch pipelined ----------------
// tile 128 x BN, 4 waves (2x2); wave = 64 x BN/2 via 4 x (BN/32) frags of 16x16, K-step 32
template<int BN>
__global__ __launch_bounds__(256) void gemm_mfma(const float* __restrict__ A, const float* __restrict__ W,
                                                 const float* __restrict__ bias, const float* __restrict__ pe,
                                                 const float* __restrict__ rowbias, float* __restrict__ C,
                                                 int Nout, int K, int act, int accum)
{
    constexpr int NI = BN / 32;
    __shared__ unsigned short As[128][40];
    __shared__ unsigned short Bs[BN][40];
    int tid = threadIdx.x;
    int row0 = blockIdx.y * 128, col0 = blockIdx.x * BN;
    int wid = tid >> 6, lane = tid & 63;
    int wm = wid >> 1, wn = wid & 1;
    int lrow = lane & 15, kg = lane >> 4;
    int sr = tid >> 3, sc4 = (tid & 7) * 4;
    f32x4 acc[4][NI] = {};
    float4 ra[4], rb[NI];

    auto loadG = [&](int k0) {
#pragma unroll
        for (int p = 0; p < 4; ++p)
            ra[p] = *(const float4*)&A[(size_t)(row0 + p * 32 + sr) * K + k0 + sc4];
#pragma unroll
        for (int p = 0; p < NI; ++p)
            rb[p] = *(const float4*)&W[(size_t)(col0 + p * 32 + sr) * K + k0 + sc4];
    };
    auto storeLDS = [&]() {
#pragma unroll
        for (int p = 0; p < 4; ++p) {
            ushort4 hh;
            hh.x = f2bf(ra[p].x); hh.y = f2bf(ra[p].y); hh.z = f2bf(ra[p].z); hh.w = f2bf(ra[p].w);
            *(ushort4*)&As[p * 32 + sr][sc4] = hh;
        }
#pragma unroll
        for (int p = 0; p < NI; ++p) {
            ushort4 hh;
            hh.x = f2bf(rb[p].x); hh.y = f2bf(rb[p].y); hh.z = f2bf(rb[p].z); hh.w = f2bf(rb[p].w);
            *(ushort4*)&Bs[p * 32 + sr][sc4] = hh;
        }
    };

    loadG(0);
    for (int k0 = 0; ; ) {
        __syncthreads();          // prior readers done (no-op on first pass)
        storeLDS();
        __syncthreads();
        int kn = k0 + 32;
        if (kn < K) loadG(kn);    // issue next-tile loads; latency hides under MFMA below
        shortx8 av[4], bv[NI];
#pragma unroll
        for (int mi = 0; mi < 4; ++mi)
            av[mi] = *(const shortx8*)&As[wm * 64 + mi * 16 + lrow][kg * 8];
#pragma unroll
        for (int ni = 0; ni < NI; ++ni)
            bv[ni] = *(const shortx8*)&Bs[wn * (BN / 2) + ni * 16 + lrow][kg * 8];
#pragma unroll
        for (int mi = 0; mi < 4; ++mi)
#pragma unroll
            for (int ni = 0; ni < NI; ++ni)
                acc[mi][ni] = __builtin_amdgcn_mfma_f32_16x16x32_bf16(av[mi], bv[ni], acc[mi][ni], 0, 0, 0);
        k0 = kn;
        if (k0 >= K) break;
    }
#pragma unroll
    for (int mi = 0; mi < 4; ++mi) {
#pragma unroll
        for (int ni = 0; ni < NI; ++ni) {
            int col = col0 + wn * (BN / 2) + ni * 16 + lrow;
            if (col >= Nout) continue;
#pragma unroll
            for (int r = 0; r < 4; ++r) {
                int row = row0 + wm * 64 + mi * 16 + kg * 4 + r;
                float v = acc[mi][ni][r];
                if (bias) v += bias[col];
                if (pe) v += pe[(size_t)(row % L) * Nout + col];
                if (rowbias) v += rowbias[(size_t)(row / L) * Nout + col];
                if (act) v = 0.5f * v * (1.f + erff(v * 0.70710678118654752f));
                size_t o = (size_t)row * Nout + col;
                if (accum) C[o] += v; else C[o] = v;
            }
        }
    }
}

// trend combine: dec_out[b,l,o] = xmean[b,o] + Y[b,l-1, o] + Y[b,l, 64+o] + Y[b,l+1, 128+o]  (circular)
__global__ void trend_combine(const float* __restrict__ Y, const float* __restrict__ xmean,
                              float* __restrict__ dec_out)
{
    int idx = blockIdx.x * 256 + threadIdx.x;
    if (idx >= B * L * COUT) return;
    int o = idx % COUT; int l = (idx / COUT) % L; int b = idx / (COUT * L);
    int lm = (l + L - 1) % L, lp = (l + 1) % L;
    float v = xmean[(size_t)b * CIN + o]
            + Y[((size_t)b * L + lm) * 192 + o]
            + Y[((size_t)b * L + l ) * 192 + 64 + o]
            + Y[((size_t)b * L + lp) * 192 + 128 + o];
    dec_out[idx] = v;
}

// ---------------- forward DFT: X (B,L,D) head-sliced -> xf (H,MODES,B,E) float2 ----------------
__global__ __launch_bounds__(256) void dft_fwd(const float* __restrict__ X,
                                               const float* __restrict__ twc, const float* __restrict__ tws,
                                               float2* __restrict__ xf)
{
    int b = blockIdx.x / H, h = blockIdx.x % H;
    __shared__ float xs[L][E];
    __shared__ float c[L][MODES], s[L][MODES];
    for (int i = threadIdx.x; i < L * E; i += 256) {
        int t = i / E, e = i % E;
        xs[t][e] = X[((size_t)b * L + t) * D + h * E + e];
    }
    for (int i = threadIdx.x; i < L * MODES; i += 256) { c[i / MODES][i % MODES] = twc[i]; s[i / MODES][i % MODES] = tws[i]; }
    __syncthreads();
    for (int o = threadIdx.x; o < E * MODES; o += 256) {
        int m = o / E, e = o % E;
        float re = 0.f, im = 0.f;
        for (int t = 0; t < L; ++t) {
            float v = xs[t][e];
            re += v * c[t][m];
            im -= v * s[t][m];
        }
        xf[((size_t)(h * MODES + m) * B + b) * E + e] = make_float2(re, im);
    }
}

// ---------------- per-(h,m) complex GEMM, in place: X[b][o] = sum_e X[b][e]*W[e][o] ----------------
__global__ __launch_bounds__(256) void mode_gemm2(float2* __restrict__ xf, const float2* __restrict__ wt)
{
    int hm = blockIdx.x;
    int bt = blockIdx.y;
    __shared__ float2 Wc[E][E];
    __shared__ float2 Ac[32][E];
    for (int i = threadIdx.x; i < E * E; i += 256) Wc[i / E][i % E] = wt[(size_t)hm * (E * E) + i];
    for (int i = threadIdx.x; i < 32 * E; i += 256)
        Ac[i / E][i % E] = xf[((size_t)hm * B + bt * 32 + i / E) * E + i % E];
    __syncthreads();
    int o = threadIdx.x & 63, bb = threadIdx.x >> 6;
    float2 acc[8];
#pragma unroll
    for (int j = 0; j < 8; ++j) acc[j] = make_float2(0.f, 0.f);
    for (int e = 0; e < E; ++e) {
        float2 w = Wc[e][o];
#pragma unroll
        for (int j = 0; j < 8; ++j) {
            float2 a = Ac[bb * 8 + j][e];
            acc[j].x += a.x * w.x - a.y * w.y;
            acc[j].y += a.x * w.y + a.y * w.x;
        }
    }
#pragma unroll
    for (int j = 0; j < 8; ++j)
        xf[((size_t)hm * B + bt * 32 + bb * 8 + j) * E + o] = acc[j];
}

// iDFT: sel (H,MODES,B,E) float2 -> out (B,L,D) head-sliced, scaled (DC imag ignored)
__global__ __launch_bounds__(256) void idft(const float2* __restrict__ sel,
                                            const float* __restrict__ twc, const float* __restrict__ tws,
                                            float* __restrict__ out, float scale)
{
    int b = blockIdx.x / H, h = blockIdx.x % H;
    __shared__ float2 sc[MODES][E];
    __shared__ float c[L][MODES], s[L][MODES];
    for (int i = threadIdx.x; i < MODES * E; i += 256) {
        int m = i / E, e = i % E;
        sc[m][e] = sel[((size_t)(h * MODES + m) * B + b) * E + e];
    }
    for (int i = threadIdx.x; i < L * MODES; i += 256) { c[i / MODES][i % MODES] = twc[i]; s[i / MODES][i % MODES] = tws[i]; }
    __syncthreads();
    for (int o = threadIdx.x; o < L * E; o += 256) {
        int t = o / E, e = o % E;
        float acc = sc[0][e].x;
        for (int m = 1; m < MODES; ++m)
            acc += 2.f * (sc[m][e].x * c[t][m] - sc[m][e].y * s[t][m]);
        out[((size_t)b * L + t) * D + h * E + e] = acc * scale;
    }
}

// FourierCross steps 1-2: qk = ctanh(qf^T kf), qkv = qk * kf; writes qkv over kf (same layout)
__global__ __launch_bounds__(256) void fourier_qk(const float2* __restrict__ qf, float2* __restrict__ kf)
{
    int b = blockIdx.x / H, h = blockIdx.x % H;
    __shared__ float2 qm[MODES][E + 1], km[MODES][E + 1], vm[MODES][E + 1];
    __shared__ float tr[MODES][MODES + 1], ti[MODES][MODES + 1];
    for (int i = threadIdx.x; i < MODES * E; i += 256) {
        int m = i / E, e = i % E;
        size_t idx = ((size_t)(h * MODES + m) * B + b) * E + e;
        qm[m][e] = qf[idx];
        km[m][e] = kf[idx];
    }
    __syncthreads();
    for (int i = threadIdx.x; i < MODES * MODES; i += 256) {
        int x = i / MODES, y = i % MODES;
        float re = 0.f, im = 0.f;
        for (int e = 0; e < E; ++e) {
            float2 a = qm[x][e], k2 = km[y][e];
            re += a.x * k2.x - a.y * k2.y;
            im += a.x * k2.y + a.y * k2.x;
        }
        float aa = fminf(fmaxf(2.f * re, -30.f), 30.f);
        float b2 = 2.f * im;
        float den = coshf(aa) + cosf(b2);
        tr[x][y] = sinhf(aa) / den;
        ti[x][y] = sinf(b2) / den;
    }
    __syncthreads();
    for (int i = threadIdx.x; i < MODES * E; i += 256) {
        int x = i / E, e = i % E;
        float re = 0.f, im = 0.f;
        for (int y = 0; y < MODES; ++y) {
            float ar = tr[x][y], ai = ti[x][y];
            float2 kk = km[y][e];
            re += ar * kk.x - ai * kk.y;
            im += ar * kk.y + ai * kk.x;
        }
        vm[x][e] = make_float2(re, im);
    }
    __syncthreads();
    for (int i = threadIdx.x; i < MODES * E; i += 256) {
        int m = i / E, e = i % E;
        kf[((size_t)(h * MODES + m) * B + b) * E + e] = vm[m][e];
    }
}

// scores[b,h,l,s] = (1/8) sum_e q[b,l,h,e]*k[b,s,h,e]
__global__ __launch_bounds__(256) void scores_kernel(const float* __restrict__ Q, const float* __restrict__ Kk,
                                                     float* __restrict__ out)
{
    int b = blockIdx.x / H, h = blockIdx.x % H;
    __shared__ float qs[L][E + 1], ks[L][E + 1];
    for (int i = threadIdx.x; i < L * E; i += 256) {
        int t = i / E, e = i % E;
        qs[t][e] = Q[((size_t)b * L + t) * D + h * E + e];
        ks[t][e] = Kk[((size_t)b * L + t) * D + h * E + e];
    }
    __syncthreads();
    for (int o = threadIdx.x; o < L * L; o += 256) {
        int l = o / L, ss = o % L;
        float acc = 0.f;
        for (int e = 0; e < E; ++e) acc += qs[l][e] * ks[ss][e];
        out[(((size_t)b * H + h) * L + l) * L + ss] = acc * 0.125f;
    }
}

__global__ __launch_bounds__(256) void softmax_rows(float* __restrict__ data, int nrows)
{
    int row = blockIdx.x * 4 + threadIdx.x / 64;
    int lane = threadIdx.x % 64;
    if (row >= nrows) return;
    float* p = data + (size_t)row * L;
    float v0 = (lane < L) ? p[lane] : -1e30f;
    float v1 = (lane + 64 < L) ? p[lane + 64] : -1e30f;
    float mx = fmaxf(v0, v1);
    for (int off = 32; off; off >>= 1) mx = fmaxf(mx, __shfl_xor(mx, off));
    float e0 = (lane < L) ? expf(v0 - mx) : 0.f;
    float e1 = (lane + 64 < L) ? expf(v1 - mx) : 0.f;
    float sum = e0 + e1;
    for (int off = 32; off; off >>= 1) sum += __shfl_xor(sum, off);
    float inv = 1.f / sum;
    if (lane < L) p[lane] = e0 * inv;
    if (lane + 64 < L) p[lane + 64] = e1 * inv;
}

// sigma: (B,H,L) = 3^(sigmoid(5*(enc@w.T+b))+1e-5)-1, stored transposed. One wave per row.
__global__ __launch_bounds__(256) void sigma_kernel(const float* __restrict__ enc, const float* __restrict__ w,
                                                    const float* __restrict__ bias, float* __restrict__ sig_out)
{
    __shared__ float wsh[H][D];
    for (int i = threadIdx.x; i < H * D; i += 256) wsh[i / D][i % D] = w[i];
    __syncthreads();
    int wid = threadIdx.x / 64, lane = threadIdx.x % 64;
    int row = blockIdx.x * 4 + wid;
    const float* p = enc + (size_t)row * D;
    float xv[8];
#pragma unroll
    for (int i = 0; i < 8; ++i) xv[i] = p[lane + i * 64];
    int b = row / L, l = row % L;
#pragma unroll
    for (int h = 0; h < H; ++h) {
        float s = 0.f;
#pragma unroll
        for (int i = 0; i < 8; ++i) s += xv[i] * wsh[h][lane + i * 64];
        for (int off = 32; off; off >>= 1) s += __shfl_xor(s, off);
        if (lane == 0) {
            float acc = s + bias[h];
            float sg = 1.f / (1.f + expf(-5.f * acc));
            float val = expf((sg + 1e-5f) * 1.0986122886681098f) - 1.f; // 3^u - 1
            sig_out[((size_t)b * H + h) * L + l] = val;
        }
    }
}

__global__ void prior_kernel(const float* __restrict__ sig, float* __restrict__ prior)
{
    int idx = blockIdx.x * 256 + threadIdx.x;
    if (idx >= (int)(B * H * L * L)) return;
    int s = idx % L; int l = (idx / L) % L; int bh = idx / (L * L);
    float sg = sig[(size_t)bh * L + l];
    float d = (float)abs(l - s);
    prior[idx] = expf(-d * d / (2.f * sg * sg)) * INV_SQRT_2PI / sg;
}

// series_decomp_multi: res = x - mean; tmode: 0 none, 1 trend = mean, 2 trend += mean
__global__ __launch_bounds__(256) void decomp_kernel(const float* __restrict__ in1, const float* __restrict__ in2,
                                                     const float* __restrict__ w, const float* __restrict__ bc,
                                                     float* __restrict__ res, float* __restrict__ trend, int tmode)
{
    int b = blockIdx.x / (D / 64);
    int d0 = (blockIdx.x % (D / 64)) * 64;
    __shared__ float xs[L][64];
    for (int i = threadIdx.x; i < L * 64; i += 256) {
        int t = i / 64, dd = i % 64;
        size_t g = ((size_t)b * L + t) * D + d0 + dd;
        float v = in1[g];
        if (in2) v += in2[g];
        xs[t][dd] = v;
    }
    __syncthreads();
    float w0 = w[0], w1 = w[1], b0 = bc[0], b1 = bc[1];
    for (int i = threadIdx.x; i < L * 64; i += 256) {
        int l = i / 64, dd = i % 64;
        float s12 = 0.f;
        for (int j = l - 5; j <= l + 6; ++j) s12 += xs[min(max(j, 0), L - 1)][dd];
        float s24 = 0.f;
        for (int j = l - 11; j <= l + 12; ++j) s24 += xs[min(max(j, 0), L - 1)][dd];
        float m0 = s12 * (1.f / 12.f), m1 = s24 * (1.f / 24.f);
        float x = xs[l][dd];
        float z0 = x * w0 + b0, z1 = x * w1 + b1;
        float zm = fmaxf(z0, z1);
        float e0 = expf(z0 - zm), e1 = expf(z1 - zm);
        float p0 = e0 / (e0 + e1);
        float mean = m0 * p0 + m1 * (1.f - p0);
        size_t g = ((size_t)b * L + l) * D + d0 + dd;
        res[g] = x - mean;
        if (tmode == 1) trend[g] = mean;
        else if (tmode == 2) trend[g] += mean;
    }
}

__global__ __launch_bounds__(256) void ln_row(const float* __restrict__ x, const float* __restrict__ g,
                                              const float* __restrict__ bb, float* __restrict__ out)
{
    int row = blockIdx.x;
    const float* p = x + (size_t)row * D;
    float s = 0.f, s2 = 0.f;
    for (int d = threadIdx.x; d < D; d += 256) { float v = p[d]; s += v; s2 += v * v; }
    for (int off = 32; off; off >>= 1) { s += __shfl_xor(s, off); s2 += __shfl_xor(s2, off); }
    __shared__ float red[8];
    int wid = threadIdx.x / 64, lane = threadIdx.x % 64;
    if (lane == 0) { red[wid] = s; red[4 + wid] = s2; }
    __syncthreads();
    if (threadIdx.x == 0) {
        red[0] = red[0] + red[1] + red[2] + red[3];
        red[4] = red[4] + red[5] + red[6] + red[7];
    }
    __syncthreads();
    float mu = red[0] / (float)D;
    float var = red[4] / (float)D - mu * mu;
    float rstd = rsqrtf(var + 1e-5f);
    for (int d = threadIdx.x; d < D; d += 256)
        out[(size_t)row * D + d] = (p[d] - mu) * rstd * g[d] + bb[d];
}

__global__ void col_sub(const float* __restrict__ xh, float* __restrict__ out)
{
    int idx = blockIdx.x * 256 + threadIdx.x;
    if (idx >= B * D) return;
    int b = idx / D, d = idx % D;
    float s = 0.f;
    for (int l = 0; l < L; ++l) s += xh[((size_t)b * L + l) * D + d];
    s *= (1.f / (float)L);
    for (int l = 0; l < L; ++l) {
        size_t g = ((size_t)b * L + l) * D + d;
        out[g] = xh[g] - s;
    }
}

extern "C" void kernel_launch(void* const* d_in, const int* in_sizes, int n_in,
                              void* d_out, int out_size, void* d_ws, size_t ws_size,
                              hipStream_t stream)
{
    const float* x           = (const float*)d_in[0];
    const float* emb_enc_w   = (const float*)d_in[1];
    const float* emb_dec_w   = (const float*)d_in[2];
    const float* enc_proj_w  = (const float*)d_in[3];
    const float* enc_proj_b  = (const float*)d_in[4];
    const float* enc_sig_w   = (const float*)d_in[5];
    const float* enc_sig_b   = (const float*)d_in[6];
    const float* enc_four_wr = (const float*)d_in[7];
    const float* enc_four_wi = (const float*)d_in[8];
    const float* enc_ffn_w1  = (const float*)d_in[9];
    const float* enc_ffn_w2  = (const float*)d_in[10];
    const float* enc_dcmp_w  = (const float*)d_in[11];
    const float* enc_dcmp_b  = (const float*)d_in[12];
    const float* enc_norm_g  = (const float*)d_in[13];
    const float* enc_norm_b  = (const float*)d_in[14];
    const float* dec_proj_w  = (const float*)d_in[15];
    const float* dec_proj_b  = (const float*)d_in[16];
    const float* dec_four_wr = (const float*)d_in[17];
    const float* dec_four_wi = (const float*)d_in[18];
    const float* crs_proj_w  = (const float*)d_in[19];
    const float* crs_proj_b  = (const float*)d_in[20];
    const float* crs_four_wr = (const float*)d_in[21];
    const float* crs_four_wi = (const float*)d_in[22];
    const float* dec_ffn_w1  = (const float*)d_in[23];
    const float* dec_ffn_w2  = (const float*)d_in[24];
    const float* dec_dcmp_w  = (const float*)d_in[25];
    const float* dec_dcmp_b  = (const float*)d_in[26];
    const float* dec_trend_w = (const float*)d_in[27];
    const float* dec_norm_g  = (const float*)d_in[28];
    const float* dec_norm_b  = (const float*)d_in[29];
    const float* out_proj_w  = (const float*)d_in[30];
    const float* out_proj_b  = (const float*)d_in[31];

    float* ws = (float*)d_ws;
    size_t off = 0;
    float* pe    = ws + off; off += (size_t)L * D;
    float* twc   = ws + off; off += (size_t)L * MODES;
    float* tws_  = ws + off; off += (size_t)L * MODES;
    float* xmean = ws + off; off += (size_t)B * CIN;
    float* enc   = ws + off; off += BLD;
    float* bufA  = ws + off; off += BLD;
    float* bufB  = ws + off; off += BLD;
    float* bufC  = ws + off; off += BLD;
    float* bufD  = ws + off; off += BLD;
    float* bufH  = ws + off; off += BLD;
    float* tacc  = ws + off; off += BLD;
    float2* xfc  = (float2*)(ws + off); off += 2 * BHEM;   // (H,MODES,B,E) complex
    float2* kfc  = (float2*)(ws + off); off += 2 * BHEM;
    float2* wtb  = (float2*)(ws + off); off += 2 * (size_t)H * MODES * E * E;
    float* wp_enc  = ws + off; off += (size_t)D * KEMB;
    float* wp_dec  = ws + off; off += (size_t)D * KEMB;
    float* wp_trd  = ws + off; off += (size_t)192 * D;    // stacked-tap trend weight
    float* wp_seas = ws + off; off += (size_t)64 * D;     // padded out_proj_w

    float* out       = (float*)d_out;
    float* dec_out   = out;                                   // B*L*COUT
    float* series_out= out + (size_t)B * L * COUT;            // 2*BHLL
    float* prior_out = series_out + 2 * BHLL;                 // 2*BHLL
    float* sigma_out = prior_out + 2 * BHLL;                  // 2*B*H*L

    const int BH = B * H;

    init_consts<<<200, 256, 0, stream>>>(pe, twc, tws_);
    xmean_kernel<<<cdiv(B * CIN, 256), 256, 0, stream>>>(x, xmean);
    pad_rows<<<cdiv(D * KEMB, 256), 256, 0, stream>>>(emb_enc_w, wp_enc, D, D, CIN * 3, KEMB);
    pad_rows<<<cdiv(D * KEMB, 256), 256, 0, stream>>>(emb_dec_w, wp_dec, D, D, CIN * 3, KEMB);
    pad_trend_w2<<<cdiv(192 * D, 256), 256, 0, stream>>>(dec_trend_w, wp_trd);
    pad_rows<<<cdiv(64 * D, 256), 256, 0, stream>>>(out_proj_w, wp_seas, COUT, 64, D, D);
    transpose_w<<<H * E, 256, 0, stream>>>(enc_four_wr, enc_four_wi, wtb);

    auto gemm = [&](const float* A, const float* W, const float* bias, const float* pe_, const float* rowb,
                    float* C, int N, int Nout, int K, int act, int accum) {
        if (N % 128 == 0) {
            dim3 grid(N / 128, M_ROWS / 128);
            gemm_mfma<128><<<grid, 256, 0, stream>>>(A, W, bias, pe_, rowb, C, Nout, K, act, accum);
        } else {
            dim3 grid(N / 64, M_ROWS / 128);
            gemm_mfma<64><<<grid, 256, 0, stream>>>(A, W, bias, pe_, rowb, C, Nout, K, act, accum);
        }
    };
    dim3 mg_grid(H * MODES, B / 32);

    // encoder embedding: im2col + GEMM (+pe fused)
    im2col_emb<<<cdiv(M_ROWS * KEMB, 256), 256, 0, stream>>>(x, nullptr, bufA);
    gemm(bufA, wp_enc, nullptr, pe, nullptr, enc, D, D, KEMB, 0, 0);

    for (int i = 0; i < 2; ++i) {
        const float* Wp = enc_proj_w + (size_t)i * 4 * D * D;
        const float* bp = enc_proj_b + (size_t)i * 4 * D;
        float* series_i = series_out + (size_t)i * BHLL;
        float* prior_i  = prior_out  + (size_t)i * BHLL;
        float* sigma_i  = sigma_out  + (size_t)i * B * H * L;

        gemm(enc, Wp,             bp,         nullptr, nullptr, bufA, D, D, D, 0, 0);   // q
        gemm(enc, Wp + D * D,     bp + D,     nullptr, nullptr, bufB, D, D, D, 0, 0);   // k
        dft_fwd<<<BH, 256, 0, stream>>>(bufA, twc, tws_, xfc);
        mode_gemm2<<<mg_grid, 256, 0, stream>>>(xfc, wtb);
        idft<<<BH, 256, 0, stream>>>(xfc, twc, tws_, bufC, 1.f / (float)L);
        gemm(bufC, Wp + 3 * D * D, bp + 3 * D, nullptr, nullptr, bufD, D, D, D, 0, 0);  // attn_out
        scores_kernel<<<BH, 256, 0, stream>>>(bufA, bufB, series_i);
        softmax_rows<<<B * H * L / 4, 256, 0, stream>>>(series_i, B * H * L);
        sigma_kernel<<<M_ROWS / 4, 256, 0, stream>>>(enc, enc_sig_w + (size_t)i * H * D,
                                                     enc_sig_b + (size_t)i * H, sigma_i);
        prior_kernel<<<cdiv((int)BHLL, 256), 256, 0, stream>>>(sigma_i, prior_i);
        decomp_kernel<<<B * (D / 64), 256, 0, stream>>>(enc, bufD, enc_dcmp_w + (size_t)(i * 2 + 0) * NK,
                                                        enc_dcmp_b + (size_t)(i * 2 + 0) * NK, bufH, nullptr, 0);
        gemm(bufH, enc_ffn_w1 + (size_t)i * DFF * D, nullptr, nullptr, nullptr, bufC, DFF, DFF, D, 1, 0);
        gemm(bufC, enc_ffn_w2 + (size_t)i * D * DFF, nullptr, nullptr, nullptr, bufD, D, D, DFF, 0, 0);
        decomp_kernel<<<B * (D / 64), 256, 0, stream>>>(bufH, bufD, enc_dcmp_w + (size_t)(i * 2 + 1) * NK,
                                                        enc_dcmp_b + (size_t)(i * 2 + 1) * NK, enc, nullptr, 0);
    }
    // encoder final my_layernorm
    ln_row<<<M_ROWS, 256, 0, stream>>>(enc, enc_norm_g, enc_norm_b, bufC);
    col_sub<<<cdiv(B * D, 256), 256, 0, stream>>>(bufC, enc);

    // ---------------- decoder ----------------
    transpose_w<<<H * E, 256, 0, stream>>>(dec_four_wr, dec_four_wi, wtb);
    im2col_emb<<<cdiv(M_ROWS * KEMB, 256), 256, 0, stream>>>(x, xmean, bufB);
    gemm(bufB, wp_dec, nullptr, pe, nullptr, bufA, D, D, KEMB, 0, 0);          // dec
    gemm(bufA, dec_proj_w, dec_proj_b, nullptr, nullptr, bufB, D, D, D, 0, 0); // q
    dft_fwd<<<BH, 256, 0, stream>>>(bufB, twc, tws_, xfc);
    mode_gemm2<<<mg_grid, 256, 0, stream>>>(xfc, wtb);
    idft<<<BH, 256, 0, stream>>>(xfc, twc, tws_, bufC, 1.f / (float)L);
    gemm(bufC, dec_proj_w + 3 * D * D, dec_proj_b + 3 * D, nullptr, nullptr, bufD, D, D, D, 0, 0); // sa
    decomp_kernel<<<B * (D / 64), 256, 0, stream>>>(bufA, bufD, dec_dcmp_w, dec_dcmp_b, bufH, tacc, 1); // h, t1

    gemm(bufH, crs_proj_w, crs_proj_b, nullptr, nullptr, bufB, D, D, D, 0, 0);   // qc
    dft_fwd<<<BH, 256, 0, stream>>>(bufB, twc, tws_, xfc);                       // qf
    gemm(enc, crs_proj_w + D * D, crs_proj_b + D, nullptr, nullptr, bufB, D, D, D, 0, 0); // kc
    dft_fwd<<<BH, 256, 0, stream>>>(bufB, twc, tws_, kfc);                       // kf
    transpose_w<<<H * E, 256, 0, stream>>>(crs_four_wr, crs_four_wi, (float2*)enc); // enc is dead now
    fourier_qk<<<BH, 256, 0, stream>>>(xfc, kfc);                                // kfc := qkv
    mode_gemm2<<<mg_grid, 256, 0, stream>>>(kfc, (float2*)enc);
    idft<<<BH, 256, 0, stream>>>(kfc, twc, tws_, bufC, 1.f / ((float)L * (float)D * (float)D));
    gemm(bufC, crs_proj_w + 3 * D * D, crs_proj_b + 3 * D, nullptr, nullptr, bufD, D, D, D, 0, 0); // ca
    decomp_kernel<<<B * (D / 64), 256, 0, stream>>>(bufH, bufD, dec_dcmp_w + NK, dec_dcmp_b + NK, bufA, tacc, 2); // h2, t2

    gemm(bufA, dec_ffn_w1, nullptr, nullptr, nullptr, bufC, DFF, DFF, D, 1, 0);
    gemm(bufC, dec_ffn_w2, nullptr, nullptr, nullptr, bufD, D, D, DFF, 0, 0);
    decomp_kernel<<<B * (D / 64), 256, 0, stream>>>(bufA, bufD, dec_dcmp_w + 2 * NK, dec_dcmp_b + 2 * NK, bufB, tacc, 2); // h3, t3

    // trend conv: stacked-tap GEMM (K=512, N=192) + shift-combine with trend_init (xmean)
    gemm(tacc, wp_trd, nullptr, nullptr, nullptr, bufC, 192, 192, D, 0, 0);
    trend_combine<<<cdiv(B * L * COUT, 256), 256, 0, stream>>>(bufC, xmean, dec_out);

    // final layernorm + seasonal projection accumulated into dec_out
    ln_row<<<M_ROWS, 256, 0, stream>>>(bufB, dec_norm_g, dec_norm_b, bufC);
    col_sub<<<cdiv(B * D, 256), 256, 0, stream>>>(bufC, bufD);
    gemm(bufD, wp_seas, out_proj_b, nullptr, nullptr, dec_out, 64, COUT, D, 0, 1);
}

// Round 6
// 2027.755 us; speedup vs baseline: 4.5352x; 1.0963x over previous
//
#include <hip/hip_runtime.h>
#include <cmath>

constexpr int B = 128, L = 100, CIN = 55, COUT = 55;
constexpr int D = 512, H = 8, DFF = 512, MODES = 32, E = 64;
constexpr int NK = 2;
constexpr int M_ROWS = B * L; // 12800
constexpr int KEMB = 192;     // 55*3=165 padded to 32*6
constexpr size_t BLD  = (size_t)B * L * D;         // 6,553,600
constexpr size_t BHEM = (size_t)B * H * E * MODES; // 2,097,152 complex elems
constexpr size_t BHLL = (size_t)B * H * L * L;     // 10,240,000
constexpr float INV_SQRT_2PI = 0.3989422804014327f;

static inline int cdiv(int a, int b) { return (a + b - 1) / b; }

typedef short shortx8 __attribute__((ext_vector_type(8)));
typedef float f32x4 __attribute__((ext_vector_type(4)));

__device__ inline unsigned short f2bf(float f)
{
    unsigned int u = __float_as_uint(f);
    unsigned int r = (u + 0x7FFFu + ((u >> 16) & 1u)) >> 16;
    return (unsigned short)r;
}

// ---------------- constants: positional emb + DFT twiddles ----------------
__global__ void init_consts(float* __restrict__ pe, float* __restrict__ twc, float* __restrict__ tws)
{
    int idx = blockIdx.x * 256 + threadIdx.x;
    if (idx < L * D) {
        int l = idx / D, d = idx % D;
        int i2 = d & ~1;
        float div = expf((float)i2 * (-logf(10000.f) / (float)D));
        float ang = (float)l * div;
        pe[idx] = (d & 1) ? cosf(ang) : sinf(ang);
    }
    if (idx < L * MODES) {
        int t = idx / MODES, m = idx % MODES;
        float th = 2.f * 3.14159265358979323846f * (float)m * (float)t / (float)L;
        twc[idx] = cosf(th);
        tws[idx] = sinf(th);
    }
}

__global__ void xmean_kernel(const float* __restrict__ x, float* __restrict__ xm)
{
    int idx = blockIdx.x * 256 + threadIdx.x;
    if (idx >= B * CIN) return;
    int b = idx / CIN, c = idx % CIN;
    float s = 0.f;
    for (int l = 0; l < L; ++l) s += x[((size_t)b * L + l) * CIN + c];
    xm[idx] = s * (1.f / (float)L);
}

// pad src (rows_src x k_src) into dst (rows_dst x k_dst), zero-filled
__global__ void pad_rows(const float* __restrict__ src, float* __restrict__ dst,
                         int rows_src, int rows_dst, int k_src, int k_dst)
{
    int idx = blockIdx.x * 256 + threadIdx.x;
    if (idx >= rows_dst * k_dst) return;
    int r = idx / k_dst, k = idx % k_dst;
    dst[idx] = (r < rows_src && k < k_src) ? src[(size_t)r * k_src + k] : 0.f;
}

// trend weight reshaped for stacked-tap GEMM: dst[(j*64+o)][d] = W[o,d,j] (o>=COUT -> 0)
__global__ void pad_trend_w2(const float* __restrict__ src, float* __restrict__ dst)
{
    int idx = blockIdx.x * 256 + threadIdx.x;
    if (idx >= 192 * D) return;
    int n = idx / D, d = idx % D;
    int j = n / 64, o = n % 64;
    dst[idx] = (o < COUT) ? src[(size_t)o * (D * 3) + d * 3 + j] : 0.f;
}

// Fourier weight transpose: wt[((h*M+m)*E + e)*E + o] = {wr,wi}[((h*E+e)*E+o)*M + m]
__global__ __launch_bounds__(256) void transpose_w(const float* __restrict__ wr, const float* __restrict__ wi,
                                                   float2* __restrict__ wt)
{
    int h = blockIdx.x / E, e = blockIdx.x % E;
    __shared__ float tr[64][33], ti[64][33];
    for (int i = threadIdx.x; i < E * MODES; i += 256) {
        int o = i / MODES, m = i % MODES;
        size_t s = (((size_t)h * E + e) * E + o) * MODES + m;
        tr[o][m] = wr[s]; ti[o][m] = wi[s];
    }
    __syncthreads();
    for (int i = threadIdx.x; i < MODES * E; i += 256) {
        int m = i / E, o = i % E;
        wt[(((size_t)h * MODES + m) * E + e) * E + o] = make_float2(tr[o][m], ti[o][m]);
    }
}

// im2col for kernel-3 circular conv on (B,L,CIN): A2[m][k], k=c*3+j, padded to KEMB
__global__ void im2col_emb(const float* __restrict__ x, const float* __restrict__ xmean,
                           float* __restrict__ A2)
{
    int idx = blockIdx.x * 256 + threadIdx.x;
    if (idx >= M_ROWS * KEMB) return;
    int k = idx % KEMB, m = idx / KEMB;
    float v = 0.f;
    if (k < CIN * 3) {
        int c = k / 3, j = k % 3;
        int l = m % L, b = m / L;
        int ls = l + j - 1; ls = (ls + L) % L;
        v = x[((size_t)b * L + ls) * CIN + c];
        if (xmean) v -= xmean[(size_t)b * CIN + c];
    }
    A2[idx] = v;
}

// ---------------- bf16 MFMA GEMM, reg-prefetch pipelined ----------------
// tile 128 x BN, 4 waves (2x2); wave = 64 x BN/2 via 4 x (BN/32) frags of 16x16, K-step 32
template<int BN>
__global__ __launch_bounds__(256) void gemm_mfma(const float* __restrict__ A, const float* __restrict__ W,
                                                 const float* __restrict__ bias, const float* __restrict__ pe,
                                                 const float* __restrict__ rowbias, float* __restrict__ C,
                                                 int Nout, int K, int act, int accum)
{
    constexpr int NI = BN / 32;
    __shared__ unsigned short As[128][40];
    __shared__ unsigned short Bs[BN][40];
    int tid = threadIdx.x;
    int row0 = blockIdx.y * 128, col0 = blockIdx.x * BN;
    int wid = tid >> 6, lane = tid & 63;
    int wm = wid >> 1, wn = wid & 1;
    int lrow = lane & 15, kg = lane >> 4;
    int sr = tid >> 3, sc4 = (tid & 7) * 4;
    f32x4 acc[4][NI] = {};
    float4 ra[4], rb[NI];

    auto loadG = [&](int k0) {
#pragma unroll
        for (int p = 0; p < 4; ++p)
            ra[p] = *(const float4*)&A[(size_t)(row0 + p * 32 + sr) * K + k0 + sc4];
#pragma unroll
        for (int p = 0; p < NI; ++p)
            rb[p] = *(const float4*)&W[(size_t)(col0 + p * 32 + sr) * K + k0 + sc4];
    };
    auto storeLDS = [&]() {
#pragma unroll
        for (int p = 0; p < 4; ++p) {
            ushort4 hh;
            hh.x = f2bf(ra[p].x); hh.y = f2bf(ra[p].y); hh.z = f2bf(ra[p].z); hh.w = f2bf(ra[p].w);
            *(ushort4*)&As[p * 32 + sr][sc4] = hh;
        }
#pragma unroll
        for (int p = 0; p < NI; ++p) {
            ushort4 hh;
            hh.x = f2bf(rb[p].x); hh.y = f2bf(rb[p].y); hh.z = f2bf(rb[p].z); hh.w = f2bf(rb[p].w);
            *(ushort4*)&Bs[p * 32 + sr][sc4] = hh;
        }
    };

    loadG(0);
    for (int k0 = 0; ; ) {
        __syncthreads();          // prior readers done (no-op on first pass)
        storeLDS();
        __syncthreads();
        int kn = k0 + 32;
        if (kn < K) loadG(kn);    // issue next-tile loads; latency hides under MFMA below
        shortx8 av[4], bv[NI];
#pragma unroll
        for (int mi = 0; mi < 4; ++mi)
            av[mi] = *(const shortx8*)&As[wm * 64 + mi * 16 + lrow][kg * 8];
#pragma unroll
        for (int ni = 0; ni < NI; ++ni)
            bv[ni] = *(const shortx8*)&Bs[wn * (BN / 2) + ni * 16 + lrow][kg * 8];
#pragma unroll
        for (int mi = 0; mi < 4; ++mi)
#pragma unroll
            for (int ni = 0; ni < NI; ++ni)
                acc[mi][ni] = __builtin_amdgcn_mfma_f32_16x16x32_bf16(av[mi], bv[ni], acc[mi][ni], 0, 0, 0);
        k0 = kn;
        if (k0 >= K) break;
    }
#pragma unroll
    for (int mi = 0; mi < 4; ++mi) {
#pragma unroll
        for (int ni = 0; ni < NI; ++ni) {
            int col = col0 + wn * (BN / 2) + ni * 16 + lrow;
            if (col >= Nout) continue;
#pragma unroll
            for (int r = 0; r < 4; ++r) {
                int row = row0 + wm * 64 + mi * 16 + kg * 4 + r;
                float v = acc[mi][ni][r];
                if (bias) v += bias[col];
                if (pe) v += pe[(size_t)(row % L) * Nout + col];
                if (rowbias) v += rowbias[(size_t)(row / L) * Nout + col];
                if (act) v = 0.5f * v * (1.f + erff(v * 0.70710678118654752f));
                size_t o = (size_t)row * Nout + col;
                if (accum) C[o] += v; else C[o] = v;
            }
        }
    }
}

// ---------------- fused QK^T/8 + row-softmax -> series (B,H,L,L), MFMA ----------------
// grid (B*H, 2); 4 waves; pass p: wave w owns q-rows p*64 + w*16 .. +15 (full rows -> local softmax)
__global__ __launch_bounds__(256) void scores_softmax(const float* __restrict__ Q, const float* __restrict__ Kk,
                                                      float* __restrict__ out)
{
    int bh = blockIdx.x, b = bh / H, h = bh % H;
    int pass = blockIdx.y;
    __shared__ unsigned short Ks[112][72];
    __shared__ unsigned short Qs[64][72];
    int tid = threadIdx.x;
    int srow = tid >> 4, sc4 = (tid & 15) * 4;
#pragma unroll
    for (int i = 0; i < 7; ++i) {
        int r = i * 16 + srow;
        ushort4 hh = {0, 0, 0, 0};
        if (r < L) {
            float4 v = *(const float4*)&Kk[((size_t)b * L + r) * D + h * E + sc4];
            hh.x = f2bf(v.x); hh.y = f2bf(v.y); hh.z = f2bf(v.z); hh.w = f2bf(v.w);
        }
        *(ushort4*)&Ks[r][sc4] = hh;
    }
#pragma unroll
    for (int i = 0; i < 4; ++i) {
        int r = i * 16 + srow;
        int gr = pass * 64 + r;
        ushort4 hh = {0, 0, 0, 0};
        if (gr < L) {
            float4 v = *(const float4*)&Q[((size_t)b * L + gr) * D + h * E + sc4];
            hh.x = f2bf(v.x); hh.y = f2bf(v.y); hh.z = f2bf(v.z); hh.w = f2bf(v.w);
        }
        *(ushort4*)&Qs[r][sc4] = hh;
    }
    __syncthreads();
    int wid = tid >> 6, lane = tid & 63;
    int lrow = lane & 15, kg = lane >> 4;
    f32x4 acc[7] = {};
#pragma unroll
    for (int ks = 0; ks < 2; ++ks) {
        shortx8 aq = *(const shortx8*)&Qs[wid * 16 + lrow][ks * 32 + kg * 8];
#pragma unroll
        for (int tj = 0; tj < 7; ++tj) {
            shortx8 bk = *(const shortx8*)&Ks[tj * 16 + lrow][ks * 32 + kg * 8];
            acc[tj] = __builtin_amdgcn_mfma_f32_16x16x32_bf16(aq, bk, acc[tj], 0, 0, 0);
        }
    }
    // lane holds rows q = wid*16 + kg*4 + r (r=0..3), col = tj*16 + lrow
    float mx[4] = {-1e30f, -1e30f, -1e30f, -1e30f};
#pragma unroll
    for (int tj = 0; tj < 7; ++tj) {
        bool valid = (tj * 16 + lrow) < L;
#pragma unroll
        for (int r = 0; r < 4; ++r) {
            float v = acc[tj][r] * 0.125f;
            acc[tj][r] = valid ? v : -1e30f;
            if (valid) mx[r] = fmaxf(mx[r], v);
        }
    }
#pragma unroll
    for (int off = 1; off < 16; off <<= 1)
#pragma unroll
        for (int r = 0; r < 4; ++r) mx[r] = fmaxf(mx[r], __shfl_xor(mx[r], off));
    float sum[4] = {0.f, 0.f, 0.f, 0.f};
#pragma unroll
    for (int tj = 0; tj < 7; ++tj)
#pragma unroll
        for (int r = 0; r < 4; ++r) {
            float e = expf(acc[tj][r] - mx[r]);
            acc[tj][r] = e;
            sum[r] += e;
        }
#pragma unroll
    for (int off = 1; off < 16; off <<= 1)
#pragma unroll
        for (int r = 0; r < 4; ++r) sum[r] += __shfl_xor(sum[r], off);
    float inv[4];
#pragma unroll
    for (int r = 0; r < 4; ++r) inv[r] = 1.f / sum[r];
    float* base = out + (size_t)bh * L * L;
#pragma unroll
    for (int r = 0; r < 4; ++r) {
        int row = pass * 64 + wid * 16 + kg * 4 + r;
        if (row >= L) continue;
#pragma unroll
        for (int tj = 0; tj < 7; ++tj) {
            int col = tj * 16 + lrow;
            if (col < L) base[(size_t)row * L + col] = acc[tj][r] * inv[r];
        }
    }
}

// trend combine: dec_out[b,l,o] = xmean[b,o] + Y[b,l-1, o] + Y[b,l, 64+o] + Y[b,l+1, 128+o]  (circular)
__global__ void trend_combine(const float* __restrict__ Y, const float* __restrict__ xmean,
                              float* __restrict__ dec_out)
{
    int idx = blockIdx.x * 256 + threadIdx.x;
    if (idx >= B * L * COUT) return;
    int o = idx % COUT; int l = (idx / COUT) % L; int b = idx / (COUT * L);
    int lm = (l + L - 1) % L, lp = (l + 1) % L;
    float v = xmean[(size_t)b * CIN + o]
            + Y[((size_t)b * L + lm) * 192 + o]
            + Y[((size_t)b * L + l ) * 192 + 64 + o]
            + Y[((size_t)b * L + lp) * 192 + 128 + o];
    dec_out[idx] = v;
}

// ---------------- forward DFT: X (B,L,D) head-sliced -> xf (H,MODES,B,E) float2 ----------------
__global__ __launch_bounds__(256) void dft_fwd(const float* __restrict__ X,
                                               const float* __restrict__ twc, const float* __restrict__ tws,
                                               float2* __restrict__ xf)
{
    int b = blockIdx.x / H, h = blockIdx.x % H;
    __shared__ float xs[L][E];
    __shared__ float c[L][MODES], s[L][MODES];
    for (int i = threadIdx.x; i < L * E; i += 256) {
        int t = i / E, e = i % E;
        xs[t][e] = X[((size_t)b * L + t) * D + h * E + e];
    }
    for (int i = threadIdx.x; i < L * MODES; i += 256) { c[i / MODES][i % MODES] = twc[i]; s[i / MODES][i % MODES] = tws[i]; }
    __syncthreads();
    for (int o = threadIdx.x; o < E * MODES; o += 256) {
        int m = o / E, e = o % E;
        float re = 0.f, im = 0.f;
        for (int t = 0; t < L; ++t) {
            float v = xs[t][e];
            re += v * c[t][m];
            im -= v * s[t][m];
        }
        xf[((size_t)(h * MODES + m) * B + b) * E + e] = make_float2(re, im);
    }
}

// ---------------- per-(h,m) complex GEMM, in place: X[b][o] = sum_e X[b][e]*W[e][o] ----------------
__global__ __launch_bounds__(256) void mode_gemm2(float2* __restrict__ xf, const float2* __restrict__ wt)
{
    int hm = blockIdx.x;
    int bt = blockIdx.y;
    __shared__ float2 Wc[E][E];
    __shared__ float2 Ac[32][E];
    for (int i = threadIdx.x; i < E * E; i += 256) Wc[i / E][i % E] = wt[(size_t)hm * (E * E) + i];
    for (int i = threadIdx.x; i < 32 * E; i += 256)
        Ac[i / E][i % E] = xf[((size_t)hm * B + bt * 32 + i / E) * E + i % E];
    __syncthreads();
    int o = threadIdx.x & 63, bb = threadIdx.x >> 6;
    float2 acc[8];
#pragma unroll
    for (int j = 0; j < 8; ++j) acc[j] = make_float2(0.f, 0.f);
    for (int e = 0; e < E; ++e) {
        float2 w = Wc[e][o];
#pragma unroll
        for (int j = 0; j < 8; ++j) {
            float2 a = Ac[bb * 8 + j][e];
            acc[j].x += a.x * w.x - a.y * w.y;
            acc[j].y += a.x * w.y + a.y * w.x;
        }
    }
#pragma unroll
    for (int j = 0; j < 8; ++j)
        xf[((size_t)hm * B + bt * 32 + bb * 8 + j) * E + o] = acc[j];
}

// iDFT: sel (H,MODES,B,E) float2 -> out (B,L,D) head-sliced, scaled (DC imag ignored)
__global__ __launch_bounds__(256) void idft(const float2* __restrict__ sel,
                                            const float* __restrict__ twc, const float* __restrict__ tws,
                                            float* __restrict__ out, float scale)
{
    int b = blockIdx.x / H, h = blockIdx.x % H;
    __shared__ float2 sc[MODES][E];
    __shared__ float c[L][MODES], s[L][MODES];
    for (int i = threadIdx.x; i < MODES * E; i += 256) {
        int m = i / E, e = i % E;
        sc[m][e] = sel[((size_t)(h * MODES + m) * B + b) * E + e];
    }
    for (int i = threadIdx.x; i < L * MODES; i += 256) { c[i / MODES][i % MODES] = twc[i]; s[i / MODES][i % MODES] = tws[i]; }
    __syncthreads();
    for (int o = threadIdx.x; o < L * E; o += 256) {
        int t = o / E, e = o % E;
        float acc = sc[0][e].x;
        for (int m = 1; m < MODES; ++m)
            acc += 2.f * (sc[m][e].x * c[t][m] - sc[m][e].y * s[t][m]);
        out[((size_t)b * L + t) * D + h * E + e] = acc * scale;
    }
}

// FourierCross steps 1-2: qk = ctanh(qf^T kf), qkv = qk * kf; writes qkv over kf (same layout)
__global__ __launch_bounds__(256) void fourier_qk(const float2* __restrict__ qf, float2* __restrict__ kf)
{
    int b = blockIdx.x / H, h = blockIdx.x % H;
    __shared__ float2 qm[MODES][E + 1], km[MODES][E + 1], vm[MODES][E + 1];
    __shared__ float tr[MODES][MODES + 1], ti[MODES][MODES + 1];
    for (int i = threadIdx.x; i < MODES * E; i += 256) {
        int m = i / E, e = i % E;
        size_t idx = ((size_t)(h * MODES + m) * B + b) * E + e;
        qm[m][e] = qf[idx];
        km[m][e] = kf[idx];
    }
    __syncthreads();
    for (int i = threadIdx.x; i < MODES * MODES; i += 256) {
        int x = i / MODES, y = i % MODES;
        float re = 0.f, im = 0.f;
        for (int e = 0; e < E; ++e) {
            float2 a = qm[x][e], k2 = km[y][e];
            re += a.x * k2.x - a.y * k2.y;
            im += a.x * k2.y + a.y * k2.x;
        }
        float aa = fminf(fmaxf(2.f * re, -30.f), 30.f);
        float b2 = 2.f * im;
        float den = coshf(aa) + cosf(b2);
        tr[x][y] = sinhf(aa) / den;
        ti[x][y] = sinf(b2) / den;
    }
    __syncthreads();
    for (int i = threadIdx.x; i < MODES * E; i += 256) {
        int x = i / E, e = i % E;
        float re = 0.f, im = 0.f;
        for (int y = 0; y < MODES; ++y) {
            float ar = tr[x][y], ai = ti[x][y];
            float2 kk = km[y][e];
            re += ar * kk.x - ai * kk.y;
            im += ar * kk.y + ai * kk.x;
        }
        vm[x][e] = make_float2(re, im);
    }
    __syncthreads();
    for (int i = threadIdx.x; i < MODES * E; i += 256) {
        int m = i / E, e = i % E;
        kf[((size_t)(h * MODES + m) * B + b) * E + e] = vm[m][e];
    }
}

// sigma: (B,H,L) = 3^(sigmoid(5*(enc@w.T+b))+1e-5)-1, stored transposed. One wave per row.
__global__ __launch_bounds__(256) void sigma_kernel(const float* __restrict__ enc, const float* __restrict__ w,
                                                    const float* __restrict__ bias, float* __restrict__ sig_out)
{
    __shared__ float wsh[H][D];
    for (int i = threadIdx.x; i < H * D; i += 256) wsh[i / D][i % D] = w[i];
    __syncthreads();
    int wid = threadIdx.x / 64, lane = threadIdx.x % 64;
    int row = blockIdx.x * 4 + wid;
    const float* p = enc + (size_t)row * D;
    float xv[8];
#pragma unroll
    for (int i = 0; i < 8; ++i) xv[i] = p[lane + i * 64];
    int b = row / L, l = row % L;
#pragma unroll
    for (int h = 0; h < H; ++h) {
        float s = 0.f;
#pragma unroll
        for (int i = 0; i < 8; ++i) s += xv[i] * wsh[h][lane + i * 64];
        for (int off = 32; off; off >>= 1) s += __shfl_xor(s, off);
        if (lane == 0) {
            float acc = s + bias[h];
            float sg = 1.f / (1.f + expf(-5.f * acc));
            float val = expf((sg + 1e-5f) * 1.0986122886681098f) - 1.f; // 3^u - 1
            sig_out[((size_t)b * H + h) * L + l] = val;
        }
    }
}

__global__ void prior_kernel(const float* __restrict__ sig, float* __restrict__ prior)
{
    int idx = blockIdx.x * 256 + threadIdx.x;
    if (idx >= (int)(B * H * L * L)) return;
    int s = idx % L; int l = (idx / L) % L; int bh = idx / (L * L);
    float sg = sig[(size_t)bh * L + l];
    float d = (float)abs(l - s);
    prior[idx] = expf(-d * d / (2.f * sg * sg)) * INV_SQRT_2PI / sg;
}

// series_decomp_multi: res = x - mean; tmode: 0 none, 1 trend = mean, 2 trend += mean
__global__ __launch_bounds__(256) void decomp_kernel(const float* __restrict__ in1, const float* __restrict__ in2,
                                                     const float* __restrict__ w, const float* __restrict__ bc,
                                                     float* __restrict__ res, float* __restrict__ trend, int tmode)
{
    int b = blockIdx.x / (D / 64);
    int d0 = (blockIdx.x % (D / 64)) * 64;
    __shared__ float xs[L][64];
    for (int i = threadIdx.x; i < L * 64; i += 256) {
        int t = i / 64, dd = i % 64;
        size_t g = ((size_t)b * L + t) * D + d0 + dd;
        float v = in1[g];
        if (in2) v += in2[g];
        xs[t][dd] = v;
    }
    __syncthreads();
    float w0 = w[0], w1 = w[1], b0 = bc[0], b1 = bc[1];
    for (int i = threadIdx.x; i < L * 64; i += 256) {
        int l = i / 64, dd = i % 64;
        float s12 = 0.f;
        for (int j = l - 5; j <= l + 6; ++j) s12 += xs[min(max(j, 0), L - 1)][dd];
        float s24 = 0.f;
        for (int j = l - 11; j <= l + 12; ++j) s24 += xs[min(max(j, 0), L - 1)][dd];
        float m0 = s12 * (1.f / 12.f), m1 = s24 * (1.f / 24.f);
        float x = xs[l][dd];
        float z0 = x * w0 + b0, z1 = x * w1 + b1;
        float zm = fmaxf(z0, z1);
        float e0 = expf(z0 - zm), e1 = expf(z1 - zm);
        float p0 = e0 / (e0 + e1);
        float mean = m0 * p0 + m1 * (1.f - p0);
        size_t g = ((size_t)b * L + l) * D + d0 + dd;
        res[g] = x - mean;
        if (tmode == 1) trend[g] = mean;
        else if (tmode == 2) trend[g] += mean;
    }
}

__global__ __launch_bounds__(256) void ln_row(const float* __restrict__ x, const float* __restrict__ g,
                                              const float* __restrict__ bb, float* __restrict__ out)
{
    int row = blockIdx.x;
    const float* p = x + (size_t)row * D;
    float s = 0.f, s2 = 0.f;
    for (int d = threadIdx.x; d < D; d += 256) { float v = p[d]; s += v; s2 += v * v; }
    for (int off = 32; off; off >>= 1) { s += __shfl_xor(s, off); s2 += __shfl_xor(s2, off); }
    __shared__ float red[8];
    int wid = threadIdx.x / 64, lane = threadIdx.x % 64;
    if (lane == 0) { red[wid] = s; red[4 + wid] = s2; }
    __syncthreads();
    if (threadIdx.x == 0) {
        red[0] = red[0] + red[1] + red[2] + red[3];
        red[4] = red[4] + red[5] + red[6] + red[7];
    }
    __syncthreads();
    float mu = red[0] / (float)D;
    float var = red[4] / (float)D - mu * mu;
    float rstd = rsqrtf(var + 1e-5f);
    for (int d = threadIdx.x; d < D; d += 256)
        out[(size_t)row * D + d] = (p[d] - mu) * rstd * g[d] + bb[d];
}

__global__ void col_sub(const float* __restrict__ xh, float* __restrict__ out)
{
    int idx = blockIdx.x * 256 + threadIdx.x;
    if (idx >= B * D) return;
    int b = idx / D, d = idx % D;
    float s = 0.f;
    for (int l = 0; l < L; ++l) s += xh[((size_t)b * L + l) * D + d];
    s *= (1.f / (float)L);
    for (int l = 0; l < L; ++l) {
        size_t g = ((size_t)b * L + l) * D + d;
        out[g] = xh[g] - s;
    }
}

extern "C" void kernel_launch(void* const* d_in, const int* in_sizes, int n_in,
                              void* d_out, int out_size, void* d_ws, size_t ws_size,
                              hipStream_t stream)
{
    const float* x           = (const float*)d_in[0];
    const float* emb_enc_w   = (const float*)d_in[1];
    const float* emb_dec_w   = (const float*)d_in[2];
    const float* enc_proj_w  = (const float*)d_in[3];
    const float* enc_proj_b  = (const float*)d_in[4];
    const float* enc_sig_w   = (const float*)d_in[5];
    const float* enc_sig_b   = (const float*)d_in[6];
    const float* enc_four_wr = (const float*)d_in[7];
    const float* enc_four_wi = (const float*)d_in[8];
    const float* enc_ffn_w1  = (const float*)d_in[9];
    const float* enc_ffn_w2  = (const float*)d_in[10];
    const float* enc_dcmp_w  = (const float*)d_in[11];
    const float* enc_dcmp_b  = (const float*)d_in[12];
    const float* enc_norm_g  = (const float*)d_in[13];
    const float* enc_norm_b  = (const float*)d_in[14];
    const float* dec_proj_w  = (const float*)d_in[15];
    const float* dec_proj_b  = (const float*)d_in[16];
    const float* dec_four_wr = (const float*)d_in[17];
    const float* dec_four_wi = (const float*)d_in[18];
    const float* crs_proj_w  = (const float*)d_in[19];
    const float* crs_proj_b  = (const float*)d_in[20];
    const float* crs_four_wr = (const float*)d_in[21];
    const float* crs_four_wi = (const float*)d_in[22];
    const float* dec_ffn_w1  = (const float*)d_in[23];
    const float* dec_ffn_w2  = (const float*)d_in[24];
    const float* dec_dcmp_w  = (const float*)d_in[25];
    const float* dec_dcmp_b  = (const float*)d_in[26];
    const float* dec_trend_w = (const float*)d_in[27];
    const float* dec_norm_g  = (const float*)d_in[28];
    const float* dec_norm_b  = (const float*)d_in[29];
    const float* out_proj_w  = (const float*)d_in[30];
    const float* out_proj_b  = (const float*)d_in[31];

    float* ws = (float*)d_ws;
    size_t off = 0;
    float* pe    = ws + off; off += (size_t)L * D;
    float* twc   = ws + off; off += (size_t)L * MODES;
    float* tws_  = ws + off; off += (size_t)L * MODES;
    float* xmean = ws + off; off += (size_t)B * CIN;
    float* enc   = ws + off; off += BLD;
    float* bufA  = ws + off; off += BLD;
    float* bufB  = ws + off; off += BLD;
    float* bufC  = ws + off; off += BLD;
    float* bufD  = ws + off; off += BLD;
    float* bufH  = ws + off; off += BLD;
    float* tacc  = ws + off; off += BLD;
    float2* xfc  = (float2*)(ws + off); off += 2 * BHEM;   // (H,MODES,B,E) complex
    float2* kfc  = (float2*)(ws + off); off += 2 * BHEM;
    float2* wtb  = (float2*)(ws + off); off += 2 * (size_t)H * MODES * E * E;
    float* wp_enc  = ws + off; off += (size_t)D * KEMB;
    float* wp_dec  = ws + off; off += (size_t)D * KEMB;
    float* wp_trd  = ws + off; off += (size_t)192 * D;    // stacked-tap trend weight
    float* wp_seas = ws + off; off += (size_t)64 * D;     // padded out_proj_w

    float* out       = (float*)d_out;
    float* dec_out   = out;                                   // B*L*COUT
    float* series_out= out + (size_t)B * L * COUT;            // 2*BHLL
    float* prior_out = series_out + 2 * BHLL;                 // 2*BHLL
    float* sigma_out = prior_out + 2 * BHLL;                  // 2*B*H*L

    const int BH = B * H;

    init_consts<<<200, 256, 0, stream>>>(pe, twc, tws_);
    xmean_kernel<<<cdiv(B * CIN, 256), 256, 0, stream>>>(x, xmean);
    pad_rows<<<cdiv(D * KEMB, 256), 256, 0, stream>>>(emb_enc_w, wp_enc, D, D, CIN * 3, KEMB);
    pad_rows<<<cdiv(D * KEMB, 256), 256, 0, stream>>>(emb_dec_w, wp_dec, D, D, CIN * 3, KEMB);
    pad_trend_w2<<<cdiv(192 * D, 256), 256, 0, stream>>>(dec_trend_w, wp_trd);
    pad_rows<<<cdiv(64 * D, 256), 256, 0, stream>>>(out_proj_w, wp_seas, COUT, 64, D, D);
    transpose_w<<<H * E, 256, 0, stream>>>(enc_four_wr, enc_four_wi, wtb);

    auto gemm = [&](const float* A, const float* W, const float* bias, const float* pe_, const float* rowb,
                    float* C, int N, int Nout, int K, int act, int accum) {
        if (N % 128 == 0) {
            dim3 grid(N / 128, M_ROWS / 128);
            gemm_mfma<128><<<grid, 256, 0, stream>>>(A, W, bias, pe_, rowb, C, Nout, K, act, accum);
        } else {
            dim3 grid(N / 64, M_ROWS / 128);
            gemm_mfma<64><<<grid, 256, 0, stream>>>(A, W, bias, pe_, rowb, C, Nout, K, act, accum);
        }
    };
    dim3 mg_grid(H * MODES, B / 32);
    dim3 sc_grid(BH, 2);

    // encoder embedding: im2col + GEMM (+pe fused)
    im2col_emb<<<cdiv(M_ROWS * KEMB, 256), 256, 0, stream>>>(x, nullptr, bufA);
    gemm(bufA, wp_enc, nullptr, pe, nullptr, enc, D, D, KEMB, 0, 0);

    for (int i = 0; i < 2; ++i) {
        const float* Wp = enc_proj_w + (size_t)i * 4 * D * D;
        const float* bp = enc_proj_b + (size_t)i * 4 * D;
        float* series_i = series_out + (size_t)i * BHLL;
        float* prior_i  = prior_out  + (size_t)i * BHLL;
        float* sigma_i  = sigma_out  + (size_t)i * B * H * L;

        gemm(enc, Wp,             bp,         nullptr, nullptr, bufA, D, D, D, 0, 0);   // q
        gemm(enc, Wp + D * D,     bp + D,     nullptr, nullptr, bufB, D, D, D, 0, 0);   // k
        dft_fwd<<<BH, 256, 0, stream>>>(bufA, twc, tws_, xfc);
        mode_gemm2<<<mg_grid, 256, 0, stream>>>(xfc, wtb);
        idft<<<BH, 256, 0, stream>>>(xfc, twc, tws_, bufC, 1.f / (float)L);
        gemm(bufC, Wp + 3 * D * D, bp + 3 * D, nullptr, nullptr, bufD, D, D, D, 0, 0);  // attn_out
        scores_softmax<<<sc_grid, 256, 0, stream>>>(bufA, bufB, series_i);
        sigma_kernel<<<M_ROWS / 4, 256, 0, stream>>>(enc, enc_sig_w + (size_t)i * H * D,
                                                     enc_sig_b + (size_t)i * H, sigma_i);
        prior_kernel<<<cdiv((int)BHLL, 256), 256, 0, stream>>>(sigma_i, prior_i);
        decomp_kernel<<<B * (D / 64), 256, 0, stream>>>(enc, bufD, enc_dcmp_w + (size_t)(i * 2 + 0) * NK,
                                                        enc_dcmp_b + (size_t)(i * 2 + 0) * NK, bufH, nullptr, 0);
        gemm(bufH, enc_ffn_w1 + (size_t)i * DFF * D, nullptr, nullptr, nullptr, bufC, DFF, DFF, D, 1, 0);
        gemm(bufC, enc_ffn_w2 + (size_t)i * D * DFF, nullptr, nullptr, nullptr, bufD, D, D, DFF, 0, 0);
        decomp_kernel<<<B * (D / 64), 256, 0, stream>>>(bufH, bufD, enc_dcmp_w + (size_t)(i * 2 + 1) * NK,
                                                        enc_dcmp_b + (size_t)(i * 2 + 1) * NK, enc, nullptr, 0);
    }
    // encoder final my_layernorm
    ln_row<<<M_ROWS, 256, 0, stream>>>(enc, enc_norm_g, enc_norm_b, bufC);
    col_sub<<<cdiv(B * D, 256), 256, 0, stream>>>(bufC, enc);

    // ---------------- decoder ----------------
    transpose_w<<<H * E, 256, 0, stream>>>(dec_four_wr, dec_four_wi, wtb);
    im2col_emb<<<cdiv(M_ROWS * KEMB, 256), 256, 0, stream>>>(x, xmean, bufB);
    gemm(bufB, wp_dec, nullptr, pe, nullptr, bufA, D, D, KEMB, 0, 0);          // dec
    gemm(bufA, dec_proj_w, dec_proj_b, nullptr, nullptr, bufB, D, D, D, 0, 0); // q
    dft_fwd<<<BH, 256, 0, stream>>>(bufB, twc, tws_, xfc);
    mode_gemm2<<<mg_grid, 256, 0, stream>>>(xfc, wtb);
    idft<<<BH, 256, 0, stream>>>(xfc, twc, tws_, bufC, 1.f / (float)L);
    gemm(bufC, dec_proj_w + 3 * D * D, dec_proj_b + 3 * D, nullptr, nullptr, bufD, D, D, D, 0, 0); // sa
    decomp_kernel<<<B * (D / 64), 256, 0, stream>>>(bufA, bufD, dec_dcmp_w, dec_dcmp_b, bufH, tacc, 1); // h, t1

    gemm(bufH, crs_proj_w, crs_proj_b, nullptr, nullptr, bufB, D, D, D, 0, 0);   // qc
    dft_fwd<<<BH, 256, 0, stream>>>(bufB, twc, tws_, xfc);                       // qf
    gemm(enc, crs_proj_w + D * D, crs_proj_b + D, nullptr, nullptr, bufB, D, D, D, 0, 0); // kc
    dft_fwd<<<BH, 256, 0, stream>>>(bufB, twc, tws_, kfc);                       // kf
    transpose_w<<<H * E, 256, 0, stream>>>(crs_four_wr, crs_four_wi, (float2*)enc); // enc is dead now
    fourier_qk<<<BH, 256, 0, stream>>>(xfc, kfc);                                // kfc := qkv
    mode_gemm2<<<mg_grid, 256, 0, stream>>>(kfc, (float2*)enc);
    idft<<<BH, 256, 0, stream>>>(kfc, twc, tws_, bufC, 1.f / ((float)L * (float)D * (float)D));
    gemm(bufC, crs_proj_w + 3 * D * D, crs_proj_b + 3 * D, nullptr, nullptr, bufD, D, D, D, 0, 0); // ca
    decomp_kernel<<<B * (D / 64), 256, 0, stream>>>(bufH, bufD, dec_dcmp_w + NK, dec_dcmp_b + NK, bufA, tacc, 2); // h2, t2

    gemm(bufA, dec_ffn_w1, nullptr, nullptr, nullptr, bufC, DFF, DFF, D, 1, 0);
    gemm(bufC, dec_ffn_w2, nullptr, nullptr, nullptr, bufD, D, D, DFF, 0, 0);
    decomp_kernel<<<B * (D / 64), 256, 0, stream>>>(bufA, bufD, dec_dcmp_w + 2 * NK, dec_dcmp_b + 2 * NK, bufB, tacc, 2); // h3, t3

    // trend conv: stacked-tap GEMM (K=512, N=192) + shift-combine with trend_init (xmean)
    gemm(tacc, wp_trd, nullptr, nullptr, nullptr, bufC, 192, 192, D, 0, 0);
    trend_combine<<<cdiv(B * L * COUT, 256), 256, 0, stream>>>(bufC, xmean, dec_out);

    // final layernorm + seasonal projection accumulated into dec_out
    ln_row<<<M_ROWS, 256, 0, stream>>>(bufB, dec_norm_g, dec_norm_b, bufC);
    col_sub<<<cdiv(B * D, 256), 256, 0, stream>>>(bufC, bufD);
    gemm(bufD, wp_seas, out_proj_b, nullptr, nullptr, dec_out, 64, COUT, D, 0, 1);
}

// Round 7
// 1979.551 us; speedup vs baseline: 4.6456x; 1.0244x over previous
//
#include <hip/hip_runtime.h>
#include <hip/hip_bf16.h>
#include <cmath>

constexpr int B = 128, L = 100, CIN = 55, COUT = 55;
constexpr int D = 512, H = 8, DFF = 512, MODES = 32, E = 64;
constexpr int NK = 2;
constexpr int M_ROWS = B * L; // 12800
constexpr int KEMB = 192;     // 55*3=165 padded to 32*6
constexpr size_t BLD  = (size_t)B * L * D;         // 6,553,600
constexpr size_t BHEM = (size_t)B * H * E * MODES; // 2,097,152 complex elems
constexpr size_t BHLL = (size_t)B * H * L * L;     // 10,240,000
constexpr float INV_SQRT_2PI = 0.3989422804014327f;

static inline int cdiv(int a, int b) { return (a + b - 1) / b; }

typedef short shortx8 __attribute__((ext_vector_type(8)));
typedef float f32x4 __attribute__((ext_vector_type(4)));

__device__ inline unsigned short f2bf(float f)    // RNE, for one-time weight conversion
{
    unsigned int u = __float_as_uint(f);
    unsigned int r = (u + 0x7FFFu + ((u >> 16) & 1u)) >> 16;
    return (unsigned short)r;
}
__device__ inline unsigned short f2bf_n(float f)  // native (packs to v_cvt_pk_bf16_f32)
{
    union { __hip_bfloat16 h; unsigned short u; } cv;
    cv.h = __float2bfloat16(f);
    return cv.u;
}

// ---------------- constants: positional emb + DFT twiddles ----------------
__global__ void init_consts(float* __restrict__ pe, float* __restrict__ twc, float* __restrict__ tws)
{
    int idx = blockIdx.x * 256 + threadIdx.x;
    if (idx < L * D) {
        int l = idx / D, d = idx % D;
        int i2 = d & ~1;
        float div = expf((float)i2 * (-logf(10000.f) / (float)D));
        float ang = (float)l * div;
        pe[idx] = (d & 1) ? cosf(ang) : sinf(ang);
    }
    if (idx < L * MODES) {
        int t = idx / MODES, m = idx % MODES;
        float th = 2.f * 3.14159265358979323846f * (float)m * (float)t / (float)L;
        twc[idx] = cosf(th);
        tws[idx] = sinf(th);
    }
}

__global__ void xmean_kernel(const float* __restrict__ x, float* __restrict__ xm)
{
    int idx = blockIdx.x * 256 + threadIdx.x;
    if (idx >= B * CIN) return;
    int b = idx / CIN, c = idx % CIN;
    float s = 0.f;
    for (int l = 0; l < L; ++l) s += x[((size_t)b * L + l) * CIN + c];
    xm[idx] = s * (1.f / (float)L);
}

// f32 -> bf16 bulk conversion (n multiple of 4)
__global__ void to_bf16(const float* __restrict__ src, unsigned short* __restrict__ dst, int n4)
{
    int i = blockIdx.x * 256 + threadIdx.x;
    if (i >= n4) return;
    float4 v = *(const float4*)&src[(size_t)i * 4];
    ushort4 h;
    h.x = f2bf(v.x); h.y = f2bf(v.y); h.z = f2bf(v.z); h.w = f2bf(v.w);
    *(ushort4*)&dst[(size_t)i * 4] = h;
}

// pad src (rows_src x k_src) into bf16 dst (rows_dst x k_dst), zero-filled
__global__ void pad_rows_bf(const float* __restrict__ src, unsigned short* __restrict__ dst,
                            int rows_src, int rows_dst, int k_src, int k_dst)
{
    int idx = blockIdx.x * 256 + threadIdx.x;
    if (idx >= rows_dst * k_dst) return;
    int r = idx / k_dst, k = idx % k_dst;
    dst[idx] = (r < rows_src && k < k_src) ? f2bf(src[(size_t)r * k_src + k]) : (unsigned short)0;
}

// trend weight reshaped for stacked-tap GEMM: dst[(j*64+o)][d] = W[o,d,j] (o>=COUT -> 0), bf16
__global__ void pad_trend_w2_bf(const float* __restrict__ src, unsigned short* __restrict__ dst)
{
    int idx = blockIdx.x * 256 + threadIdx.x;
    if (idx >= 192 * D) return;
    int n = idx / D, d = idx % D;
    int j = n / 64, o = n % 64;
    dst[idx] = (o < COUT) ? f2bf(src[(size_t)o * (D * 3) + d * 3 + j]) : (unsigned short)0;
}

// Fourier weight transpose: wt[((h*M+m)*E + e)*E + o] = {wr,wi}[((h*E+e)*E+o)*M + m]
__global__ __launch_bounds__(256) void transpose_w(const float* __restrict__ wr, const float* __restrict__ wi,
                                                   float2* __restrict__ wt)
{
    int h = blockIdx.x / E, e = blockIdx.x % E;
    __shared__ float tr[64][33], ti[64][33];
    for (int i = threadIdx.x; i < E * MODES; i += 256) {
        int o = i / MODES, m = i % MODES;
        size_t s = (((size_t)h * E + e) * E + o) * MODES + m;
        tr[o][m] = wr[s]; ti[o][m] = wi[s];
    }
    __syncthreads();
    for (int i = threadIdx.x; i < MODES * E; i += 256) {
        int m = i / E, o = i % E;
        wt[(((size_t)h * MODES + m) * E + e) * E + o] = make_float2(tr[o][m], ti[o][m]);
    }
}

// im2col for kernel-3 circular conv on (B,L,CIN): A2[m][k], k=c*3+j, padded to KEMB
__global__ void im2col_emb(const float* __restrict__ x, const float* __restrict__ xmean,
                           float* __restrict__ A2)
{
    int idx = blockIdx.x * 256 + threadIdx.x;
    if (idx >= M_ROWS * KEMB) return;
    int k = idx % KEMB, m = idx / KEMB;
    float v = 0.f;
    if (k < CIN * 3) {
        int c = k / 3, j = k % 3;
        int l = m % L, b = m / L;
        int ls = l + j - 1; ls = (ls + L) % L;
        v = x[((size_t)b * L + ls) * CIN + c];
        if (xmean) v -= xmean[(size_t)b * CIN + c];
    }
    A2[idx] = v;
}

// ---------------- bf16 MFMA GEMM, bf16 weights, reg-prefetch pipelined ----------------
// tile 128 x BN, 4 waves (2x2); wave = 64 x BN/2 via 4 x (BN/32) frags of 16x16, K-step 32
template<int BN>
__global__ __launch_bounds__(256) void gemm_mfma(const float* __restrict__ A, const unsigned short* __restrict__ Wb,
                                                 const float* __restrict__ bias, const float* __restrict__ pe,
                                                 const float* __restrict__ rowbias, float* __restrict__ C,
                                                 int Nout, int K, int act, int accum)
{
    constexpr int NI = BN / 32;
    constexpr int BI = BN / 64;
    __shared__ unsigned short As[128][40];
    __shared__ unsigned short Bs[BN][40];
    int tid = threadIdx.x;
    int row0 = blockIdx.y * 128, col0 = blockIdx.x * BN;
    int wid = tid >> 6, lane = tid & 63;
    int wm = wid >> 1, wn = wid & 1;
    int lrow = lane & 15, kg = lane >> 4;
    int sr = tid >> 3, sc4 = (tid & 7) * 4;
    int br = tid >> 2, bc8 = (tid & 3) * 8;
    f32x4 acc[4][NI] = {};
    float4 ra[4];
    shortx8 rbh[BI];

    auto loadG = [&](int k0) {
#pragma unroll
        for (int p = 0; p < 4; ++p)
            ra[p] = *(const float4*)&A[(size_t)(row0 + p * 32 + sr) * K + k0 + sc4];
#pragma unroll
        for (int p = 0; p < BI; ++p)
            rbh[p] = *(const shortx8*)&Wb[(size_t)(col0 + p * 64 + br) * K + k0 + bc8];
    };
    auto storeLDS = [&]() {
#pragma unroll
        for (int p = 0; p < 4; ++p) {
            ushort4 hh;
            hh.x = f2bf_n(ra[p].x); hh.y = f2bf_n(ra[p].y); hh.z = f2bf_n(ra[p].z); hh.w = f2bf_n(ra[p].w);
            *(ushort4*)&As[p * 32 + sr][sc4] = hh;
        }
#pragma unroll
        for (int p = 0; p < BI; ++p)
            *(shortx8*)&Bs[p * 64 + br][bc8] = rbh[p];
    };

    loadG(0);
    for (int k0 = 0; ; ) {
        __syncthreads();
        storeLDS();
        __syncthreads();
        int kn = k0 + 32;
        if (kn < K) loadG(kn);    // next-tile loads hide under MFMA below
        shortx8 av[4], bv[NI];
#pragma unroll
        for (int mi = 0; mi < 4; ++mi)
            av[mi] = *(const shortx8*)&As[wm * 64 + mi * 16 + lrow][kg * 8];
#pragma unroll
        for (int ni = 0; ni < NI; ++ni)
            bv[ni] = *(const shortx8*)&Bs[wn * (BN / 2) + ni * 16 + lrow][kg * 8];
#pragma unroll
        for (int mi = 0; mi < 4; ++mi)
#pragma unroll
            for (int ni = 0; ni < NI; ++ni)
                acc[mi][ni] = __builtin_amdgcn_mfma_f32_16x16x32_bf16(av[mi], bv[ni], acc[mi][ni], 0, 0, 0);
        k0 = kn;
        if (k0 >= K) break;
    }
#pragma unroll
    for (int mi = 0; mi < 4; ++mi) {
#pragma unroll
        for (int ni = 0; ni < NI; ++ni) {
            int col = col0 + wn * (BN / 2) + ni * 16 + lrow;
            if (col >= Nout) continue;
#pragma unroll
            for (int r = 0; r < 4; ++r) {
                int row = row0 + wm * 64 + mi * 16 + kg * 4 + r;
                float v = acc[mi][ni][r];
                if (bias) v += bias[col];
                if (pe) v += pe[(size_t)(row % L) * Nout + col];
                if (rowbias) v += rowbias[(size_t)(row / L) * Nout + col];
                if (act) v = 0.5f * v * (1.f + erff(v * 0.70710678118654752f));
                size_t o = (size_t)row * Nout + col;
                if (accum) C[o] += v; else C[o] = v;
            }
        }
    }
}

// ---------------- fused QK^T/8 + row-softmax -> series (B,H,L,L), MFMA ----------------
// QK buffer layout: row stride 1024, q at col 0, k at col 512. grid (B*H, 2); 4 waves.
__global__ __launch_bounds__(256) void scores_softmax(const float* __restrict__ QK, float* __restrict__ out)
{
    int bh = blockIdx.x, b = bh / H, h = bh % H;
    int pass = blockIdx.y;
    __shared__ unsigned short Ks[112][72];
    __shared__ unsigned short Qs[64][72];
    int tid = threadIdx.x;
    int srow = tid >> 4, sc4 = (tid & 15) * 4;
#pragma unroll
    for (int i = 0; i < 7; ++i) {
        int r = i * 16 + srow;
        ushort4 hh = {0, 0, 0, 0};
        if (r < L) {
            float4 v = *(const float4*)&QK[((size_t)b * L + r) * 1024 + 512 + h * E + sc4];
            hh.x = f2bf_n(v.x); hh.y = f2bf_n(v.y); hh.z = f2bf_n(v.z); hh.w = f2bf_n(v.w);
        }
        *(ushort4*)&Ks[r][sc4] = hh;
    }
#pragma unroll
    for (int i = 0; i < 4; ++i) {
        int r = i * 16 + srow;
        int gr = pass * 64 + r;
        ushort4 hh = {0, 0, 0, 0};
        if (gr < L) {
            float4 v = *(const float4*)&QK[((size_t)b * L + gr) * 1024 + h * E + sc4];
            hh.x = f2bf_n(v.x); hh.y = f2bf_n(v.y); hh.z = f2bf_n(v.z); hh.w = f2bf_n(v.w);
        }
        *(ushort4*)&Qs[r][sc4] = hh;
    }
    __syncthreads();
    int wid = tid >> 6, lane = tid & 63;
    int lrow = lane & 15, kg = lane >> 4;
    f32x4 acc[7] = {};
#pragma unroll
    for (int ks = 0; ks < 2; ++ks) {
        shortx8 aq = *(const shortx8*)&Qs[wid * 16 + lrow][ks * 32 + kg * 8];
#pragma unroll
        for (int tj = 0; tj < 7; ++tj) {
            shortx8 bk = *(const shortx8*)&Ks[tj * 16 + lrow][ks * 32 + kg * 8];
            acc[tj] = __builtin_amdgcn_mfma_f32_16x16x32_bf16(aq, bk, acc[tj], 0, 0, 0);
        }
    }
    float mx[4] = {-1e30f, -1e30f, -1e30f, -1e30f};
#pragma unroll
    for (int tj = 0; tj < 7; ++tj) {
        bool valid = (tj * 16 + lrow) < L;
#pragma unroll
        for (int r = 0; r < 4; ++r) {
            float v = acc[tj][r] * 0.125f;
            acc[tj][r] = valid ? v : -1e30f;
            if (valid) mx[r] = fmaxf(mx[r], v);
        }
    }
#pragma unroll
    for (int off = 1; off < 16; off <<= 1)
#pragma unroll
        for (int r = 0; r < 4; ++r) mx[r] = fmaxf(mx[r], __shfl_xor(mx[r], off));
    float sum[4] = {0.f, 0.f, 0.f, 0.f};
#pragma unroll
    for (int tj = 0; tj < 7; ++tj)
#pragma unroll
        for (int r = 0; r < 4; ++r) {
            float e = expf(acc[tj][r] - mx[r]);
            acc[tj][r] = e;
            sum[r] += e;
        }
#pragma unroll
    for (int off = 1; off < 16; off <<= 1)
#pragma unroll
        for (int r = 0; r < 4; ++r) sum[r] += __shfl_xor(sum[r], off);
    float inv[4];
#pragma unroll
    for (int r = 0; r < 4; ++r) inv[r] = 1.f / sum[r];
    float* base = out + (size_t)bh * L * L;
#pragma unroll
    for (int r = 0; r < 4; ++r) {
        int row = pass * 64 + wid * 16 + kg * 4 + r;
        if (row >= L) continue;
#pragma unroll
        for (int tj = 0; tj < 7; ++tj) {
            int col = tj * 16 + lrow;
            if (col < L) base[(size_t)row * L + col] = acc[tj][r] * inv[r];
        }
    }
}

// trend combine: dec_out[b,l,o] = xmean[b,o] + Y[b,l-1, o] + Y[b,l, 64+o] + Y[b,l+1, 128+o]  (circular)
__global__ void trend_combine(const float* __restrict__ Y, const float* __restrict__ xmean,
                              float* __restrict__ dec_out)
{
    int idx = blockIdx.x * 256 + threadIdx.x;
    if (idx >= B * L * COUT) return;
    int o = idx % COUT; int l = (idx / COUT) % L; int b = idx / (COUT * L);
    int lm = (l + L - 1) % L, lp = (l + 1) % L;
    float v = xmean[(size_t)b * CIN + o]
            + Y[((size_t)b * L + lm) * 192 + o]
            + Y[((size_t)b * L + l ) * 192 + 64 + o]
            + Y[((size_t)b * L + lp) * 192 + 128 + o];
    dec_out[idx] = v;
}

// ---------------- forward DFT: X (stride-rowed) head-sliced -> xf (H,MODES,B,E) float2 ----------------
__global__ __launch_bounds__(256) void dft_fwd(const float* __restrict__ X,
                                               const float* __restrict__ twc, const float* __restrict__ tws,
                                               float2* __restrict__ xf, int stride)
{
    int b = blockIdx.x / H, h = blockIdx.x % H;
    __shared__ float xs[L][E];
    __shared__ float c[L][MODES], s[L][MODES];
    for (int i = threadIdx.x; i < L * E; i += 256) {
        int t = i / E, e = i % E;
        xs[t][e] = X[((size_t)b * L + t) * stride + h * E + e];
    }
    for (int i = threadIdx.x; i < L * MODES; i += 256) { c[i / MODES][i % MODES] = twc[i]; s[i / MODES][i % MODES] = tws[i]; }
    __syncthreads();
    for (int o = threadIdx.x; o < E * MODES; o += 256) {
        int m = o / E, e = o % E;
        float re = 0.f, im = 0.f;
        for (int t = 0; t < L; ++t) {
            float v = xs[t][e];
            re += v * c[t][m];
            im -= v * s[t][m];
        }
        xf[((size_t)(h * MODES + m) * B + b) * E + e] = make_float2(re, im);
    }
}

// ---------------- per-(h,m) complex GEMM, in place: X[b][o] = sum_e X[b][e]*W[e][o] ----------------
__global__ __launch_bounds__(256) void mode_gemm2(float2* __restrict__ xf, const float2* __restrict__ wt)
{
    int hm = blockIdx.x;
    int bt = blockIdx.y;
    __shared__ float2 Wc[E][E];
    __shared__ float2 Ac[32][E];
    for (int i = threadIdx.x; i < E * E; i += 256) Wc[i / E][i % E] = wt[(size_t)hm * (E * E) + i];
    for (int i = threadIdx.x; i < 32 * E; i += 256)
        Ac[i / E][i % E] = xf[((size_t)hm * B + bt * 32 + i / E) * E + i % E];
    __syncthreads();
    int o = threadIdx.x & 63, bb = threadIdx.x >> 6;
    float2 acc[8];
#pragma unroll
    for (int j = 0; j < 8; ++j) acc[j] = make_float2(0.f, 0.f);
    for (int e = 0; e < E; ++e) {
        float2 w = Wc[e][o];
#pragma unroll
        for (int j = 0; j < 8; ++j) {
            float2 a = Ac[bb * 8 + j][e];
            acc[j].x += a.x * w.x - a.y * w.y;
            acc[j].y += a.x * w.y + a.y * w.x;
        }
    }
#pragma unroll
    for (int j = 0; j < 8; ++j)
        xf[((size_t)hm * B + bt * 32 + bb * 8 + j) * E + o] = acc[j];
}

// iDFT: sel (H,MODES,B,E) float2 -> out (B,L,D) head-sliced, scaled (DC imag ignored)
__global__ __launch_bounds__(256) void idft(const float2* __restrict__ sel,
                                            const float* __restrict__ twc, const float* __restrict__ tws,
                                            float* __restrict__ out, float scale)
{
    int b = blockIdx.x / H, h = blockIdx.x % H;
    __shared__ float2 sc[MODES][E];
    __shared__ float c[L][MODES], s[L][MODES];
    for (int i = threadIdx.x; i < MODES * E; i += 256) {
        int m = i / E, e = i % E;
        sc[m][e] = sel[((size_t)(h * MODES + m) * B + b) * E + e];
    }
    for (int i = threadIdx.x; i < L * MODES; i += 256) { c[i / MODES][i % MODES] = twc[i]; s[i / MODES][i % MODES] = tws[i]; }
    __syncthreads();
    for (int o = threadIdx.x; o < L * E; o += 256) {
        int t = o / E, e = o % E;
        float acc = sc[0][e].x;
        for (int m = 1; m < MODES; ++m)
            acc += 2.f * (sc[m][e].x * c[t][m] - sc[m][e].y * s[t][m]);
        out[((size_t)b * L + t) * D + h * E + e] = acc * scale;
    }
}

// FourierCross steps 1-2: qk = ctanh(qf^T kf), qkv = qk * kf; writes qkv over kf (same layout)
__global__ __launch_bounds__(256) void fourier_qk(const float2* __restrict__ qf, float2* __restrict__ kf)
{
    int b = blockIdx.x / H, h = blockIdx.x % H;
    __shared__ float2 qm[MODES][E + 1], km[MODES][E + 1], vm[MODES][E + 1];
    __shared__ float tr[MODES][MODES + 1], ti[MODES][MODES + 1];
    for (int i = threadIdx.x; i < MODES * E; i += 256) {
        int m = i / E, e = i % E;
        size_t idx = ((size_t)(h * MODES + m) * B + b) * E + e;
        qm[m][e] = qf[idx];
        km[m][e] = kf[idx];
    }
    __syncthreads();
    for (int i = threadIdx.x; i < MODES * MODES; i += 256) {
        int x = i / MODES, y = i % MODES;
        float re = 0.f, im = 0.f;
        for (int e = 0; e < E; ++e) {
            float2 a = qm[x][e], k2 = km[y][e];
            re += a.x * k2.x - a.y * k2.y;
            im += a.x * k2.y + a.y * k2.x;
        }
        float aa = fminf(fmaxf(2.f * re, -30.f), 30.f);
        float b2 = 2.f * im;
        float den = coshf(aa) + cosf(b2);
        tr[x][y] = sinhf(aa) / den;
        ti[x][y] = sinf(b2) / den;
    }
    __syncthreads();
    for (int i = threadIdx.x; i < MODES * E; i += 256) {
        int x = i / E, e = i % E;
        float re = 0.f, im = 0.f;
        for (int y = 0; y < MODES; ++y) {
            float ar = tr[x][y], ai = ti[x][y];
            float2 kk = km[y][e];
            re += ar * kk.x - ai * kk.y;
            im += ar * kk.y + ai * kk.x;
        }
        vm[x][e] = make_float2(re, im);
    }
    __syncthreads();
    for (int i = threadIdx.x; i < MODES * E; i += 256) {
        int m = i / E, e = i % E;
        kf[((size_t)(h * MODES + m) * B + b) * E + e] = vm[m][e];
    }
}

// sigma: (B,H,L) = 3^(sigmoid(5*(enc@w.T+b))+1e-5)-1, stored transposed. One wave per row.
__global__ __launch_bounds__(256) void sigma_kernel(const float* __restrict__ enc, const float* __restrict__ w,
                                                    const float* __restrict__ bias, float* __restrict__ sig_out)
{
    __shared__ float wsh[H][D];
    for (int i = threadIdx.x; i < H * D; i += 256) wsh[i / D][i % D] = w[i];
    __syncthreads();
    int wid = threadIdx.x / 64, lane = threadIdx.x % 64;
    int row = blockIdx.x * 4 + wid;
    const float* p = enc + (size_t)row * D;
    float xv[8];
#pragma unroll
    for (int i = 0; i < 8; ++i) xv[i] = p[lane + i * 64];
    int b = row / L, l = row % L;
#pragma unroll
    for (int h = 0; h < H; ++h) {
        float s = 0.f;
#pragma unroll
        for (int i = 0; i < 8; ++i) s += xv[i] * wsh[h][lane + i * 64];
        for (int off = 32; off; off >>= 1) s += __shfl_xor(s, off);
        if (lane == 0) {
            float acc = s + bias[h];
            float sg = 1.f / (1.f + expf(-5.f * acc));
            float val = expf((sg + 1e-5f) * 1.0986122886681098f) - 1.f; // 3^u - 1
            sig_out[((size_t)b * H + h) * L + l] = val;
        }
    }
}

__global__ void prior_kernel(const float* __restrict__ sig, float* __restrict__ prior)
{
    int idx = blockIdx.x * 256 + threadIdx.x;
    if (idx >= (int)(B * H * L * L)) return;
    int s = idx % L; int l = (idx / L) % L; int bh = idx / (L * L);
    float sg = sig[(size_t)bh * L + l];
    float d = (float)abs(l - s);
    prior[idx] = expf(-d * d / (2.f * sg * sg)) * INV_SQRT_2PI / sg;
}

// series_decomp_multi: res = x - mean; tmode: 0 none, 1 trend = mean, 2 trend += mean
__global__ __launch_bounds__(256) void decomp_kernel(const float* __restrict__ in1, const float* __restrict__ in2,
                                                     const float* __restrict__ w, const float* __restrict__ bc,
                                                     float* __restrict__ res, float* __restrict__ trend, int tmode)
{
    int b = blockIdx.x / (D / 64);
    int d0 = (blockIdx.x % (D / 64)) * 64;
    __shared__ float xs[L][64];
    for (int i = threadIdx.x; i < L * 64; i += 256) {
        int t = i / 64, dd = i % 64;
        size_t g = ((size_t)b * L + t) * D + d0 + dd;
        float v = in1[g];
        if (in2) v += in2[g];
        xs[t][dd] = v;
    }
    __syncthreads();
    float w0 = w[0], w1 = w[1], b0 = bc[0], b1 = bc[1];
    for (int i = threadIdx.x; i < L * 64; i += 256) {
        int l = i / 64, dd = i % 64;
        float s12 = 0.f;
        for (int j = l - 5; j <= l + 6; ++j) s12 += xs[min(max(j, 0), L - 1)][dd];
        float s24 = 0.f;
        for (int j = l - 11; j <= l + 12; ++j) s24 += xs[min(max(j, 0), L - 1)][dd];
        float m0 = s12 * (1.f / 12.f), m1 = s24 * (1.f / 24.f);
        float x = xs[l][dd];
        float z0 = x * w0 + b0, z1 = x * w1 + b1;
        float zm = fmaxf(z0, z1);
        float e0 = expf(z0 - zm), e1 = expf(z1 - zm);
        float p0 = e0 / (e0 + e1);
        float mean = m0 * p0 + m1 * (1.f - p0);
        size_t g = ((size_t)b * L + l) * D + d0 + dd;
        res[g] = x - mean;
        if (tmode == 1) trend[g] = mean;
        else if (tmode == 2) trend[g] += mean;
    }
}

__global__ __launch_bounds__(256) void ln_row(const float* __restrict__ x, const float* __restrict__ g,
                                              const float* __restrict__ bb, float* __restrict__ out)
{
    int row = blockIdx.x;
    const float* p = x + (size_t)row * D;
    float s = 0.f, s2 = 0.f;
    for (int d = threadIdx.x; d < D; d += 256) { float v = p[d]; s += v; s2 += v * v; }
    for (int off = 32; off; off >>= 1) { s += __shfl_xor(s, off); s2 += __shfl_xor(s2, off); }
    __shared__ float red[8];
    int wid = threadIdx.x / 64, lane = threadIdx.x % 64;
    if (lane == 0) { red[wid] = s; red[4 + wid] = s2; }
    __syncthreads();
    if (threadIdx.x == 0) {
        red[0] = red[0] + red[1] + red[2] + red[3];
        red[4] = red[4] + red[5] + red[6] + red[7];
    }
    __syncthreads();
    float mu = red[0] / (float)D;
    float var = red[4] / (float)D - mu * mu;
    float rstd = rsqrtf(var + 1e-5f);
    for (int d = threadIdx.x; d < D; d += 256)
        out[(size_t)row * D + d] = (p[d] - mu) * rstd * g[d] + bb[d];
}

__global__ void col_sub(const float* __restrict__ xh, float* __restrict__ out)
{
    int idx = blockIdx.x * 256 + threadIdx.x;
    if (idx >= B * D) return;
    int b = idx / D, d = idx % D;
    float s = 0.f;
    for (int l = 0; l < L; ++l) s += xh[((size_t)b * L + l) * D + d];
    s *= (1.f / (float)L);
    for (int l = 0; l < L; ++l) {
        size_t g = ((size_t)b * L + l) * D + d;
        out[g] = xh[g] - s;
    }
}

extern "C" void kernel_launch(void* const* d_in, const int* in_sizes, int n_in,
                              void* d_out, int out_size, void* d_ws, size_t ws_size,
                              hipStream_t stream)
{
    const float* x           = (const float*)d_in[0];
    const float* emb_enc_w   = (const float*)d_in[1];
    const float* emb_dec_w   = (const float*)d_in[2];
    const float* enc_proj_w  = (const float*)d_in[3];
    const float* enc_proj_b  = (const float*)d_in[4];
    const float* enc_sig_w   = (const float*)d_in[5];
    const float* enc_sig_b   = (const float*)d_in[6];
    const float* enc_four_wr = (const float*)d_in[7];
    const float* enc_four_wi = (const float*)d_in[8];
    const float* enc_ffn_w1  = (const float*)d_in[9];
    const float* enc_ffn_w2  = (const float*)d_in[10];
    const float* enc_dcmp_w  = (const float*)d_in[11];
    const float* enc_dcmp_b  = (const float*)d_in[12];
    const float* enc_norm_g  = (const float*)d_in[13];
    const float* enc_norm_b  = (const float*)d_in[14];
    const float* dec_proj_w  = (const float*)d_in[15];
    const float* dec_proj_b  = (const float*)d_in[16];
    const float* dec_four_wr = (const float*)d_in[17];
    const float* dec_four_wi = (const float*)d_in[18];
    const float* crs_proj_w  = (const float*)d_in[19];
    const float* crs_proj_b  = (const float*)d_in[20];
    const float* crs_four_wr = (const float*)d_in[21];
    const float* crs_four_wi = (const float*)d_in[22];
    const float* dec_ffn_w1  = (const float*)d_in[23];
    const float* dec_ffn_w2  = (const float*)d_in[24];
    const float* dec_dcmp_w  = (const float*)d_in[25];
    const float* dec_dcmp_b  = (const float*)d_in[26];
    const float* dec_trend_w = (const float*)d_in[27];
    const float* dec_norm_g  = (const float*)d_in[28];
    const float* dec_norm_b  = (const float*)d_in[29];
    const float* out_proj_w  = (const float*)d_in[30];
    const float* out_proj_b  = (const float*)d_in[31];

    float* ws = (float*)d_ws;
    size_t off = 0;
    float* pe    = ws + off; off += (size_t)L * D;
    float* twc   = ws + off; off += (size_t)L * MODES;
    float* tws_  = ws + off; off += (size_t)L * MODES;
    float* xmean = ws + off; off += (size_t)B * CIN;
    float* enc   = ws + off; off += BLD;
    float* bufA  = ws + off; off += BLD;   // bufA+bufB = fused QK buffer (M_ROWS x 1024)
    float* bufB  = ws + off; off += BLD;
    float* bufC  = ws + off; off += BLD;
    float* bufD  = ws + off; off += BLD;
    float* bufH  = ws + off; off += BLD;
    float* tacc  = ws + off; off += BLD;
    float2* xfc  = (float2*)(ws + off); off += 2 * BHEM;   // (H,MODES,B,E) complex
    float2* kfc  = (float2*)(ws + off); off += 2 * BHEM;
    float2* wtb  = (float2*)(ws + off); off += 2 * (size_t)H * MODES * E * E;
    // bf16 weight store (ushort regions carved out of float ws)
    unsigned short* wbf_encproj = (unsigned short*)(ws + off); off += (size_t)2 * 4 * D * D / 2;
    unsigned short* wbf_ffn1    = (unsigned short*)(ws + off); off += (size_t)2 * DFF * D / 2;
    unsigned short* wbf_ffn2    = (unsigned short*)(ws + off); off += (size_t)2 * D * DFF / 2;
    unsigned short* wbf_decproj = (unsigned short*)(ws + off); off += (size_t)4 * D * D / 2;
    unsigned short* wbf_crsproj = (unsigned short*)(ws + off); off += (size_t)4 * D * D / 2;
    unsigned short* wbf_dffn1   = (unsigned short*)(ws + off); off += (size_t)DFF * D / 2;
    unsigned short* wbf_dffn2   = (unsigned short*)(ws + off); off += (size_t)D * DFF / 2;
    unsigned short* wbf_embenc  = (unsigned short*)(ws + off); off += (size_t)D * KEMB / 2;
    unsigned short* wbf_embdec  = (unsigned short*)(ws + off); off += (size_t)D * KEMB / 2;
    unsigned short* wbf_trd     = (unsigned short*)(ws + off); off += (size_t)192 * D / 2;
    unsigned short* wbf_seas    = (unsigned short*)(ws + off); off += (size_t)64 * D / 2;

    float* out       = (float*)d_out;
    float* dec_out   = out;                                   // B*L*COUT
    float* series_out= out + (size_t)B * L * COUT;            // 2*BHLL
    float* prior_out = series_out + 2 * BHLL;                 // 2*BHLL
    float* sigma_out = prior_out + 2 * BHLL;                  // 2*B*H*L

    const int BH = B * H;

    init_consts<<<200, 256, 0, stream>>>(pe, twc, tws_);
    xmean_kernel<<<cdiv(B * CIN, 256), 256, 0, stream>>>(x, xmean);
    to_bf16<<<cdiv(2 * 4 * D * D / 4, 256), 256, 0, stream>>>(enc_proj_w, wbf_encproj, 2 * 4 * D * D / 4);
    to_bf16<<<cdiv(2 * DFF * D / 4, 256), 256, 0, stream>>>(enc_ffn_w1, wbf_ffn1, 2 * DFF * D / 4);
    to_bf16<<<cdiv(2 * D * DFF / 4, 256), 256, 0, stream>>>(enc_ffn_w2, wbf_ffn2, 2 * D * DFF / 4);
    to_bf16<<<cdiv(4 * D * D / 4, 256), 256, 0, stream>>>(dec_proj_w, wbf_decproj, 4 * D * D / 4);
    to_bf16<<<cdiv(4 * D * D / 4, 256), 256, 0, stream>>>(crs_proj_w, wbf_crsproj, 4 * D * D / 4);
    to_bf16<<<cdiv(DFF * D / 4, 256), 256, 0, stream>>>(dec_ffn_w1, wbf_dffn1, DFF * D / 4);
    to_bf16<<<cdiv(D * DFF / 4, 256), 256, 0, stream>>>(dec_ffn_w2, wbf_dffn2, D * DFF / 4);
    pad_rows_bf<<<cdiv(D * KEMB, 256), 256, 0, stream>>>(emb_enc_w, wbf_embenc, D, D, CIN * 3, KEMB);
    pad_rows_bf<<<cdiv(D * KEMB, 256), 256, 0, stream>>>(emb_dec_w, wbf_embdec, D, D, CIN * 3, KEMB);
    pad_trend_w2_bf<<<cdiv(192 * D, 256), 256, 0, stream>>>(dec_trend_w, wbf_trd);
    pad_rows_bf<<<cdiv(64 * D, 256), 256, 0, stream>>>(out_proj_w, wbf_seas, COUT, 64, D, D);
    transpose_w<<<H * E, 256, 0, stream>>>(enc_four_wr, enc_four_wi, wtb);

    auto gemm = [&](const float* A, const unsigned short* Wb, const float* bias, const float* pe_, const float* rowb,
                    float* C, int N, int Nout, int K, int act, int accum) {
        if (N % 128 == 0) {
            dim3 grid(N / 128, M_ROWS / 128);
            gemm_mfma<128><<<grid, 256, 0, stream>>>(A, Wb, bias, pe_, rowb, C, Nout, K, act, accum);
        } else {
            dim3 grid(N / 64, M_ROWS / 128);
            gemm_mfma<64><<<grid, 256, 0, stream>>>(A, Wb, bias, pe_, rowb, C, Nout, K, act, accum);
        }
    };
    dim3 mg_grid(H * MODES, B / 32);
    dim3 sc_grid(BH, 2);

    // encoder embedding: im2col + GEMM (+pe fused)
    im2col_emb<<<cdiv(M_ROWS * KEMB, 256), 256, 0, stream>>>(x, nullptr, bufA);
    gemm(bufA, wbf_embenc, nullptr, pe, nullptr, enc, D, D, KEMB, 0, 0);

    for (int i = 0; i < 2; ++i) {
        const unsigned short* Wp = wbf_encproj + (size_t)i * 4 * D * D;
        const float* bp = enc_proj_b + (size_t)i * 4 * D;
        float* series_i = series_out + (size_t)i * BHLL;
        float* prior_i  = prior_out  + (size_t)i * BHLL;
        float* sigma_i  = sigma_out  + (size_t)i * B * H * L;

        // fused q+k projection: N=1024 (weight rows: q slice then k slice, contiguous)
        gemm(enc, Wp, bp, nullptr, nullptr, bufA, 1024, 1024, D, 0, 0);
        dft_fwd<<<BH, 256, 0, stream>>>(bufA, twc, tws_, xfc, 1024);
        mode_gemm2<<<mg_grid, 256, 0, stream>>>(xfc, wtb);
        idft<<<BH, 256, 0, stream>>>(xfc, twc, tws_, bufC, 1.f / (float)L);
        gemm(bufC, Wp + (size_t)3 * D * D, bp + 3 * D, nullptr, nullptr, bufD, D, D, D, 0, 0);  // attn_out
        scores_softmax<<<sc_grid, 256, 0, stream>>>(bufA, series_i);
        sigma_kernel<<<M_ROWS / 4, 256, 0, stream>>>(enc, enc_sig_w + (size_t)i * H * D,
                                                     enc_sig_b + (size_t)i * H, sigma_i);
        prior_kernel<<<cdiv((int)BHLL, 256), 256, 0, stream>>>(sigma_i, prior_i);
        decomp_kernel<<<B * (D / 64), 256, 0, stream>>>(enc, bufD, enc_dcmp_w + (size_t)(i * 2 + 0) * NK,
                                                        enc_dcmp_b + (size_t)(i * 2 + 0) * NK, bufH, nullptr, 0);
        gemm(bufH, wbf_ffn1 + (size_t)i * DFF * D, nullptr, nullptr, nullptr, bufC, DFF, DFF, D, 1, 0);
        gemm(bufC, wbf_ffn2 + (size_t)i * D * DFF, nullptr, nullptr, nullptr, bufD, D, D, DFF, 0, 0);
        decomp_kernel<<<B * (D / 64), 256, 0, stream>>>(bufH, bufD, enc_dcmp_w + (size_t)(i * 2 + 1) * NK,
                                                        enc_dcmp_b + (size_t)(i * 2 + 1) * NK, enc, nullptr, 0);
    }
    // encoder final my_layernorm
    ln_row<<<M_ROWS, 256, 0, stream>>>(enc, enc_norm_g, enc_norm_b, bufC);
    col_sub<<<cdiv(B * D, 256), 256, 0, stream>>>(bufC, enc);

    // ---------------- decoder ----------------
    transpose_w<<<H * E, 256, 0, stream>>>(dec_four_wr, dec_four_wi, wtb);
    im2col_emb<<<cdiv(M_ROWS * KEMB, 256), 256, 0, stream>>>(x, xmean, bufB);
    gemm(bufB, wbf_embdec, nullptr, pe, nullptr, bufA, D, D, KEMB, 0, 0);          // dec
    gemm(bufA, wbf_decproj, dec_proj_b, nullptr, nullptr, bufB, D, D, D, 0, 0);    // q
    dft_fwd<<<BH, 256, 0, stream>>>(bufB, twc, tws_, xfc, D);
    mode_gemm2<<<mg_grid, 256, 0, stream>>>(xfc, wtb);
    idft<<<BH, 256, 0, stream>>>(xfc, twc, tws_, bufC, 1.f / (float)L);
    gemm(bufC, wbf_decproj + (size_t)3 * D * D, dec_proj_b + 3 * D, nullptr, nullptr, bufD, D, D, D, 0, 0); // sa
    decomp_kernel<<<B * (D / 64), 256, 0, stream>>>(bufA, bufD, dec_dcmp_w, dec_dcmp_b, bufH, tacc, 1); // h, t1

    gemm(bufH, wbf_crsproj, crs_proj_b, nullptr, nullptr, bufB, D, D, D, 0, 0);    // qc
    dft_fwd<<<BH, 256, 0, stream>>>(bufB, twc, tws_, xfc, D);                      // qf
    gemm(enc, wbf_crsproj + (size_t)D * D, crs_proj_b + D, nullptr, nullptr, bufB, D, D, D, 0, 0); // kc
    dft_fwd<<<BH, 256, 0, stream>>>(bufB, twc, tws_, kfc, D);                      // kf
    transpose_w<<<H * E, 256, 0, stream>>>(crs_four_wr, crs_four_wi, (float2*)enc); // enc is dead now
    fourier_qk<<<BH, 256, 0, stream>>>(xfc, kfc);                                  // kfc := qkv
    mode_gemm2<<<mg_grid, 256, 0, stream>>>(kfc, (float2*)enc);
    idft<<<BH, 256, 0, stream>>>(kfc, twc, tws_, bufC, 1.f / ((float)L * (float)D * (float)D));
    gemm(bufC, wbf_crsproj + (size_t)3 * D * D, crs_proj_b + 3 * D, nullptr, nullptr, bufD, D, D, D, 0, 0); // ca
    decomp_kernel<<<B * (D / 64), 256, 0, stream>>>(bufH, bufD, dec_dcmp_w + NK, dec_dcmp_b + NK, bufA, tacc, 2); // h2, t2

    gemm(bufA, wbf_dffn1, nullptr, nullptr, nullptr, bufC, DFF, DFF, D, 1, 0);
    gemm(bufC, wbf_dffn2, nullptr, nullptr, nullptr, bufD, D, D, DFF, 0, 0);
    decomp_kernel<<<B * (D / 64), 256, 0, stream>>>(bufA, bufD, dec_dcmp_w + 2 * NK, dec_dcmp_b + 2 * NK, bufB, tacc, 2); // h3, t3

    // trend conv: stacked-tap GEMM (K=512, N=192) + shift-combine with trend_init (xmean)
    gemm(tacc, wbf_trd, nullptr, nullptr, nullptr, bufC, 192, 192, D, 0, 0);
    trend_combine<<<cdiv(B * L * COUT, 256), 256, 0, stream>>>(bufC, xmean, dec_out);

    // final layernorm + seasonal projection accumulated into dec_out
    ln_row<<<M_ROWS, 256, 0, stream>>>(bufB, dec_norm_g, dec_norm_b, bufC);
    col_sub<<<cdiv(B * D, 256), 256, 0, stream>>>(bufC, bufD);
    gemm(bufD, wbf_seas, out_proj_b, nullptr, nullptr, dec_out, 64, COUT, D, 0, 1);
}

// Round 8
// 1866.335 us; speedup vs baseline: 4.9274x; 1.0607x over previous
//
#include <hip/hip_runtime.h>
#include <hip/hip_bf16.h>
#include <cmath>

constexpr int B = 128, L = 100, CIN = 55, COUT = 55;
constexpr int D = 512, H = 8, DFF = 512, MODES = 32, E = 64;
constexpr int NK = 2;
constexpr int M_ROWS = B * L; // 12800
constexpr int KEMB = 192;     // 55*3=165 padded to 32*6
constexpr size_t BLD  = (size_t)B * L * D;         // 6,553,600
constexpr size_t BHEM = (size_t)B * H * E * MODES; // 2,097,152 complex elems
constexpr size_t BHLL = (size_t)B * H * L * L;     // 10,240,000
constexpr float INV_SQRT_2PI = 0.3989422804014327f;

static inline int cdiv(int a, int b) { return (a + b - 1) / b; }

typedef short shortx8 __attribute__((ext_vector_type(8)));
typedef float f32x4 __attribute__((ext_vector_type(4)));

__device__ inline unsigned short f2bf(float f)    // RNE (weight prep)
{
    unsigned int u = __float_as_uint(f);
    unsigned int r = (u + 0x7FFFu + ((u >> 16) & 1u)) >> 16;
    return (unsigned short)r;
}
__device__ inline unsigned short f2bf_n(float f)  // native cvt
{
    union { __hip_bfloat16 h; unsigned short u; } cv;
    cv.h = __float2bfloat16(f);
    return cv.u;
}
__device__ inline float bf2f(unsigned short u)
{
    union { unsigned int i; float f; } c;
    c.i = (unsigned int)u << 16;
    return c.f;
}

// ---------------- constants ----------------
__global__ void init_consts(float* __restrict__ pe, float* __restrict__ twc, float* __restrict__ tws)
{
    int idx = blockIdx.x * 256 + threadIdx.x;
    if (idx < L * D) {
        int l = idx / D, d = idx % D;
        int i2 = d & ~1;
        float div = expf((float)i2 * (-logf(10000.f) / (float)D));
        float ang = (float)l * div;
        pe[idx] = (d & 1) ? cosf(ang) : sinf(ang);
    }
    if (idx < L * MODES) {
        int t = idx / MODES, m = idx % MODES;
        float th = 2.f * 3.14159265358979323846f * (float)m * (float)t / (float)L;
        twc[idx] = cosf(th);
        tws[idx] = sinf(th);
    }
}

__global__ void xmean_kernel(const float* __restrict__ x, float* __restrict__ xm)
{
    int idx = blockIdx.x * 256 + threadIdx.x;
    if (idx >= B * CIN) return;
    int b = idx / CIN, c = idx % CIN;
    float s = 0.f;
    for (int l = 0; l < L; ++l) s += x[((size_t)b * L + l) * CIN + c];
    xm[idx] = s * (1.f / (float)L);
}

// f32 -> bf16 bulk conversion (n multiple of 4)
__global__ void to_bf16(const float* __restrict__ src, unsigned short* __restrict__ dst, int n4)
{
    int i = blockIdx.x * 256 + threadIdx.x;
    if (i >= n4) return;
    float4 v = *(const float4*)&src[(size_t)i * 4];
    ushort4 h;
    h.x = f2bf(v.x); h.y = f2bf(v.y); h.z = f2bf(v.z); h.w = f2bf(v.w);
    *(ushort4*)&dst[(size_t)i * 4] = h;
}

__global__ void pad_rows_bf(const float* __restrict__ src, unsigned short* __restrict__ dst,
                            int rows_src, int rows_dst, int k_src, int k_dst)
{
    int idx = blockIdx.x * 256 + threadIdx.x;
    if (idx >= rows_dst * k_dst) return;
    int r = idx / k_dst, k = idx % k_dst;
    dst[idx] = (r < rows_src && k < k_src) ? f2bf(src[(size_t)r * k_src + k]) : (unsigned short)0;
}

__global__ void pad_trend_w2_bf(const float* __restrict__ src, unsigned short* __restrict__ dst)
{
    int idx = blockIdx.x * 256 + threadIdx.x;
    if (idx >= 192 * D) return;
    int n = idx / D, d = idx % D;
    int j = n / 64, o = n % 64;
    dst[idx] = (o < COUT) ? f2bf(src[(size_t)o * (D * 3) + d * 3 + j]) : (unsigned short)0;
}

__global__ __launch_bounds__(256) void transpose_w(const float* __restrict__ wr, const float* __restrict__ wi,
                                                   float2* __restrict__ wt)
{
    int h = blockIdx.x / E, e = blockIdx.x % E;
    __shared__ float tr[64][33], ti[64][33];
    for (int i = threadIdx.x; i < E * MODES; i += 256) {
        int o = i / MODES, m = i % MODES;
        size_t s = (((size_t)h * E + e) * E + o) * MODES + m;
        tr[o][m] = wr[s]; ti[o][m] = wi[s];
    }
    __syncthreads();
    for (int i = threadIdx.x; i < MODES * E; i += 256) {
        int m = i / E, o = i % E;
        wt[(((size_t)h * MODES + m) * E + e) * E + o] = make_float2(tr[o][m], ti[o][m]);
    }
}

// im2col for kernel-3 circular conv: bf16 out
__global__ void im2col_emb(const float* __restrict__ x, const float* __restrict__ xmean,
                           unsigned short* __restrict__ A2)
{
    int idx = blockIdx.x * 256 + threadIdx.x;
    if (idx >= M_ROWS * KEMB) return;
    int k = idx % KEMB, m = idx / KEMB;
    float v = 0.f;
    if (k < CIN * 3) {
        int c = k / 3, j = k % 3;
        int l = m % L, b = m / L;
        int ls = l + j - 1; ls = (ls + L) % L;
        v = x[((size_t)b * L + ls) * CIN + c];
        if (xmean) v -= xmean[(size_t)b * CIN + c];
    }
    A2[idx] = f2bf(v);
}

// ---------------- bf16 MFMA GEMM: bf16 A and W, fp32 or bf16 out ----------------
template<int BN>
__global__ __launch_bounds__(256) void gemm_mfma(const unsigned short* __restrict__ A,
                                                 const unsigned short* __restrict__ Wb,
                                                 const float* __restrict__ bias, const float* __restrict__ pe,
                                                 float* __restrict__ C, unsigned short* __restrict__ Cb,
                                                 int Nout, int K, int act, int accum)
{
    constexpr int NI = BN / 32;
    constexpr int BI = BN / 64;
    __shared__ unsigned short As[128][40];
    __shared__ unsigned short Bs[BN][40];
    int tid = threadIdx.x;
    int row0 = blockIdx.y * 128, col0 = blockIdx.x * BN;
    int wid = tid >> 6, lane = tid & 63;
    int wm = wid >> 1, wn = wid & 1;
    int lrow = lane & 15, kg = lane >> 4;
    int ar = tid >> 2, ac8 = (tid & 3) * 8;
    f32x4 acc[4][NI] = {};
    shortx8 rah[2], rbh[BI];

    auto loadG = [&](int k0) {
#pragma unroll
        for (int p = 0; p < 2; ++p)
            rah[p] = *(const shortx8*)&A[(size_t)(row0 + p * 64 + ar) * K + k0 + ac8];
#pragma unroll
        for (int p = 0; p < BI; ++p)
            rbh[p] = *(const shortx8*)&Wb[(size_t)(col0 + p * 64 + ar) * K + k0 + ac8];
    };
    auto storeLDS = [&]() {
#pragma unroll
        for (int p = 0; p < 2; ++p)
            *(shortx8*)&As[p * 64 + ar][ac8] = rah[p];
#pragma unroll
        for (int p = 0; p < BI; ++p)
            *(shortx8*)&Bs[p * 64 + ar][ac8] = rbh[p];
    };

    loadG(0);
    for (int k0 = 0; ; ) {
        __syncthreads();
        storeLDS();
        __syncthreads();
        int kn = k0 + 32;
        if (kn < K) loadG(kn);    // next-tile loads hide under MFMA below
        shortx8 av[4], bv[NI];
#pragma unroll
        for (int mi = 0; mi < 4; ++mi)
            av[mi] = *(const shortx8*)&As[wm * 64 + mi * 16 + lrow][kg * 8];
#pragma unroll
        for (int ni = 0; ni < NI; ++ni)
            bv[ni] = *(const shortx8*)&Bs[wn * (BN / 2) + ni * 16 + lrow][kg * 8];
#pragma unroll
        for (int mi = 0; mi < 4; ++mi)
#pragma unroll
            for (int ni = 0; ni < NI; ++ni)
                acc[mi][ni] = __builtin_amdgcn_mfma_f32_16x16x32_bf16(av[mi], bv[ni], acc[mi][ni], 0, 0, 0);
        k0 = kn;
        if (k0 >= K) break;
    }
#pragma unroll
    for (int mi = 0; mi < 4; ++mi) {
#pragma unroll
        for (int ni = 0; ni < NI; ++ni) {
            int col = col0 + wn * (BN / 2) + ni * 16 + lrow;
            if (col >= Nout) continue;
#pragma unroll
            for (int r = 0; r < 4; ++r) {
                int row = row0 + wm * 64 + mi * 16 + kg * 4 + r;
                float v = acc[mi][ni][r];
                if (bias) v += bias[col];
                if (pe) v += pe[(size_t)(row % L) * Nout + col];
                if (act) v = 0.5f * v * (1.f + erff(v * 0.70710678118654752f));
                size_t o = (size_t)row * Nout + col;
                if (Cb) Cb[o] = f2bf_n(v);
                else if (accum) C[o] += v;
                else C[o] = v;
            }
        }
    }
}

// ---------------- fused QK^T/8 + row-softmax (bf16 input, row stride 1024) ----------------
__global__ __launch_bounds__(256) void scores_softmax(const unsigned short* __restrict__ QK,
                                                      float* __restrict__ out)
{
    int bh = blockIdx.x, b = bh / H, h = bh % H;
    int pass = blockIdx.y;
    __shared__ unsigned short Ks[112][72];
    __shared__ unsigned short Qs[64][72];
    int tid = threadIdx.x;
    int srow = tid >> 4, sc4 = (tid & 15) * 4;
#pragma unroll
    for (int i = 0; i < 7; ++i) {
        int r = i * 16 + srow;
        ushort4 hh = {0, 0, 0, 0};
        if (r < L) hh = *(const ushort4*)&QK[((size_t)b * L + r) * 1024 + 512 + h * E + sc4];
        *(ushort4*)&Ks[r][sc4] = hh;
    }
#pragma unroll
    for (int i = 0; i < 4; ++i) {
        int r = i * 16 + srow;
        int gr = pass * 64 + r;
        ushort4 hh = {0, 0, 0, 0};
        if (gr < L) hh = *(const ushort4*)&QK[((size_t)b * L + gr) * 1024 + h * E + sc4];
        *(ushort4*)&Qs[r][sc4] = hh;
    }
    __syncthreads();
    int wid = tid >> 6, lane = tid & 63;
    int lrow = lane & 15, kg = lane >> 4;
    f32x4 acc[7] = {};
#pragma unroll
    for (int ks = 0; ks < 2; ++ks) {
        shortx8 aq = *(const shortx8*)&Qs[wid * 16 + lrow][ks * 32 + kg * 8];
#pragma unroll
        for (int tj = 0; tj < 7; ++tj) {
            shortx8 bk = *(const shortx8*)&Ks[tj * 16 + lrow][ks * 32 + kg * 8];
            acc[tj] = __builtin_amdgcn_mfma_f32_16x16x32_bf16(aq, bk, acc[tj], 0, 0, 0);
        }
    }
    float mx[4] = {-1e30f, -1e30f, -1e30f, -1e30f};
#pragma unroll
    for (int tj = 0; tj < 7; ++tj) {
        bool valid = (tj * 16 + lrow) < L;
#pragma unroll
        for (int r = 0; r < 4; ++r) {
            float v = acc[tj][r] * 0.125f;
            acc[tj][r] = valid ? v : -1e30f;
            if (valid) mx[r] = fmaxf(mx[r], v);
        }
    }
#pragma unroll
    for (int off = 1; off < 16; off <<= 1)
#pragma unroll
        for (int r = 0; r < 4; ++r) mx[r] = fmaxf(mx[r], __shfl_xor(mx[r], off));
    float sum[4] = {0.f, 0.f, 0.f, 0.f};
#pragma unroll
    for (int tj = 0; tj < 7; ++tj)
#pragma unroll
        for (int r = 0; r < 4; ++r) {
            float e = expf(acc[tj][r] - mx[r]);
            acc[tj][r] = e;
            sum[r] += e;
        }
#pragma unroll
    for (int off = 1; off < 16; off <<= 1)
#pragma unroll
        for (int r = 0; r < 4; ++r) sum[r] += __shfl_xor(sum[r], off);
    float inv[4];
#pragma unroll
    for (int r = 0; r < 4; ++r) inv[r] = 1.f / sum[r];
    float* base = out + (size_t)bh * L * L;
#pragma unroll
    for (int r = 0; r < 4; ++r) {
        int row = pass * 64 + wid * 16 + kg * 4 + r;
        if (row >= L) continue;
#pragma unroll
        for (int tj = 0; tj < 7; ++tj) {
            int col = tj * 16 + lrow;
            if (col < L) base[(size_t)row * L + col] = acc[tj][r] * inv[r];
        }
    }
}

// trend combine (Y fp32, row stride 192)
__global__ void trend_combine(const float* __restrict__ Y, const float* __restrict__ xmean,
                              float* __restrict__ dec_out)
{
    int idx = blockIdx.x * 256 + threadIdx.x;
    if (idx >= B * L * COUT) return;
    int o = idx % COUT; int l = (idx / COUT) % L; int b = idx / (COUT * L);
    int lm = (l + L - 1) % L, lp = (l + 1) % L;
    float v = xmean[(size_t)b * CIN + o]
            + Y[((size_t)b * L + lm) * 192 + o]
            + Y[((size_t)b * L + l ) * 192 + 64 + o]
            + Y[((size_t)b * L + lp) * 192 + 128 + o];
    dec_out[idx] = v;
}

// ---------------- forward DFT: bf16 X (row stride in shorts) -> xf (H,MODES,B,E) float2 ----------------
__global__ __launch_bounds__(256) void dft_fwd(const unsigned short* __restrict__ X,
                                               const float* __restrict__ twc, const float* __restrict__ tws,
                                               float2* __restrict__ xf, int stride)
{
    int b = blockIdx.x / H, h = blockIdx.x % H;
    __shared__ float xs[L][E];
    __shared__ float c[L][MODES], s[L][MODES];
    for (int i = threadIdx.x; i < L * E / 4; i += 256) {
        int t = i >> 4, q = i & 15;
        ushort4 u = *(const ushort4*)&X[((size_t)b * L + t) * stride + h * E + q * 4];
        xs[t][q * 4 + 0] = bf2f(u.x);
        xs[t][q * 4 + 1] = bf2f(u.y);
        xs[t][q * 4 + 2] = bf2f(u.z);
        xs[t][q * 4 + 3] = bf2f(u.w);
    }
    for (int i = threadIdx.x; i < L * MODES; i += 256) { c[i / MODES][i % MODES] = twc[i]; s[i / MODES][i % MODES] = tws[i]; }
    __syncthreads();
    for (int o = threadIdx.x; o < E * MODES; o += 256) {
        int m = o / E, e = o % E;
        float re = 0.f, im = 0.f;
        for (int t = 0; t < L; ++t) {
            float v = xs[t][e];
            re += v * c[t][m];
            im -= v * s[t][m];
        }
        xf[((size_t)(h * MODES + m) * B + b) * E + e] = make_float2(re, im);
    }
}

// ---------------- per-(h,m) complex GEMM, in place ----------------
__global__ __launch_bounds__(256) void mode_gemm2(float2* __restrict__ xf, const float2* __restrict__ wt)
{
    int hm = blockIdx.x;
    int bt = blockIdx.y;
    __shared__ float2 Wc[E][E];
    __shared__ float2 Ac[32][E];
    for (int i = threadIdx.x; i < E * E; i += 256) Wc[i / E][i % E] = wt[(size_t)hm * (E * E) + i];
    for (int i = threadIdx.x; i < 32 * E; i += 256)
        Ac[i / E][i % E] = xf[((size_t)hm * B + bt * 32 + i / E) * E + i % E];
    __syncthreads();
    int o = threadIdx.x & 63, bb = threadIdx.x >> 6;
    float2 acc[8];
#pragma unroll
    for (int j = 0; j < 8; ++j) acc[j] = make_float2(0.f, 0.f);
    for (int e = 0; e < E; ++e) {
        float2 w = Wc[e][o];
#pragma unroll
        for (int j = 0; j < 8; ++j) {
            float2 a = Ac[bb * 8 + j][e];
            acc[j].x += a.x * w.x - a.y * w.y;
            acc[j].y += a.x * w.y + a.y * w.x;
        }
    }
#pragma unroll
    for (int j = 0; j < 8; ++j)
        xf[((size_t)hm * B + bt * 32 + bb * 8 + j) * E + o] = acc[j];
}

// iDFT -> bf16 out (B,L,D) head-sliced, scaled
__global__ __launch_bounds__(256) void idft(const float2* __restrict__ sel,
                                            const float* __restrict__ twc, const float* __restrict__ tws,
                                            unsigned short* __restrict__ out, float scale)
{
    int b = blockIdx.x / H, h = blockIdx.x % H;
    __shared__ float2 sc[MODES][E];
    __shared__ float c[L][MODES], s[L][MODES];
    for (int i = threadIdx.x; i < MODES * E; i += 256) {
        int m = i / E, e = i % E;
        sc[m][e] = sel[((size_t)(h * MODES + m) * B + b) * E + e];
    }
    for (int i = threadIdx.x; i < L * MODES; i += 256) { c[i / MODES][i % MODES] = twc[i]; s[i / MODES][i % MODES] = tws[i]; }
    __syncthreads();
    for (int o = threadIdx.x; o < L * E; o += 256) {
        int t = o / E, e = o % E;
        float acc = sc[0][e].x;
        for (int m = 1; m < MODES; ++m)
            acc += 2.f * (sc[m][e].x * c[t][m] - sc[m][e].y * s[t][m]);
        out[((size_t)b * L + t) * D + h * E + e] = f2bf_n(acc * scale);
    }
}

// FourierCross steps 1-2 (fp32 freq domain)
__global__ __launch_bounds__(256) void fourier_qk(const float2* __restrict__ qf, float2* __restrict__ kf)
{
    int b = blockIdx.x / H, h = blockIdx.x % H;
    __shared__ float2 qm[MODES][E + 1], km[MODES][E + 1], vm[MODES][E + 1];
    __shared__ float tr[MODES][MODES + 1], ti[MODES][MODES + 1];
    for (int i = threadIdx.x; i < MODES * E; i += 256) {
        int m = i / E, e = i % E;
        size_t idx = ((size_t)(h * MODES + m) * B + b) * E + e;
        qm[m][e] = qf[idx];
        km[m][e] = kf[idx];
    }
    __syncthreads();
    for (int i = threadIdx.x; i < MODES * MODES; i += 256) {
        int x = i / MODES, y = i % MODES;
        float re = 0.f, im = 0.f;
        for (int e = 0; e < E; ++e) {
            float2 a = qm[x][e], k2 = km[y][e];
            re += a.x * k2.x - a.y * k2.y;
            im += a.x * k2.y + a.y * k2.x;
        }
        float aa = fminf(fmaxf(2.f * re, -30.f), 30.f);
        float b2 = 2.f * im;
        float den = coshf(aa) + cosf(b2);
        tr[x][y] = sinhf(aa) / den;
        ti[x][y] = sinf(b2) / den;
    }
    __syncthreads();
    for (int i = threadIdx.x; i < MODES * E; i += 256) {
        int x = i / E, e = i % E;
        float re = 0.f, im = 0.f;
        for (int y = 0; y < MODES; ++y) {
            float ar = tr[x][y], ai = ti[x][y];
            float2 kk = km[y][e];
            re += ar * kk.x - ai * kk.y;
            im += ar * kk.y + ai * kk.x;
        }
        vm[x][e] = make_float2(re, im);
    }
    __syncthreads();
    for (int i = threadIdx.x; i < MODES * E; i += 256) {
        int m = i / E, e = i % E;
        kf[((size_t)(h * MODES + m) * B + b) * E + e] = vm[m][e];
    }
}

// sigma (bf16 enc input)
__global__ __launch_bounds__(256) void sigma_kernel(const unsigned short* __restrict__ enc,
                                                    const float* __restrict__ w,
                                                    const float* __restrict__ bias, float* __restrict__ sig_out)
{
    __shared__ float wsh[H][D];
    for (int i = threadIdx.x; i < H * D; i += 256) wsh[i / D][i % D] = w[i];
    __syncthreads();
    int wid = threadIdx.x / 64, lane = threadIdx.x % 64;
    int row = blockIdx.x * 4 + wid;
    const unsigned short* p = enc + (size_t)row * D;
    float xv[8];
#pragma unroll
    for (int i = 0; i < 8; ++i) xv[i] = bf2f(p[lane + i * 64]);
    int b = row / L, l = row % L;
#pragma unroll
    for (int h = 0; h < H; ++h) {
        float s = 0.f;
#pragma unroll
        for (int i = 0; i < 8; ++i) s += xv[i] * wsh[h][lane + i * 64];
        for (int off = 32; off; off >>= 1) s += __shfl_xor(s, off);
        if (lane == 0) {
            float acc = s + bias[h];
            float sg = 1.f / (1.f + expf(-5.f * acc));
            float val = expf((sg + 1e-5f) * 1.0986122886681098f) - 1.f; // 3^u - 1
            sig_out[((size_t)b * H + h) * L + l] = val;
        }
    }
}

__global__ void prior_kernel(const float* __restrict__ sig, float* __restrict__ prior)
{
    int idx = blockIdx.x * 256 + threadIdx.x;
    if (idx >= (int)(B * H * L * L)) return;
    int s = idx % L; int l = (idx / L) % L; int bh = idx / (L * L);
    float sg = sig[(size_t)bh * L + l];
    float d = (float)abs(l - s);
    prior[idx] = expf(-d * d / (2.f * sg * sg)) * INV_SQRT_2PI / sg;
}

// series_decomp_multi (bf16 in/out, fp32 trend acc)
__global__ __launch_bounds__(256) void decomp_kernel(const unsigned short* __restrict__ in1,
                                                     const unsigned short* __restrict__ in2,
                                                     const float* __restrict__ w, const float* __restrict__ bc,
                                                     unsigned short* __restrict__ res, float* __restrict__ trend,
                                                     int tmode)
{
    int b = blockIdx.x / (D / 64);
    int d0 = (blockIdx.x % (D / 64)) * 64;
    __shared__ float xs[L][64];
    for (int i = threadIdx.x; i < L * 64; i += 256) {
        int t = i / 64, dd = i % 64;
        size_t g = ((size_t)b * L + t) * D + d0 + dd;
        float v = bf2f(in1[g]);
        if (in2) v += bf2f(in2[g]);
        xs[t][dd] = v;
    }
    __syncthreads();
    float w0 = w[0], w1 = w[1], b0 = bc[0], b1 = bc[1];
    for (int i = threadIdx.x; i < L * 64; i += 256) {
        int l = i / 64, dd = i % 64;
        float s12 = 0.f;
        for (int j = l - 5; j <= l + 6; ++j) s12 += xs[min(max(j, 0), L - 1)][dd];
        float s24 = 0.f;
        for (int j = l - 11; j <= l + 12; ++j) s24 += xs[min(max(j, 0), L - 1)][dd];
        float m0 = s12 * (1.f / 12.f), m1 = s24 * (1.f / 24.f);
        float x = xs[l][dd];
        float z0 = x * w0 + b0, z1 = x * w1 + b1;
        float zm = fmaxf(z0, z1);
        float e0 = expf(z0 - zm), e1 = expf(z1 - zm);
        float p0 = e0 / (e0 + e1);
        float mean = m0 * p0 + m1 * (1.f - p0);
        size_t g = ((size_t)b * L + l) * D + d0 + dd;
        res[g] = f2bf_n(x - mean);
        if (tmode == 1) trend[g] = mean;
        else if (tmode == 2) trend[g] += mean;
    }
}

// row layernorm: bf16 in, fp32 out
__global__ __launch_bounds__(256) void ln_row(const unsigned short* __restrict__ x, const float* __restrict__ g,
                                              const float* __restrict__ bb, float* __restrict__ out)
{
    int row = blockIdx.x;
    const unsigned short* p = x + (size_t)row * D;
    float s = 0.f, s2 = 0.f;
    for (int d = threadIdx.x; d < D; d += 256) { float v = bf2f(p[d]); s += v; s2 += v * v; }
    for (int off = 32; off; off >>= 1) { s += __shfl_xor(s, off); s2 += __shfl_xor(s2, off); }
    __shared__ float red[8];
    int wid = threadIdx.x / 64, lane = threadIdx.x % 64;
    if (lane == 0) { red[wid] = s; red[4 + wid] = s2; }
    __syncthreads();
    if (threadIdx.x == 0) {
        red[0] = red[0] + red[1] + red[2] + red[3];
        red[4] = red[4] + red[5] + red[6] + red[7];
    }
    __syncthreads();
    float mu = red[0] / (float)D;
    float var = red[4] / (float)D - mu * mu;
    float rstd = rsqrtf(var + 1e-5f);
    for (int d = threadIdx.x; d < D; d += 256)
        out[(size_t)row * D + d] = (bf2f(p[d]) - mu) * rstd * g[d] + bb[d];
}

// column-mean subtract: fp32 in, bf16 out; grid (B * D/128), 256 threads
__global__ __launch_bounds__(256) void col_sub(const float* __restrict__ xh, unsigned short* __restrict__ out)
{
    int b = blockIdx.x / (D / 128);
    int d0 = (blockIdx.x % (D / 128)) * 128;
    int c = threadIdx.x & 127, half = threadIdx.x >> 7;
    __shared__ float red[2][128];
    float s = 0.f;
    for (int l = half * 50; l < half * 50 + 50; ++l)
        s += xh[((size_t)b * L + l) * D + d0 + c];
    red[half][c] = s;
    __syncthreads();
    float mean = (red[0][c] + red[1][c]) * (1.f / (float)L);
    for (int l = half * 50; l < half * 50 + 50; ++l) {
        size_t g = ((size_t)b * L + l) * D + d0 + c;
        out[g] = f2bf_n(xh[g] - mean);
    }
}

extern "C" void kernel_launch(void* const* d_in, const int* in_sizes, int n_in,
                              void* d_out, int out_size, void* d_ws, size_t ws_size,
                              hipStream_t stream)
{
    const float* x           = (const float*)d_in[0];
    const float* emb_enc_w   = (const float*)d_in[1];
    const float* emb_dec_w   = (const float*)d_in[2];
    const float* enc_proj_w  = (const float*)d_in[3];
    const float* enc_proj_b  = (const float*)d_in[4];
    const float* enc_sig_w   = (const float*)d_in[5];
    const float* enc_sig_b   = (const float*)d_in[6];
    const float* enc_four_wr = (const float*)d_in[7];
    const float* enc_four_wi = (const float*)d_in[8];
    const float* enc_ffn_w1  = (const float*)d_in[9];
    const float* enc_ffn_w2  = (const float*)d_in[10];
    const float* enc_dcmp_w  = (const float*)d_in[11];
    const float* enc_dcmp_b  = (const float*)d_in[12];
    const float* enc_norm_g  = (const float*)d_in[13];
    const float* enc_norm_b  = (const float*)d_in[14];
    const float* dec_proj_w  = (const float*)d_in[15];
    const float* dec_proj_b  = (const float*)d_in[16];
    const float* dec_four_wr = (const float*)d_in[17];
    const float* dec_four_wi = (const float*)d_in[18];
    const float* crs_proj_w  = (const float*)d_in[19];
    const float* crs_proj_b  = (const float*)d_in[20];
    const float* crs_four_wr = (const float*)d_in[21];
    const float* crs_four_wi = (const float*)d_in[22];
    const float* dec_ffn_w1  = (const float*)d_in[23];
    const float* dec_ffn_w2  = (const float*)d_in[24];
    const float* dec_dcmp_w  = (const float*)d_in[25];
    const float* dec_dcmp_b  = (const float*)d_in[26];
    const float* dec_trend_w = (const float*)d_in[27];
    const float* dec_norm_g  = (const float*)d_in[28];
    const float* dec_norm_b  = (const float*)d_in[29];
    const float* out_proj_w  = (const float*)d_in[30];
    const float* out_proj_b  = (const float*)d_in[31];

    float* ws = (float*)d_ws;
    size_t off = 0;
    float* pe    = ws + off; off += (size_t)L * D;
    float* twc   = ws + off; off += (size_t)L * MODES;
    float* tws_  = ws + off; off += (size_t)L * MODES;
    float* xmean = ws + off; off += (size_t)B * CIN;
    float* bufF  = ws + off; off += BLD;           // fp32 scratch (ln out / trend Y)
    float* tacc  = ws + off; off += BLD;           // fp32 trend accumulator
    float2* xfc  = (float2*)(ws + off); off += 2 * BHEM;
    float2* kfc  = (float2*)(ws + off); off += 2 * BHEM;
    float2* wtb  = (float2*)(ws + off); off += 2 * (size_t)H * MODES * E * E;
    // bf16 activation buffers
    unsigned short* qk16 = (unsigned short*)(ws + off); off += BLD;        // 2*BLD shorts (q|k fused, stride 1024)
    unsigned short* e16  = (unsigned short*)(ws + off); off += BLD / 2;
    unsigned short* c16  = (unsigned short*)(ws + off); off += BLD / 2;
    unsigned short* d16  = (unsigned short*)(ws + off); off += BLD / 2;
    unsigned short* h16  = (unsigned short*)(ws + off); off += BLD / 2;
    unsigned short* t16  = (unsigned short*)(ws + off); off += BLD / 2;
    unsigned short* im16 = (unsigned short*)(ws + off); off += (size_t)M_ROWS * KEMB / 2;
    // bf16 weights
    unsigned short* wbf_encproj = (unsigned short*)(ws + off); off += (size_t)2 * 4 * D * D / 2;
    unsigned short* wbf_ffn1    = (unsigned short*)(ws + off); off += (size_t)2 * DFF * D / 2;
    unsigned short* wbf_ffn2    = (unsigned short*)(ws + off); off += (size_t)2 * D * DFF / 2;
    unsigned short* wbf_decproj = (unsigned short*)(ws + off); off += (size_t)4 * D * D / 2;
    unsigned short* wbf_crsproj = (unsigned short*)(ws + off); off += (size_t)4 * D * D / 2;
    unsigned short* wbf_dffn1   = (unsigned short*)(ws + off); off += (size_t)DFF * D / 2;
    unsigned short* wbf_dffn2   = (unsigned short*)(ws + off); off += (size_t)D * DFF / 2;
    unsigned short* wbf_embenc  = (unsigned short*)(ws + off); off += (size_t)D * KEMB / 2;
    unsigned short* wbf_embdec  = (unsigned short*)(ws + off); off += (size_t)D * KEMB / 2;
    unsigned short* wbf_trd     = (unsigned short*)(ws + off); off += (size_t)192 * D / 2;
    unsigned short* wbf_seas    = (unsigned short*)(ws + off); off += (size_t)64 * D / 2;
    unsigned short* a16 = qk16;               // decoder reuse of qk region
    unsigned short* b16 = qk16 + BLD;

    float* out       = (float*)d_out;
    float* dec_out   = out;
    float* series_out= out + (size_t)B * L * COUT;
    float* prior_out = series_out + 2 * BHLL;
    float* sigma_out = prior_out + 2 * BHLL;

    const int BH = B * H;

    init_consts<<<200, 256, 0, stream>>>(pe, twc, tws_);
    xmean_kernel<<<cdiv(B * CIN, 256), 256, 0, stream>>>(x, xmean);
    to_bf16<<<cdiv(2 * 4 * D * D / 4, 256), 256, 0, stream>>>(enc_proj_w, wbf_encproj, 2 * 4 * D * D / 4);
    to_bf16<<<cdiv(2 * DFF * D / 4, 256), 256, 0, stream>>>(enc_ffn_w1, wbf_ffn1, 2 * DFF * D / 4);
    to_bf16<<<cdiv(2 * D * DFF / 4, 256), 256, 0, stream>>>(enc_ffn_w2, wbf_ffn2, 2 * D * DFF / 4);
    to_bf16<<<cdiv(4 * D * D / 4, 256), 256, 0, stream>>>(dec_proj_w, wbf_decproj, 4 * D * D / 4);
    to_bf16<<<cdiv(4 * D * D / 4, 256), 256, 0, stream>>>(crs_proj_w, wbf_crsproj, 4 * D * D / 4);
    to_bf16<<<cdiv(DFF * D / 4, 256), 256, 0, stream>>>(dec_ffn_w1, wbf_dffn1, DFF * D / 4);
    to_bf16<<<cdiv(D * DFF / 4, 256), 256, 0, stream>>>(dec_ffn_w2, wbf_dffn2, D * DFF / 4);
    pad_rows_bf<<<cdiv(D * KEMB, 256), 256, 0, stream>>>(emb_enc_w, wbf_embenc, D, D, CIN * 3, KEMB);
    pad_rows_bf<<<cdiv(D * KEMB, 256), 256, 0, stream>>>(emb_dec_w, wbf_embdec, D, D, CIN * 3, KEMB);
    pad_trend_w2_bf<<<cdiv(192 * D, 256), 256, 0, stream>>>(dec_trend_w, wbf_trd);
    pad_rows_bf<<<cdiv(64 * D, 256), 256, 0, stream>>>(out_proj_w, wbf_seas, COUT, 64, D, D);
    transpose_w<<<H * E, 256, 0, stream>>>(enc_four_wr, enc_four_wi, wtb);

    auto gemm = [&](const unsigned short* A, const unsigned short* Wb, const float* bias, const float* pe_,
                    float* C, unsigned short* Cb, int N, int Nout, int K, int act, int accum) {
        if (N % 128 == 0) {
            dim3 grid(N / 128, M_ROWS / 128);
            gemm_mfma<128><<<grid, 256, 0, stream>>>(A, Wb, bias, pe_, C, Cb, Nout, K, act, accum);
        } else {
            dim3 grid(N / 64, M_ROWS / 128);
            gemm_mfma<64><<<grid, 256, 0, stream>>>(A, Wb, bias, pe_, C, Cb, Nout, K, act, accum);
        }
    };
    dim3 mg_grid(H * MODES, B / 32);
    dim3 sc_grid(BH, 2);

    // encoder embedding
    im2col_emb<<<cdiv(M_ROWS * KEMB, 256), 256, 0, stream>>>(x, nullptr, im16);
    gemm(im16, wbf_embenc, nullptr, pe, nullptr, e16, D, D, KEMB, 0, 0);

    for (int i = 0; i < 2; ++i) {
        const unsigned short* Wp = wbf_encproj + (size_t)i * 4 * D * D;
        const float* bp = enc_proj_b + (size_t)i * 4 * D;
        float* series_i = series_out + (size_t)i * BHLL;
        float* prior_i  = prior_out  + (size_t)i * BHLL;
        float* sigma_i  = sigma_out  + (size_t)i * B * H * L;

        gemm(e16, Wp, bp, nullptr, nullptr, qk16, 1024, 1024, D, 0, 0);       // fused q+k
        dft_fwd<<<BH, 256, 0, stream>>>(qk16, twc, tws_, xfc, 1024);
        mode_gemm2<<<mg_grid, 256, 0, stream>>>(xfc, wtb);
        idft<<<BH, 256, 0, stream>>>(xfc, twc, tws_, c16, 1.f / (float)L);
        gemm(c16, Wp + (size_t)3 * D * D, bp + 3 * D, nullptr, nullptr, d16, D, D, D, 0, 0); // attn_out
        scores_softmax<<<sc_grid, 256, 0, stream>>>(qk16, series_i);
        sigma_kernel<<<M_ROWS / 4, 256, 0, stream>>>(e16, enc_sig_w + (size_t)i * H * D,
                                                     enc_sig_b + (size_t)i * H, sigma_i);
        prior_kernel<<<cdiv((int)BHLL, 256), 256, 0, stream>>>(sigma_i, prior_i);
        decomp_kernel<<<B * (D / 64), 256, 0, stream>>>(e16, d16, enc_dcmp_w + (size_t)(i * 2 + 0) * NK,
                                                        enc_dcmp_b + (size_t)(i * 2 + 0) * NK, h16, nullptr, 0);
        gemm(h16, wbf_ffn1 + (size_t)i * DFF * D, nullptr, nullptr, nullptr, c16, DFF, DFF, D, 1, 0);
        gemm(c16, wbf_ffn2 + (size_t)i * D * DFF, nullptr, nullptr, nullptr, d16, D, D, DFF, 0, 0);
        decomp_kernel<<<B * (D / 64), 256, 0, stream>>>(h16, d16, enc_dcmp_w + (size_t)(i * 2 + 1) * NK,
                                                        enc_dcmp_b + (size_t)(i * 2 + 1) * NK, e16, nullptr, 0);
    }
    // encoder final my_layernorm
    ln_row<<<M_ROWS, 256, 0, stream>>>(e16, enc_norm_g, enc_norm_b, bufF);
    col_sub<<<B * (D / 128), 256, 0, stream>>>(bufF, e16);

    // ---------------- decoder ----------------
    transpose_w<<<H * E, 256, 0, stream>>>(dec_four_wr, dec_four_wi, wtb);
    im2col_emb<<<cdiv(M_ROWS * KEMB, 256), 256, 0, stream>>>(x, xmean, im16);
    gemm(im16, wbf_embdec, nullptr, pe, nullptr, a16, D, D, KEMB, 0, 0);           // dec
    gemm(a16, wbf_decproj, dec_proj_b, nullptr, nullptr, b16, D, D, D, 0, 0);      // q
    dft_fwd<<<BH, 256, 0, stream>>>(b16, twc, tws_, xfc, D);
    mode_gemm2<<<mg_grid, 256, 0, stream>>>(xfc, wtb);
    idft<<<BH, 256, 0, stream>>>(xfc, twc, tws_, c16, 1.f / (float)L);
    gemm(c16, wbf_decproj + (size_t)3 * D * D, dec_proj_b + 3 * D, nullptr, nullptr, d16, D, D, D, 0, 0); // sa
    decomp_kernel<<<B * (D / 64), 256, 0, stream>>>(a16, d16, dec_dcmp_w, dec_dcmp_b, h16, tacc, 1); // h, t1

    gemm(h16, wbf_crsproj, crs_proj_b, nullptr, nullptr, b16, D, D, D, 0, 0);      // qc
    dft_fwd<<<BH, 256, 0, stream>>>(b16, twc, tws_, xfc, D);                       // qf
    gemm(e16, wbf_crsproj + (size_t)D * D, crs_proj_b + D, nullptr, nullptr, b16, D, D, D, 0, 0); // kc
    dft_fwd<<<BH, 256, 0, stream>>>(b16, twc, tws_, kfc, D);                       // kf
    transpose_w<<<H * E, 256, 0, stream>>>(crs_four_wr, crs_four_wi, wtb);
    fourier_qk<<<BH, 256, 0, stream>>>(xfc, kfc);                                  // kfc := qkv
    mode_gemm2<<<mg_grid, 256, 0, stream>>>(kfc, wtb);
    idft<<<BH, 256, 0, stream>>>(kfc, twc, tws_, c16, 1.f / ((float)L * (float)D * (float)D));
    gemm(c16, wbf_crsproj + (size_t)3 * D * D, crs_proj_b + 3 * D, nullptr, nullptr, d16, D, D, D, 0, 0); // ca
    decomp_kernel<<<B * (D / 64), 256, 0, stream>>>(h16, d16, dec_dcmp_w + NK, dec_dcmp_b + NK, a16, tacc, 2); // h2, t2

    gemm(a16, wbf_dffn1, nullptr, nullptr, nullptr, c16, DFF, DFF, D, 1, 0);
    gemm(c16, wbf_dffn2, nullptr, nullptr, nullptr, d16, D, D, DFF, 0, 0);
    decomp_kernel<<<B * (D / 64), 256, 0, stream>>>(a16, d16, dec_dcmp_w + 2 * NK, dec_dcmp_b + 2 * NK, b16, tacc, 2); // h3, t3

    // trend conv: bf16 tacc copy -> stacked-tap GEMM (K=512, N=192, fp32 out) -> combine
    to_bf16<<<cdiv((int)(BLD / 4), 256), 256, 0, stream>>>(tacc, t16, (int)(BLD / 4));
    gemm(t16, wbf_trd, nullptr, nullptr, bufF, nullptr, 192, 192, D, 0, 0);
    trend_combine<<<cdiv(B * L * COUT, 256), 256, 0, stream>>>(bufF, xmean, dec_out);

    // final layernorm + seasonal projection accumulated into dec_out
    ln_row<<<M_ROWS, 256, 0, stream>>>(b16, dec_norm_g, dec_norm_b, bufF);
    col_sub<<<B * (D / 128), 256, 0, stream>>>(bufF, d16);
    gemm(d16, wbf_seas, out_proj_b, nullptr, dec_out, nullptr, 64, COUT, D, 0, 1);
}

// Round 9
// 1328.431 us; speedup vs baseline: 6.9227x; 1.4049x over previous
//
#include <hip/hip_runtime.h>
#include <hip/hip_bf16.h>
#include <cmath>

constexpr int B = 128, L = 100, CIN = 55, COUT = 55;
constexpr int D = 512, H = 8, DFF = 512, MODES = 32, E = 64;
constexpr int NK = 2;
constexpr int M_ROWS = B * L; // 12800
constexpr int KEMB = 192;     // 55*3=165 padded to 32*6
constexpr size_t BLD  = (size_t)B * L * D;         // 6,553,600
constexpr size_t BHEM = (size_t)B * H * E * MODES; // 2,097,152 complex elems
constexpr size_t BHLL = (size_t)B * H * L * L;     // 10,240,000
constexpr float INV_SQRT_2PI = 0.3989422804014327f;

static inline int cdiv(int a, int b) { return (a + b - 1) / b; }

typedef short shortx8 __attribute__((ext_vector_type(8)));
typedef float f32x4 __attribute__((ext_vector_type(4)));

__device__ inline unsigned short f2bf(float f)    // RNE (weight prep)
{
    unsigned int u = __float_as_uint(f);
    unsigned int r = (u + 0x7FFFu + ((u >> 16) & 1u)) >> 16;
    return (unsigned short)r;
}
__device__ inline unsigned short f2bf_n(float f)  // native cvt
{
    union { __hip_bfloat16 h; unsigned short u; } cv;
    cv.h = __float2bfloat16(f);
    return cv.u;
}
__device__ inline float bf2f(unsigned short u)
{
    union { unsigned int i; float f; } c;
    c.i = (unsigned int)u << 16;
    return c.f;
}

// ---------------- constants ----------------
__global__ void init_consts(float* __restrict__ pe, float* __restrict__ twc, float* __restrict__ tws)
{
    int idx = blockIdx.x * 256 + threadIdx.x;
    if (idx < L * D) {
        int l = idx / D, d = idx % D;
        int i2 = d & ~1;
        float div = expf((float)i2 * (-logf(10000.f) / (float)D));
        float ang = (float)l * div;
        pe[idx] = (d & 1) ? cosf(ang) : sinf(ang);
    }
    if (idx < L * MODES) {
        int t = idx / MODES, m = idx % MODES;
        float th = 2.f * 3.14159265358979323846f * (float)m * (float)t / (float)L;
        twc[idx] = cosf(th);
        tws[idx] = sinf(th);
    }
}

// bf16 twiddle tables for MFMA DFT/iDFT
// twf [64][128]: m'<32: cos(2pi m' t / L); m'>=32: -sin(2pi (m'-32) t / L); t>=L: 0
// twi [128][64]: t row; m'=0: 1; m'<32: 2cos; m'=32: 0; m'>32: -2sin; t>=L rows: 0
__global__ void init_tw(unsigned short* __restrict__ twf, unsigned short* __restrict__ twi)
{
    int idx = blockIdx.x * 256 + threadIdx.x;
    if (idx >= 64 * 128) return;
    {
        int mp = idx / 128, t = idx % 128;
        float v = 0.f;
        if (t < L) {
            if (mp < 32) v = cosf(2.f * 3.14159265358979323846f * (float)mp * (float)t / (float)L);
            else v = -sinf(2.f * 3.14159265358979323846f * (float)(mp - 32) * (float)t / (float)L);
        }
        twf[idx] = f2bf(v);
    }
    {
        int t = idx / 64, mp = idx % 64;
        float v = 0.f;
        if (t < L) {
            if (mp == 0) v = 1.f;
            else if (mp < 32) v = 2.f * cosf(2.f * 3.14159265358979323846f * (float)mp * (float)t / (float)L);
            else if (mp == 32) v = 0.f;
            else v = -2.f * sinf(2.f * 3.14159265358979323846f * (float)(mp - 32) * (float)t / (float)L);
        }
        twi[idx] = f2bf(v);
    }
}

__global__ void xmean_kernel(const float* __restrict__ x, float* __restrict__ xm)
{
    int idx = blockIdx.x * 256 + threadIdx.x;
    if (idx >= B * CIN) return;
    int b = idx / CIN, c = idx % CIN;
    float s = 0.f;
    for (int l = 0; l < L; ++l) s += x[((size_t)b * L + l) * CIN + c];
    xm[idx] = s * (1.f / (float)L);
}

// f32 -> bf16 bulk conversion (n multiple of 4)
__global__ void to_bf16(const float* __restrict__ src, unsigned short* __restrict__ dst, int n4)
{
    int i = blockIdx.x * 256 + threadIdx.x;
    if (i >= n4) return;
    float4 v = *(const float4*)&src[(size_t)i * 4];
    ushort4 h;
    h.x = f2bf(v.x); h.y = f2bf(v.y); h.z = f2bf(v.z); h.w = f2bf(v.w);
    *(ushort4*)&dst[(size_t)i * 4] = h;
}

__global__ void pad_rows_bf(const float* __restrict__ src, unsigned short* __restrict__ dst,
                            int rows_src, int rows_dst, int k_src, int k_dst)
{
    int idx = blockIdx.x * 256 + threadIdx.x;
    if (idx >= rows_dst * k_dst) return;
    int r = idx / k_dst, k = idx % k_dst;
    dst[idx] = (r < rows_src && k < k_src) ? f2bf(src[(size_t)r * k_src + k]) : (unsigned short)0;
}

__global__ void pad_trend_w2_bf(const float* __restrict__ src, unsigned short* __restrict__ dst)
{
    int idx = blockIdx.x * 256 + threadIdx.x;
    if (idx >= 192 * D) return;
    int n = idx / D, d = idx % D;
    int j = n / 64, o = n % 64;
    dst[idx] = (o < COUT) ? f2bf(src[(size_t)o * (D * 3) + d * 3 + j]) : (unsigned short)0;
}

__global__ __launch_bounds__(256) void transpose_w(const float* __restrict__ wr, const float* __restrict__ wi,
                                                   float2* __restrict__ wt)
{
    int h = blockIdx.x / E, e = blockIdx.x % E;
    __shared__ float tr[64][33], ti[64][33];
    for (int i = threadIdx.x; i < E * MODES; i += 256) {
        int o = i / MODES, m = i % MODES;
        size_t s = (((size_t)h * E + e) * E + o) * MODES + m;
        tr[o][m] = wr[s]; ti[o][m] = wi[s];
    }
    __syncthreads();
    for (int i = threadIdx.x; i < MODES * E; i += 256) {
        int m = i / E, o = i % E;
        wt[(((size_t)h * MODES + m) * E + e) * E + o] = make_float2(tr[o][m], ti[o][m]);
    }
}

// im2col for kernel-3 circular conv: bf16 out
__global__ void im2col_emb(const float* __restrict__ x, const float* __restrict__ xmean,
                           unsigned short* __restrict__ A2)
{
    int idx = blockIdx.x * 256 + threadIdx.x;
    if (idx >= M_ROWS * KEMB) return;
    int k = idx % KEMB, m = idx / KEMB;
    float v = 0.f;
    if (k < CIN * 3) {
        int c = k / 3, j = k % 3;
        int l = m % L, b = m / L;
        int ls = l + j - 1; ls = (ls + L) % L;
        v = x[((size_t)b * L + ls) * CIN + c];
        if (xmean) v -= xmean[(size_t)b * CIN + c];
    }
    A2[idx] = f2bf(v);
}

// ---------------- bf16 MFMA GEMM: bf16 A and W, fp32 or bf16 out ----------------
template<int BN>
__global__ __launch_bounds__(256) void gemm_mfma(const unsigned short* __restrict__ A,
                                                 const unsigned short* __restrict__ Wb,
                                                 const float* __restrict__ bias, const float* __restrict__ pe,
                                                 float* __restrict__ C, unsigned short* __restrict__ Cb,
                                                 int Nout, int K, int act, int accum)
{
    constexpr int NI = BN / 32;
    constexpr int BI = BN / 64;
    __shared__ unsigned short As[128][40];
    __shared__ unsigned short Bs[BN][40];
    int tid = threadIdx.x;
    int row0 = blockIdx.y * 128, col0 = blockIdx.x * BN;
    int wid = tid >> 6, lane = tid & 63;
    int wm = wid >> 1, wn = wid & 1;
    int lrow = lane & 15, kg = lane >> 4;
    int ar = tid >> 2, ac8 = (tid & 3) * 8;
    f32x4 acc[4][NI] = {};
    shortx8 rah[2], rbh[BI];

    auto loadG = [&](int k0) {
#pragma unroll
        for (int p = 0; p < 2; ++p)
            rah[p] = *(const shortx8*)&A[(size_t)(row0 + p * 64 + ar) * K + k0 + ac8];
#pragma unroll
        for (int p = 0; p < BI; ++p)
            rbh[p] = *(const shortx8*)&Wb[(size_t)(col0 + p * 64 + ar) * K + k0 + ac8];
    };
    auto storeLDS = [&]() {
#pragma unroll
        for (int p = 0; p < 2; ++p)
            *(shortx8*)&As[p * 64 + ar][ac8] = rah[p];
#pragma unroll
        for (int p = 0; p < BI; ++p)
            *(shortx8*)&Bs[p * 64 + ar][ac8] = rbh[p];
    };

    loadG(0);
    for (int k0 = 0; ; ) {
        __syncthreads();
        storeLDS();
        __syncthreads();
        int kn = k0 + 32;
        if (kn < K) loadG(kn);    // next-tile loads hide under MFMA below
        shortx8 av[4], bv[NI];
#pragma unroll
        for (int mi = 0; mi < 4; ++mi)
            av[mi] = *(const shortx8*)&As[wm * 64 + mi * 16 + lrow][kg * 8];
#pragma unroll
        for (int ni = 0; ni < NI; ++ni)
            bv[ni] = *(const shortx8*)&Bs[wn * (BN / 2) + ni * 16 + lrow][kg * 8];
#pragma unroll
        for (int mi = 0; mi < 4; ++mi)
#pragma unroll
            for (int ni = 0; ni < NI; ++ni)
                acc[mi][ni] = __builtin_amdgcn_mfma_f32_16x16x32_bf16(av[mi], bv[ni], acc[mi][ni], 0, 0, 0);
        k0 = kn;
        if (k0 >= K) break;
    }
#pragma unroll
    for (int mi = 0; mi < 4; ++mi) {
#pragma unroll
        for (int ni = 0; ni < NI; ++ni) {
            int col = col0 + wn * (BN / 2) + ni * 16 + lrow;
            if (col >= Nout) continue;
#pragma unroll
            for (int r = 0; r < 4; ++r) {
                int row = row0 + wm * 64 + mi * 16 + kg * 4 + r;
                float v = acc[mi][ni][r];
                if (bias) v += bias[col];
                if (pe) v += pe[(size_t)(row % L) * Nout + col];
                if (act) v = 0.5f * v * (1.f + erff(v * 0.70710678118654752f));
                size_t o = (size_t)row * Nout + col;
                if (Cb) Cb[o] = f2bf_n(v);
                else if (accum) C[o] += v;
                else C[o] = v;
            }
        }
    }
}

// ---------------- fused QK^T/8 + row-softmax (bf16 input, row stride 1024) ----------------
__global__ __launch_bounds__(256) void scores_softmax(const unsigned short* __restrict__ QK,
                                                      float* __restrict__ out)
{
    int bh = blockIdx.x, b = bh / H, h = bh % H;
    int pass = blockIdx.y;
    __shared__ unsigned short Ks[112][72];
    __shared__ unsigned short Qs[64][72];
    int tid = threadIdx.x;
    int srow = tid >> 4, sc4 = (tid & 15) * 4;
#pragma unroll
    for (int i = 0; i < 7; ++i) {
        int r = i * 16 + srow;
        ushort4 hh = {0, 0, 0, 0};
        if (r < L) hh = *(const ushort4*)&QK[((size_t)b * L + r) * 1024 + 512 + h * E + sc4];
        *(ushort4*)&Ks[r][sc4] = hh;
    }
#pragma unroll
    for (int i = 0; i < 4; ++i) {
        int r = i * 16 + srow;
        int gr = pass * 64 + r;
        ushort4 hh = {0, 0, 0, 0};
        if (gr < L) hh = *(const ushort4*)&QK[((size_t)b * L + gr) * 1024 + h * E + sc4];
        *(ushort4*)&Qs[r][sc4] = hh;
    }
    __syncthreads();
    int wid = tid >> 6, lane = tid & 63;
    int lrow = lane & 15, kg = lane >> 4;
    f32x4 acc[7] = {};
#pragma unroll
    for (int ks = 0; ks < 2; ++ks) {
        shortx8 aq = *(const shortx8*)&Qs[wid * 16 + lrow][ks * 32 + kg * 8];
#pragma unroll
        for (int tj = 0; tj < 7; ++tj) {
            shortx8 bk = *(const shortx8*)&Ks[tj * 16 + lrow][ks * 32 + kg * 8];
            acc[tj] = __builtin_amdgcn_mfma_f32_16x16x32_bf16(aq, bk, acc[tj], 0, 0, 0);
        }
    }
    float mx[4] = {-1e30f, -1e30f, -1e30f, -1e30f};
#pragma unroll
    for (int tj = 0; tj < 7; ++tj) {
        bool valid = (tj * 16 + lrow) < L;
#pragma unroll
        for (int r = 0; r < 4; ++r) {
            float v = acc[tj][r] * 0.125f;
            acc[tj][r] = valid ? v : -1e30f;
            if (valid) mx[r] = fmaxf(mx[r], v);
        }
    }
#pragma unroll
    for (int off = 1; off < 16; off <<= 1)
#pragma unroll
        for (int r = 0; r < 4; ++r) mx[r] = fmaxf(mx[r], __shfl_xor(mx[r], off));
    float sum[4] = {0.f, 0.f, 0.f, 0.f};
#pragma unroll
    for (int tj = 0; tj < 7; ++tj)
#pragma unroll
        for (int r = 0; r < 4; ++r) {
            float e = expf(acc[tj][r] - mx[r]);
            acc[tj][r] = e;
            sum[r] += e;
        }
#pragma unroll
    for (int off = 1; off < 16; off <<= 1)
#pragma unroll
        for (int r = 0; r < 4; ++r) sum[r] += __shfl_xor(sum[r], off);
    float inv[4];
#pragma unroll
    for (int r = 0; r < 4; ++r) inv[r] = 1.f / sum[r];
    float* base = out + (size_t)bh * L * L;
#pragma unroll
    for (int r = 0; r < 4; ++r) {
        int row = pass * 64 + wid * 16 + kg * 4 + r;
        if (row >= L) continue;
#pragma unroll
        for (int tj = 0; tj < 7; ++tj) {
            int col = tj * 16 + lrow;
            if (col < L) base[(size_t)row * L + col] = acc[tj][r] * inv[r];
        }
    }
}

// trend combine (Y fp32, row stride 192)
__global__ void trend_combine(const float* __restrict__ Y, const float* __restrict__ xmean,
                              float* __restrict__ dec_out)
{
    int idx = blockIdx.x * 256 + threadIdx.x;
    if (idx >= B * L * COUT) return;
    int o = idx % COUT; int l = (idx / COUT) % L; int b = idx / (COUT * L);
    int lm = (l + L - 1) % L, lp = (l + 1) % L;
    float v = xmean[(size_t)b * CIN + o]
            + Y[((size_t)b * L + lm) * 192 + o]
            + Y[((size_t)b * L + l ) * 192 + 64 + o]
            + Y[((size_t)b * L + lp) * 192 + 128 + o];
    dec_out[idx] = v;
}

// ---------------- MFMA forward DFT: C[m'][e] = twf[m'][t] * X^T[e][t] per (b,h) ----------------
__global__ __launch_bounds__(256) void dft_mfma(const unsigned short* __restrict__ X,
                                                const unsigned short* __restrict__ twf,
                                                float2* __restrict__ xf, int stride)
{
    int b = blockIdx.x / H, h = blockIdx.x % H;
    __shared__ unsigned short Xs[64][136];   // [e][t], t padded to 128
    int tid = threadIdx.x;
    for (int i = tid; i < L * E / 4; i += 256) {
        int t = i >> 4, e4 = (i & 15) * 4;
        ushort4 u = *(const ushort4*)&X[((size_t)b * L + t) * stride + h * E + e4];
        Xs[e4][t] = u.x; Xs[e4 + 1][t] = u.y; Xs[e4 + 2][t] = u.z; Xs[e4 + 3][t] = u.w;
    }
    for (int i = tid; i < 64 * 28; i += 256) {
        int e = i / 28, t = L + i % 28;
        Xs[e][t] = 0;
    }
    __syncthreads();
    int wid = tid >> 6, lane = tid & 63;
    int lrow = lane & 15, kg = lane >> 4;
    f32x4 acc[4] = {};
#pragma unroll
    for (int k0 = 0; k0 < 4; ++k0) {
        shortx8 bx = *(const shortx8*)&Xs[wid * 16 + lrow][k0 * 32 + kg * 8];
#pragma unroll
        for (int mi = 0; mi < 4; ++mi) {
            shortx8 aw = *(const shortx8*)&twf[(size_t)(mi * 16 + lrow) * 128 + k0 * 32 + kg * 8];
            acc[mi] = __builtin_amdgcn_mfma_f32_16x16x32_bf16(aw, bx, acc[mi], 0, 0, 0);
        }
    }
    int e = wid * 16 + lrow;
#pragma unroll
    for (int mi = 0; mi < 2; ++mi)
#pragma unroll
        for (int r = 0; r < 4; ++r) {
            int m = mi * 16 + kg * 4 + r;
            xf[((size_t)(h * MODES + m) * B + b) * E + e] = make_float2(acc[mi][r], acc[mi + 2][r]);
        }
}

// ---------------- MFMA iDFT: C[t][o] = twi[t][m'] * S[o][m'] per (b,h), scaled, bf16 out ----------------
__global__ __launch_bounds__(256) void idft_mfma(const float2* __restrict__ sel,
                                                 const unsigned short* __restrict__ twi,
                                                 unsigned short* __restrict__ out, float scale)
{
    int b = blockIdx.x / H, h = blockIdx.x % H;
    __shared__ unsigned short Ss[64][72];    // [o][m'], m' = 32 re + 32 im
    int tid = threadIdx.x;
    for (int i = tid; i < MODES * E; i += 256) {
        int m = i >> 6, o = i & 63;
        float2 v = sel[((size_t)(h * MODES + m) * B + b) * E + o];
        Ss[o][m] = f2bf_n(v.x);
        Ss[o][m + 32] = f2bf_n(v.y);
    }
    __syncthreads();
    int wid = tid >> 6, lane = tid & 63;
    int lrow = lane & 15, kg = lane >> 4;
    f32x4 acc[2][4] = {};
#pragma unroll
    for (int k0 = 0; k0 < 2; ++k0) {
        shortx8 bs[4];
#pragma unroll
        for (int ni = 0; ni < 4; ++ni)
            bs[ni] = *(const shortx8*)&Ss[ni * 16 + lrow][k0 * 32 + kg * 8];
#pragma unroll
        for (int ti = 0; ti < 2; ++ti) {
            shortx8 at = *(const shortx8*)&twi[(size_t)((wid * 2 + ti) * 16 + lrow) * 64 + k0 * 32 + kg * 8];
#pragma unroll
            for (int ni = 0; ni < 4; ++ni)
                acc[ti][ni] = __builtin_amdgcn_mfma_f32_16x16x32_bf16(at, bs[ni], acc[ti][ni], 0, 0, 0);
        }
    }
#pragma unroll
    for (int ti = 0; ti < 2; ++ti)
#pragma unroll
        for (int ni = 0; ni < 4; ++ni)
#pragma unroll
            for (int r = 0; r < 4; ++r) {
                int t = (wid * 2 + ti) * 16 + kg * 4 + r;
                if (t < L) {
                    int o = ni * 16 + lrow;
                    out[((size_t)b * L + t) * D + h * E + o] = f2bf_n(acc[ti][ni][r] * scale);
                }
            }
}

// ---------------- per-(h,m) complex GEMM, in place ----------------
__global__ __launch_bounds__(256) void mode_gemm2(float2* __restrict__ xf, const float2* __restrict__ wt)
{
    int hm = blockIdx.x;
    int bt = blockIdx.y;
    __shared__ float2 Wc[E][E];
    __shared__ float2 Ac[32][E];
    for (int i = threadIdx.x; i < E * E; i += 256) Wc[i / E][i % E] = wt[(size_t)hm * (E * E) + i];
    for (int i = threadIdx.x; i < 32 * E; i += 256)
        Ac[i / E][i % E] = xf[((size_t)hm * B + bt * 32 + i / E) * E + i % E];
    __syncthreads();
    int o = threadIdx.x & 63, bb = threadIdx.x >> 6;
    float2 acc[8];
#pragma unroll
    for (int j = 0; j < 8; ++j) acc[j] = make_float2(0.f, 0.f);
    for (int e = 0; e < E; ++e) {
        float2 w = Wc[e][o];
#pragma unroll
        for (int j = 0; j < 8; ++j) {
            float2 a = Ac[bb * 8 + j][e];
            acc[j].x += a.x * w.x - a.y * w.y;
            acc[j].y += a.x * w.y + a.y * w.x;
        }
    }
#pragma unroll
    for (int j = 0; j < 8; ++j)
        xf[((size_t)hm * B + bt * 32 + bb * 8 + j) * E + o] = acc[j];
}

// FourierCross steps 1-2 (fp32 freq domain)
__global__ __launch_bounds__(256) void fourier_qk(const float2* __restrict__ qf, float2* __restrict__ kf)
{
    int b = blockIdx.x / H, h = blockIdx.x % H;
    __shared__ float2 qm[MODES][E + 1], km[MODES][E + 1], vm[MODES][E + 1];
    __shared__ float tr[MODES][MODES + 1], ti[MODES][MODES + 1];
    for (int i = threadIdx.x; i < MODES * E; i += 256) {
        int m = i / E, e = i % E;
        size_t idx = ((size_t)(h * MODES + m) * B + b) * E + e;
        qm[m][e] = qf[idx];
        km[m][e] = kf[idx];
    }
    __syncthreads();
    for (int i = threadIdx.x; i < MODES * MODES; i += 256) {
        int x = i / MODES, y = i % MODES;
        float re = 0.f, im = 0.f;
        for (int e = 0; e < E; ++e) {
            float2 a = qm[x][e], k2 = km[y][e];
            re += a.x * k2.x - a.y * k2.y;
            im += a.x * k2.y + a.y * k2.x;
        }
        float aa = fminf(fmaxf(2.f * re, -30.f), 30.f);
        float b2 = 2.f * im;
        float den = coshf(aa) + cosf(b2);
        tr[x][y] = sinhf(aa) / den;
        ti[x][y] = sinf(b2) / den;
    }
    __syncthreads();
    for (int i = threadIdx.x; i < MODES * E; i += 256) {
        int x = i / E, e = i % E;
        float re = 0.f, im = 0.f;
        for (int y = 0; y < MODES; ++y) {
            float ar = tr[x][y], ai = ti[x][y];
            float2 kk = km[y][e];
            re += ar * kk.x - ai * kk.y;
            im += ar * kk.y + ai * kk.x;
        }
        vm[x][e] = make_float2(re, im);
    }
    __syncthreads();
    for (int i = threadIdx.x; i < MODES * E; i += 256) {
        int m = i / E, e = i % E;
        kf[((size_t)(h * MODES + m) * B + b) * E + e] = vm[m][e];
    }
}

// sigma (bf16 enc input)
__global__ __launch_bounds__(256) void sigma_kernel(const unsigned short* __restrict__ enc,
                                                    const float* __restrict__ w,
                                                    const float* __restrict__ bias, float* __restrict__ sig_out)
{
    __shared__ float wsh[H][D];
    for (int i = threadIdx.x; i < H * D; i += 256) wsh[i / D][i % D] = w[i];
    __syncthreads();
    int wid = threadIdx.x / 64, lane = threadIdx.x % 64;
    int row = blockIdx.x * 4 + wid;
    const unsigned short* p = enc + (size_t)row * D;
    float xv[8];
#pragma unroll
    for (int i = 0; i < 8; ++i) xv[i] = bf2f(p[lane + i * 64]);
    int b = row / L, l = row % L;
#pragma unroll
    for (int h = 0; h < H; ++h) {
        float s = 0.f;
#pragma unroll
        for (int i = 0; i < 8; ++i) s += xv[i] * wsh[h][lane + i * 64];
        for (int off = 32; off; off >>= 1) s += __shfl_xor(s, off);
        if (lane == 0) {
            float acc = s + bias[h];
            float sg = 1.f / (1.f + expf(-5.f * acc));
            float val = expf((sg + 1e-5f) * 1.0986122886681098f) - 1.f; // 3^u - 1
            sig_out[((size_t)b * H + h) * L + l] = val;
        }
    }
}

__global__ void prior_kernel(const float* __restrict__ sig, float* __restrict__ prior)
{
    int idx = blockIdx.x * 256 + threadIdx.x;
    if (idx >= (int)(B * H * L * L)) return;
    int s = idx % L; int l = (idx / L) % L; int bh = idx / (L * L);
    float sg = sig[(size_t)bh * L + l];
    float d = (float)abs(l - s);
    prior[idx] = expf(-d * d / (2.f * sg * sg)) * INV_SQRT_2PI / sg;
}

// series_decomp_multi via replicate-padded prefix sum (bf16 in/out, fp32 trend acc)
// padded idx p in [0,124): j = clamp(p-12, 0, L-1); P[k] = sum_{p<k} val[p]
// s12 = P[l+19]-P[l+7]; s24 = P[l+25]-P[l+1]; x = P[l+13]-P[l+12]
__global__ __launch_bounds__(256) void decomp_kernel(const unsigned short* __restrict__ in1,
                                                     const unsigned short* __restrict__ in2,
                                                     const float* __restrict__ w, const float* __restrict__ bc,
                                                     unsigned short* __restrict__ res, float* __restrict__ trend,
                                                     int tmode)
{
    int b = blockIdx.x / (D / 64);
    int d0 = (blockIdx.x % (D / 64)) * 64;
    __shared__ float P[125][65];
    __shared__ float qtot[4][64];
    int tid = threadIdx.x;
    int dd = tid & 63, q = tid >> 6;
    int p0 = q * 31;
    float run = 0.f;
#pragma unroll
    for (int i = 0; i < 31; ++i) {
        int p = p0 + i;
        int j = min(max(p - 12, 0), L - 1);
        size_t g = ((size_t)b * L + j) * D + d0 + dd;
        float v = bf2f(in1[g]);
        if (in2) v += bf2f(in2[g]);
        run += v;
        P[p + 1][dd] = run;
    }
    qtot[q][dd] = run;
    if (tid < 64) P[0][dd] = 0.f;
    __syncthreads();
    if (q > 0) {
        float off = qtot[0][dd];
        if (q > 1) off += qtot[1][dd];
        if (q > 2) off += qtot[2][dd];
#pragma unroll
        for (int i = 0; i < 31; ++i)
            P[p0 + i + 1][dd] += off;
    }
    __syncthreads();
    float w0 = w[0], w1 = w[1], b0 = bc[0], b1 = bc[1];
    for (int i = tid; i < L * 64; i += 256) {
        int l = i >> 6, d2 = i & 63;
        float s12 = P[l + 19][d2] - P[l + 7][d2];
        float s24 = P[l + 25][d2] - P[l + 1][d2];
        float x = P[l + 13][d2] - P[l + 12][d2];
        float m0 = s12 * (1.f / 12.f), m1 = s24 * (1.f / 24.f);
        float z0 = x * w0 + b0, z1 = x * w1 + b1;
        float zm = fmaxf(z0, z1);
        float e0 = expf(z0 - zm), e1 = expf(z1 - zm);
        float p0f = e0 / (e0 + e1);
        float mean = m0 * p0f + m1 * (1.f - p0f);
        size_t g = ((size_t)b * L + l) * D + d0 + d2;
        res[g] = f2bf_n(x - mean);
        if (tmode == 1) trend[g] = mean;
        else if (tmode == 2) trend[g] += mean;
    }
}

// row layernorm: bf16 in, fp32 out
__global__ __launch_bounds__(256) void ln_row(const unsigned short* __restrict__ x, const float* __restrict__ g,
                                              const float* __restrict__ bb, float* __restrict__ out)
{
    int row = blockIdx.x;
    const unsigned short* p = x + (size_t)row * D;
    float s = 0.f, s2 = 0.f;
    for (int d = threadIdx.x; d < D; d += 256) { float v = bf2f(p[d]); s += v; s2 += v * v; }
    for (int off = 32; off; off >>= 1) { s += __shfl_xor(s, off); s2 += __shfl_xor(s2, off); }
    __shared__ float red[8];
    int wid = threadIdx.x / 64, lane = threadIdx.x % 64;
    if (lane == 0) { red[wid] = s; red[4 + wid] = s2; }
    __syncthreads();
    if (threadIdx.x == 0) {
        red[0] = red[0] + red[1] + red[2] + red[3];
        red[4] = red[4] + red[5] + red[6] + red[7];
    }
    __syncthreads();
    float mu = red[0] / (float)D;
    float var = red[4] / (float)D - mu * mu;
    float rstd = rsqrtf(var + 1e-5f);
    for (int d = threadIdx.x; d < D; d += 256)
        out[(size_t)row * D + d] = (bf2f(p[d]) - mu) * rstd * g[d] + bb[d];
}

// column-mean subtract: fp32 in, bf16 out; grid (B * D/128), 256 threads
__global__ __launch_bounds__(256) void col_sub(const float* __restrict__ xh, unsigned short* __restrict__ out)
{
    int b = blockIdx.x / (D / 128);
    int d0 = (blockIdx.x % (D / 128)) * 128;
    int c = threadIdx.x & 127, half = threadIdx.x >> 7;
    __shared__ float red[2][128];
    float s = 0.f;
    for (int l = half * 50; l < half * 50 + 50; ++l)
        s += xh[((size_t)b * L + l) * D + d0 + c];
    red[half][c] = s;
    __syncthreads();
    float mean = (red[0][c] + red[1][c]) * (1.f / (float)L);
    for (int l = half * 50; l < half * 50 + 50; ++l) {
        size_t g = ((size_t)b * L + l) * D + d0 + c;
        out[g] = f2bf_n(xh[g] - mean);
    }
}

extern "C" void kernel_launch(void* const* d_in, const int* in_sizes, int n_in,
                              void* d_out, int out_size, void* d_ws, size_t ws_size,
                              hipStream_t stream)
{
    const float* x           = (const float*)d_in[0];
    const float* emb_enc_w   = (const float*)d_in[1];
    const float* emb_dec_w   = (const float*)d_in[2];
    const float* enc_proj_w  = (const float*)d_in[3];
    const float* enc_proj_b  = (const float*)d_in[4];
    const float* enc_sig_w   = (const float*)d_in[5];
    const float* enc_sig_b   = (const float*)d_in[6];
    const float* enc_four_wr = (const float*)d_in[7];
    const float* enc_four_wi = (const float*)d_in[8];
    const float* enc_ffn_w1  = (const float*)d_in[9];
    const float* enc_ffn_w2  = (const float*)d_in[10];
    const float* enc_dcmp_w  = (const float*)d_in[11];
    const float* enc_dcmp_b  = (const float*)d_in[12];
    const float* enc_norm_g  = (const float*)d_in[13];
    const float* enc_norm_b  = (const float*)d_in[14];
    const float* dec_proj_w  = (const float*)d_in[15];
    const float* dec_proj_b  = (const float*)d_in[16];
    const float* dec_four_wr = (const float*)d_in[17];
    const float* dec_four_wi = (const float*)d_in[18];
    const float* crs_proj_w  = (const float*)d_in[19];
    const float* crs_proj_b  = (const float*)d_in[20];
    const float* crs_four_wr = (const float*)d_in[21];
    const float* crs_four_wi = (const float*)d_in[22];
    const float* dec_ffn_w1  = (const float*)d_in[23];
    const float* dec_ffn_w2  = (const float*)d_in[24];
    const float* dec_dcmp_w  = (const float*)d_in[25];
    const float* dec_dcmp_b  = (const float*)d_in[26];
    const float* dec_trend_w = (const float*)d_in[27];
    const float* dec_norm_g  = (const float*)d_in[28];
    const float* dec_norm_b  = (const float*)d_in[29];
    const float* out_proj_w  = (const float*)d_in[30];
    const float* out_proj_b  = (const float*)d_in[31];

    float* ws = (float*)d_ws;
    size_t off = 0;
    float* pe    = ws + off; off += (size_t)L * D;
    float* twc   = ws + off; off += (size_t)L * MODES;
    float* tws_  = ws + off; off += (size_t)L * MODES;
    float* xmean = ws + off; off += (size_t)B * CIN;
    float* bufF  = ws + off; off += BLD;           // fp32 scratch (ln out / trend Y)
    float* tacc  = ws + off; off += BLD;           // fp32 trend accumulator
    float2* xfc  = (float2*)(ws + off); off += 2 * BHEM;
    float2* kfc  = (float2*)(ws + off); off += 2 * BHEM;
    float2* wtb  = (float2*)(ws + off); off += 2 * (size_t)H * MODES * E * E;
    // bf16 activation buffers
    unsigned short* qk16 = (unsigned short*)(ws + off); off += BLD;        // 2*BLD shorts (q|k fused, stride 1024)
    unsigned short* e16  = (unsigned short*)(ws + off); off += BLD / 2;
    unsigned short* c16  = (unsigned short*)(ws + off); off += BLD / 2;
    unsigned short* d16  = (unsigned short*)(ws + off); off += BLD / 2;
    unsigned short* h16  = (unsigned short*)(ws + off); off += BLD / 2;
    unsigned short* t16  = (unsigned short*)(ws + off); off += BLD / 2;
    unsigned short* im16 = (unsigned short*)(ws + off); off += (size_t)M_ROWS * KEMB / 2;
    // bf16 weights + twiddle tables
    unsigned short* wbf_encproj = (unsigned short*)(ws + off); off += (size_t)2 * 4 * D * D / 2;
    unsigned short* wbf_ffn1    = (unsigned short*)(ws + off); off += (size_t)2 * DFF * D / 2;
    unsigned short* wbf_ffn2    = (unsigned short*)(ws + off); off += (size_t)2 * D * DFF / 2;
    unsigned short* wbf_decproj = (unsigned short*)(ws + off); off += (size_t)4 * D * D / 2;
    unsigned short* wbf_crsproj = (unsigned short*)(ws + off); off += (size_t)4 * D * D / 2;
    unsigned short* wbf_dffn1   = (unsigned short*)(ws + off); off += (size_t)DFF * D / 2;
    unsigned short* wbf_dffn2   = (unsigned short*)(ws + off); off += (size_t)D * DFF / 2;
    unsigned short* wbf_embenc  = (unsigned short*)(ws + off); off += (size_t)D * KEMB / 2;
    unsigned short* wbf_embdec  = (unsigned short*)(ws + off); off += (size_t)D * KEMB / 2;
    unsigned short* wbf_trd     = (unsigned short*)(ws + off); off += (size_t)192 * D / 2;
    unsigned short* wbf_seas    = (unsigned short*)(ws + off); off += (size_t)64 * D / 2;
    unsigned short* twf         = (unsigned short*)(ws + off); off += (size_t)64 * 128 / 2;
    unsigned short* twi         = (unsigned short*)(ws + off); off += (size_t)128 * 64 / 2;
    unsigned short* a16 = qk16;               // decoder reuse of qk region
    unsigned short* b16 = qk16 + BLD;

    float* out       = (float*)d_out;
    float* dec_out   = out;
    float* series_out= out + (size_t)B * L * COUT;
    float* prior_out = series_out + 2 * BHLL;
    float* sigma_out = prior_out + 2 * BHLL;

    const int BH = B * H;

    init_consts<<<200, 256, 0, stream>>>(pe, twc, tws_);
    init_tw<<<32, 256, 0, stream>>>(twf, twi);
    xmean_kernel<<<cdiv(B * CIN, 256), 256, 0, stream>>>(x, xmean);
    to_bf16<<<cdiv(2 * 4 * D * D / 4, 256), 256, 0, stream>>>(enc_proj_w, wbf_encproj, 2 * 4 * D * D / 4);
    to_bf16<<<cdiv(2 * DFF * D / 4, 256), 256, 0, stream>>>(enc_ffn_w1, wbf_ffn1, 2 * DFF * D / 4);
    to_bf16<<<cdiv(2 * D * DFF / 4, 256), 256, 0, stream>>>(enc_ffn_w2, wbf_ffn2, 2 * D * DFF / 4);
    to_bf16<<<cdiv(4 * D * D / 4, 256), 256, 0, stream>>>(dec_proj_w, wbf_decproj, 4 * D * D / 4);
    to_bf16<<<cdiv(4 * D * D / 4, 256), 256, 0, stream>>>(crs_proj_w, wbf_crsproj, 4 * D * D / 4);
    to_bf16<<<cdiv(DFF * D / 4, 256), 256, 0, stream>>>(dec_ffn_w1, wbf_dffn1, DFF * D / 4);
    to_bf16<<<cdiv(D * DFF / 4, 256), 256, 0, stream>>>(dec_ffn_w2, wbf_dffn2, D * DFF / 4);
    pad_rows_bf<<<cdiv(D * KEMB, 256), 256, 0, stream>>>(emb_enc_w, wbf_embenc, D, D, CIN * 3, KEMB);
    pad_rows_bf<<<cdiv(D * KEMB, 256), 256, 0, stream>>>(emb_dec_w, wbf_embdec, D, D, CIN * 3, KEMB);
    pad_trend_w2_bf<<<cdiv(192 * D, 256), 256, 0, stream>>>(dec_trend_w, wbf_trd);
    pad_rows_bf<<<cdiv(64 * D, 256), 256, 0, stream>>>(out_proj_w, wbf_seas, COUT, 64, D, D);
    transpose_w<<<H * E, 256, 0, stream>>>(enc_four_wr, enc_four_wi, wtb);

    auto gemm = [&](const unsigned short* A, const unsigned short* Wb, const float* bias, const float* pe_,
                    float* C, unsigned short* Cb, int N, int Nout, int K, int act, int accum) {
        if (N % 128 == 0) {
            dim3 grid(N / 128, M_ROWS / 128);
            gemm_mfma<128><<<grid, 256, 0, stream>>>(A, Wb, bias, pe_, C, Cb, Nout, K, act, accum);
        } else {
            dim3 grid(N / 64, M_ROWS / 128);
            gemm_mfma<64><<<grid, 256, 0, stream>>>(A, Wb, bias, pe_, C, Cb, Nout, K, act, accum);
        }
    };
    dim3 mg_grid(H * MODES, B / 32);
    dim3 sc_grid(BH, 2);

    // encoder embedding
    im2col_emb<<<cdiv(M_ROWS * KEMB, 256), 256, 0, stream>>>(x, nullptr, im16);
    gemm(im16, wbf_embenc, nullptr, pe, nullptr, e16, D, D, KEMB, 0, 0);

    for (int i = 0; i < 2; ++i) {
        const unsigned short* Wp = wbf_encproj + (size_t)i * 4 * D * D;
        const float* bp = enc_proj_b + (size_t)i * 4 * D;
        float* series_i = series_out + (size_t)i * BHLL;
        float* prior_i  = prior_out  + (size_t)i * BHLL;
        float* sigma_i  = sigma_out  + (size_t)i * B * H * L;

        gemm(e16, Wp, bp, nullptr, nullptr, qk16, 1024, 1024, D, 0, 0);       // fused q+k
        dft_mfma<<<BH, 256, 0, stream>>>(qk16, twf, xfc, 1024);
        mode_gemm2<<<mg_grid, 256, 0, stream>>>(xfc, wtb);
        idft_mfma<<<BH, 256, 0, stream>>>(xfc, twi, c16, 1.f / (float)L);
        gemm(c16, Wp + (size_t)3 * D * D, bp + 3 * D, nullptr, nullptr, d16, D, D, D, 0, 0); // attn_out
        scores_softmax<<<sc_grid, 256, 0, stream>>>(qk16, series_i);
        sigma_kernel<<<M_ROWS / 4, 256, 0, stream>>>(e16, enc_sig_w + (size_t)i * H * D,
                                                     enc_sig_b + (size_t)i * H, sigma_i);
        prior_kernel<<<cdiv((int)BHLL, 256), 256, 0, stream>>>(sigma_i, prior_i);
        decomp_kernel<<<B * (D / 64), 256, 0, stream>>>(e16, d16, enc_dcmp_w + (size_t)(i * 2 + 0) * NK,
                                                        enc_dcmp_b + (size_t)(i * 2 + 0) * NK, h16, nullptr, 0);
        gemm(h16, wbf_ffn1 + (size_t)i * DFF * D, nullptr, nullptr, nullptr, c16, DFF, DFF, D, 1, 0);
        gemm(c16, wbf_ffn2 + (size_t)i * D * DFF, nullptr, nullptr, nullptr, d16, D, D, DFF, 0, 0);
        decomp_kernel<<<B * (D / 64), 256, 0, stream>>>(h16, d16, enc_dcmp_w + (size_t)(i * 2 + 1) * NK,
                                                        enc_dcmp_b + (size_t)(i * 2 + 1) * NK, e16, nullptr, 0);
    }
    // encoder final my_layernorm
    ln_row<<<M_ROWS, 256, 0, stream>>>(e16, enc_norm_g, enc_norm_b, bufF);
    col_sub<<<B * (D / 128), 256, 0, stream>>>(bufF, e16);

    // ---------------- decoder ----------------
    transpose_w<<<H * E, 256, 0, stream>>>(dec_four_wr, dec_four_wi, wtb);
    im2col_emb<<<cdiv(M_ROWS * KEMB, 256), 256, 0, stream>>>(x, xmean, im16);
    gemm(im16, wbf_embdec, nullptr, pe, nullptr, a16, D, D, KEMB, 0, 0);           // dec
    gemm(a16, wbf_decproj, dec_proj_b, nullptr, nullptr, b16, D, D, D, 0, 0);      // q
    dft_mfma<<<BH, 256, 0, stream>>>(b16, twf, xfc, D);
    mode_gemm2<<<mg_grid, 256, 0, stream>>>(xfc, wtb);
    idft_mfma<<<BH, 256, 0, stream>>>(xfc, twi, c16, 1.f / (float)L);
    gemm(c16, wbf_decproj + (size_t)3 * D * D, dec_proj_b + 3 * D, nullptr, nullptr, d16, D, D, D, 0, 0); // sa
    decomp_kernel<<<B * (D / 64), 256, 0, stream>>>(a16, d16, dec_dcmp_w, dec_dcmp_b, h16, tacc, 1); // h, t1

    gemm(h16, wbf_crsproj, crs_proj_b, nullptr, nullptr, b16, D, D, D, 0, 0);      // qc
    dft_mfma<<<BH, 256, 0, stream>>>(b16, twf, xfc, D);                            // qf
    gemm(e16, wbf_crsproj + (size_t)D * D, crs_proj_b + D, nullptr, nullptr, b16, D, D, D, 0, 0); // kc
    dft_mfma<<<BH, 256, 0, stream>>>(b16, twf, kfc, D);                            // kf
    transpose_w<<<H * E, 256, 0, stream>>>(crs_four_wr, crs_four_wi, wtb);
    fourier_qk<<<BH, 256, 0, stream>>>(xfc, kfc);                                  // kfc := qkv
    mode_gemm2<<<mg_grid, 256, 0, stream>>>(kfc, wtb);
    idft_mfma<<<BH, 256, 0, stream>>>(kfc, twi, c16, 1.f / ((float)L * (float)D * (float)D));
    gemm(c16, wbf_crsproj + (size_t)3 * D * D, crs_proj_b + 3 * D, nullptr, nullptr, d16, D, D, D, 0, 0); // ca
    decomp_kernel<<<B * (D / 64), 256, 0, stream>>>(h16, d16, dec_dcmp_w + NK, dec_dcmp_b + NK, a16, tacc, 2); // h2, t2

    gemm(a16, wbf_dffn1, nullptr, nullptr, nullptr, c16, DFF, DFF, D, 1, 0);
    gemm(c16, wbf_dffn2, nullptr, nullptr, nullptr, d16, D, D, DFF, 0, 0);
    decomp_kernel<<<B * (D / 64), 256, 0, stream>>>(a16, d16, dec_dcmp_w + 2 * NK, dec_dcmp_b + 2 * NK, b16, tacc, 2); // h3, t3

    // trend conv: bf16 tacc copy -> stacked-tap GEMM (K=512, N=192, fp32 out) -> combine
    to_bf16<<<cdiv((int)(BLD / 4), 256), 256, 0, stream>>>(tacc, t16, (int)(BLD / 4));
    gemm(t16, wbf_trd, nullptr, nullptr, bufF, nullptr, 192, 192, D, 0, 0);
    trend_combine<<<cdiv(B * L * COUT, 256), 256, 0, stream>>>(bufF, xmean, dec_out);

    // final layernorm + seasonal projection accumulated into dec_out
    ln_row<<<M_ROWS, 256, 0, stream>>>(b16, dec_norm_g, dec_norm_b, bufF);
    col_sub<<<B * (D / 128), 256, 0, stream>>>(bufF, d16);
    gemm(d16, wbf_seas, out_proj_b, nullptr, dec_out, nullptr, 64, COUT, D, 0, 1);
}

// Round 10
// 1303.419 us; speedup vs baseline: 7.0555x; 1.0192x over previous
//
#include <hip/hip_runtime.h>
#include <hip/hip_bf16.h>
#include <cmath>

constexpr int B = 128, L = 100, CIN = 55, COUT = 55;
constexpr int D = 512, H = 8, DFF = 512, MODES = 32, E = 64;
constexpr int NK = 2;
constexpr int M_ROWS = B * L; // 12800
constexpr int KEMB = 192;     // 55*3=165 padded to 32*6
constexpr size_t BLD  = (size_t)B * L * D;         // 6,553,600
constexpr size_t BHEM = (size_t)B * H * E * MODES; // 2,097,152 complex elems
constexpr size_t BHLL = (size_t)B * H * L * L;     // 10,240,000
constexpr float INV_SQRT_2PI = 0.3989422804014327f;

static inline int cdiv(int a, int b) { return (a + b - 1) / b; }

typedef short shortx8 __attribute__((ext_vector_type(8)));
typedef float f32x4 __attribute__((ext_vector_type(4)));

__device__ inline unsigned short f2bf(float f)    // RNE (weight prep)
{
    unsigned int u = __float_as_uint(f);
    unsigned int r = (u + 0x7FFFu + ((u >> 16) & 1u)) >> 16;
    return (unsigned short)r;
}
__device__ inline unsigned short f2bf_n(float f)  // native cvt
{
    union { __hip_bfloat16 h; unsigned short u; } cv;
    cv.h = __float2bfloat16(f);
    return cv.u;
}
__device__ inline float bf2f(unsigned short u)
{
    union { unsigned int i; float f; } c;
    c.i = (unsigned int)u << 16;
    return c.f;
}

// ---------------- constants ----------------
__global__ void init_consts(float* __restrict__ pe)
{
    int idx = blockIdx.x * 256 + threadIdx.x;
    if (idx < L * D) {
        int l = idx / D, d = idx % D;
        int i2 = d & ~1;
        float div = expf((float)i2 * (-logf(10000.f) / (float)D));
        float ang = (float)l * div;
        pe[idx] = (d & 1) ? cosf(ang) : sinf(ang);
    }
}

// bf16 twiddle tables for MFMA DFT/iDFT
__global__ void init_tw(unsigned short* __restrict__ twf, unsigned short* __restrict__ twi)
{
    int idx = blockIdx.x * 256 + threadIdx.x;
    if (idx >= 64 * 128) return;
    {
        int mp = idx / 128, t = idx % 128;
        float v = 0.f;
        if (t < L) {
            if (mp < 32) v = cosf(2.f * 3.14159265358979323846f * (float)mp * (float)t / (float)L);
            else v = -sinf(2.f * 3.14159265358979323846f * (float)(mp - 32) * (float)t / (float)L);
        }
        twf[idx] = f2bf(v);
    }
    {
        int t = idx / 64, mp = idx % 64;
        float v = 0.f;
        if (t < L) {
            if (mp == 0) v = 1.f;
            else if (mp < 32) v = 2.f * cosf(2.f * 3.14159265358979323846f * (float)mp * (float)t / (float)L);
            else if (mp == 32) v = 0.f;
            else v = -2.f * sinf(2.f * 3.14159265358979323846f * (float)(mp - 32) * (float)t / (float)L);
        }
        twi[idx] = f2bf(v);
    }
}

__global__ void xmean_kernel(const float* __restrict__ x, float* __restrict__ xm)
{
    int idx = blockIdx.x * 256 + threadIdx.x;
    if (idx >= B * CIN) return;
    int b = idx / CIN, c = idx % CIN;
    float s = 0.f;
    for (int l = 0; l < L; ++l) s += x[((size_t)b * L + l) * CIN + c];
    xm[idx] = s * (1.f / (float)L);
}

// f32 -> bf16 bulk conversion (n multiple of 4)
__global__ void to_bf16(const float* __restrict__ src, unsigned short* __restrict__ dst, int n4)
{
    int i = blockIdx.x * 256 + threadIdx.x;
    if (i >= n4) return;
    float4 v = *(const float4*)&src[(size_t)i * 4];
    ushort4 h;
    h.x = f2bf(v.x); h.y = f2bf(v.y); h.z = f2bf(v.z); h.w = f2bf(v.w);
    *(ushort4*)&dst[(size_t)i * 4] = h;
}

__global__ void pad_rows_bf(const float* __restrict__ src, unsigned short* __restrict__ dst,
                            int rows_src, int rows_dst, int k_src, int k_dst)
{
    int idx = blockIdx.x * 256 + threadIdx.x;
    if (idx >= rows_dst * k_dst) return;
    int r = idx / k_dst, k = idx % k_dst;
    dst[idx] = (r < rows_src && k < k_src) ? f2bf(src[(size_t)r * k_src + k]) : (unsigned short)0;
}

__global__ void pad_trend_w2_bf(const float* __restrict__ src, unsigned short* __restrict__ dst)
{
    int idx = blockIdx.x * 256 + threadIdx.x;
    if (idx >= 192 * D) return;
    int n = idx / D, d = idx % D;
    int j = n / 64, o = n % 64;
    dst[idx] = (o < COUT) ? f2bf(src[(size_t)o * (D * 3) + d * 3 + j]) : (unsigned short)0;
}

__global__ __launch_bounds__(256) void transpose_w(const float* __restrict__ wr, const float* __restrict__ wi,
                                                   float2* __restrict__ wt)
{
    int h = blockIdx.x / E, e = blockIdx.x % E;
    __shared__ float tr[64][33], ti[64][33];
    for (int i = threadIdx.x; i < E * MODES; i += 256) {
        int o = i / MODES, m = i % MODES;
        size_t s = (((size_t)h * E + e) * E + o) * MODES + m;
        tr[o][m] = wr[s]; ti[o][m] = wi[s];
    }
    __syncthreads();
    for (int i = threadIdx.x; i < MODES * E; i += 256) {
        int m = i / E, o = i % E;
        wt[(((size_t)h * MODES + m) * E + e) * E + o] = make_float2(tr[o][m], ti[o][m]);
    }
}

// im2col for kernel-3 circular conv: bf16 out
__global__ void im2col_emb(const float* __restrict__ x, const float* __restrict__ xmean,
                           unsigned short* __restrict__ A2)
{
    int idx = blockIdx.x * 256 + threadIdx.x;
    if (idx >= M_ROWS * KEMB) return;
    int k = idx % KEMB, m = idx / KEMB;
    float v = 0.f;
    if (k < CIN * 3) {
        int c = k / 3, j = k % 3;
        int l = m % L, b = m / L;
        int ls = l + j - 1; ls = (ls + L) % L;
        v = x[((size_t)b * L + ls) * CIN + c];
        if (xmean) v -= xmean[(size_t)b * CIN + c];
    }
    A2[idx] = f2bf(v);
}

// ---------------- bf16 MFMA GEMM, double-buffered LDS, ONE barrier per K-step ----------------
template<int BN>
__global__ __launch_bounds__(256) void gemm_mfma(const unsigned short* __restrict__ A,
                                                 const unsigned short* __restrict__ Wb,
                                                 const float* __restrict__ bias, const float* __restrict__ pe,
                                                 float* __restrict__ C, unsigned short* __restrict__ Cb,
                                                 int Nout, int K, int act, int accum)
{
    constexpr int NI = BN / 32;
    constexpr int BI = BN / 64;
    __shared__ unsigned short As[2][128][40];
    __shared__ unsigned short Bs[2][BN][40];
    int tid = threadIdx.x;
    int row0 = blockIdx.y * 128, col0 = blockIdx.x * BN;
    int wid = tid >> 6, lane = tid & 63;
    int wm = wid >> 1, wn = wid & 1;
    int lrow = lane & 15, kg = lane >> 4;
    int ar = tid >> 2, ac8 = (tid & 3) * 8;
    f32x4 acc[4][NI] = {};
    shortx8 rah[2], rbh[BI];

    auto loadG = [&](int k0) {
#pragma unroll
        for (int p = 0; p < 2; ++p)
            rah[p] = *(const shortx8*)&A[(size_t)(row0 + p * 64 + ar) * K + k0 + ac8];
#pragma unroll
        for (int p = 0; p < BI; ++p)
            rbh[p] = *(const shortx8*)&Wb[(size_t)(col0 + p * 64 + ar) * K + k0 + ac8];
    };
    auto storeLDS = [&](int buf) {
#pragma unroll
        for (int p = 0; p < 2; ++p)
            *(shortx8*)&As[buf][p * 64 + ar][ac8] = rah[p];
#pragma unroll
        for (int p = 0; p < BI; ++p)
            *(shortx8*)&Bs[buf][p * 64 + ar][ac8] = rbh[p];
    };

    int nk = K >> 5;
    loadG(0);
    storeLDS(0);
    if (nk > 1) loadG(32);
    __syncthreads();
    int cur = 0;
    for (int s = 0; s < nk; ++s) {
        if (s + 1 < nk) {
            storeLDS(cur ^ 1);                 // tile s+1 (regs) -> other buffer
            if (s + 2 < nk) loadG((s + 2) << 5); // issue loads for tile s+2
        }
        shortx8 av[4], bv[NI];
#pragma unroll
        for (int mi = 0; mi < 4; ++mi)
            av[mi] = *(const shortx8*)&As[cur][wm * 64 + mi * 16 + lrow][kg * 8];
#pragma unroll
        for (int ni = 0; ni < NI; ++ni)
            bv[ni] = *(const shortx8*)&Bs[cur][wn * (BN / 2) + ni * 16 + lrow][kg * 8];
#pragma unroll
        for (int mi = 0; mi < 4; ++mi)
#pragma unroll
            for (int ni = 0; ni < NI; ++ni)
                acc[mi][ni] = __builtin_amdgcn_mfma_f32_16x16x32_bf16(av[mi], bv[ni], acc[mi][ni], 0, 0, 0);
        if (s + 1 < nk) __syncthreads();
        cur ^= 1;
    }
#pragma unroll
    for (int mi = 0; mi < 4; ++mi) {
#pragma unroll
        for (int ni = 0; ni < NI; ++ni) {
            int col = col0 + wn * (BN / 2) + ni * 16 + lrow;
            if (col >= Nout) continue;
#pragma unroll
            for (int r = 0; r < 4; ++r) {
                int row = row0 + wm * 64 + mi * 16 + kg * 4 + r;
                float v = acc[mi][ni][r];
                if (bias) v += bias[col];
                if (pe) v += pe[(size_t)(row % L) * Nout + col];
                if (act) v = 0.5f * v * (1.f + erff(v * 0.70710678118654752f));
                size_t o = (size_t)row * Nout + col;
                if (Cb) Cb[o] = f2bf_n(v);
                else if (accum) C[o] += v;
                else C[o] = v;
            }
        }
    }
}

// ---------------- fused QK^T/8 + row-softmax (bf16 input, row stride 1024) ----------------
__global__ __launch_bounds__(256) void scores_softmax(const unsigned short* __restrict__ QK,
                                                      float* __restrict__ out)
{
    int bh = blockIdx.x, b = bh / H, h = bh % H;
    int pass = blockIdx.y;
    __shared__ unsigned short Ks[112][72];
    __shared__ unsigned short Qs[64][72];
    int tid = threadIdx.x;
    int srow = tid >> 4, sc4 = (tid & 15) * 4;
#pragma unroll
    for (int i = 0; i < 7; ++i) {
        int r = i * 16 + srow;
        ushort4 hh = {0, 0, 0, 0};
        if (r < L) hh = *(const ushort4*)&QK[((size_t)b * L + r) * 1024 + 512 + h * E + sc4];
        *(ushort4*)&Ks[r][sc4] = hh;
    }
#pragma unroll
    for (int i = 0; i < 4; ++i) {
        int r = i * 16 + srow;
        int gr = pass * 64 + r;
        ushort4 hh = {0, 0, 0, 0};
        if (gr < L) hh = *(const ushort4*)&QK[((size_t)b * L + gr) * 1024 + h * E + sc4];
        *(ushort4*)&Qs[r][sc4] = hh;
    }
    __syncthreads();
    int wid = tid >> 6, lane = tid & 63;
    int lrow = lane & 15, kg = lane >> 4;
    f32x4 acc[7] = {};
#pragma unroll
    for (int ks = 0; ks < 2; ++ks) {
        shortx8 aq = *(const shortx8*)&Qs[wid * 16 + lrow][ks * 32 + kg * 8];
#pragma unroll
        for (int tj = 0; tj < 7; ++tj) {
            shortx8 bk = *(const shortx8*)&Ks[tj * 16 + lrow][ks * 32 + kg * 8];
            acc[tj] = __builtin_amdgcn_mfma_f32_16x16x32_bf16(aq, bk, acc[tj], 0, 0, 0);
        }
    }
    float mx[4] = {-1e30f, -1e30f, -1e30f, -1e30f};
#pragma unroll
    for (int tj = 0; tj < 7; ++tj) {
        bool valid = (tj * 16 + lrow) < L;
#pragma unroll
        for (int r = 0; r < 4; ++r) {
            float v = acc[tj][r] * 0.125f;
            acc[tj][r] = valid ? v : -1e30f;
            if (valid) mx[r] = fmaxf(mx[r], v);
        }
    }
#pragma unroll
    for (int off = 1; off < 16; off <<= 1)
#pragma unroll
        for (int r = 0; r < 4; ++r) mx[r] = fmaxf(mx[r], __shfl_xor(mx[r], off));
    float sum[4] = {0.f, 0.f, 0.f, 0.f};
#pragma unroll
    for (int tj = 0; tj < 7; ++tj)
#pragma unroll
        for (int r = 0; r < 4; ++r) {
            float e = expf(acc[tj][r] - mx[r]);
            acc[tj][r] = e;
            sum[r] += e;
        }
#pragma unroll
    for (int off = 1; off < 16; off <<= 1)
#pragma unroll
        for (int r = 0; r < 4; ++r) sum[r] += __shfl_xor(sum[r], off);
    float inv[4];
#pragma unroll
    for (int r = 0; r < 4; ++r) inv[r] = 1.f / sum[r];
    float* base = out + (size_t)bh * L * L;
#pragma unroll
    for (int r = 0; r < 4; ++r) {
        int row = pass * 64 + wid * 16 + kg * 4 + r;
        if (row >= L) continue;
#pragma unroll
        for (int tj = 0; tj < 7; ++tj) {
            int col = tj * 16 + lrow;
            if (col < L) base[(size_t)row * L + col] = acc[tj][r] * inv[r];
        }
    }
}

// trend combine (Y fp32, row stride 192)
__global__ void trend_combine(const float* __restrict__ Y, const float* __restrict__ xmean,
                              float* __restrict__ dec_out)
{
    int idx = blockIdx.x * 256 + threadIdx.x;
    if (idx >= B * L * COUT) return;
    int o = idx % COUT; int l = (idx / COUT) % L; int b = idx / (COUT * L);
    int lm = (l + L - 1) % L, lp = (l + 1) % L;
    float v = xmean[(size_t)b * CIN + o]
            + Y[((size_t)b * L + lm) * 192 + o]
            + Y[((size_t)b * L + l ) * 192 + 64 + o]
            + Y[((size_t)b * L + lp) * 192 + 128 + o];
    dec_out[idx] = v;
}

// ---------------- MFMA forward DFT: C[m'][e] = twf[m'][t] * X^T[e][t] per (b,h) ----------------
__global__ __launch_bounds__(256) void dft_mfma(const unsigned short* __restrict__ X,
                                                const unsigned short* __restrict__ twf,
                                                float2* __restrict__ xf, int stride)
{
    int b = blockIdx.x / H, h = blockIdx.x % H;
    __shared__ unsigned short Xs[64][136];   // [e][t], t padded to 128
    int tid = threadIdx.x;
    for (int i = tid; i < L * E / 4; i += 256) {
        int t = i >> 4, e4 = (i & 15) * 4;
        ushort4 u = *(const ushort4*)&X[((size_t)b * L + t) * stride + h * E + e4];
        Xs[e4][t] = u.x; Xs[e4 + 1][t] = u.y; Xs[e4 + 2][t] = u.z; Xs[e4 + 3][t] = u.w;
    }
    for (int i = tid; i < 64 * 28; i += 256) {
        int e = i / 28, t = L + i % 28;
        Xs[e][t] = 0;
    }
    __syncthreads();
    int wid = tid >> 6, lane = tid & 63;
    int lrow = lane & 15, kg = lane >> 4;
    f32x4 acc[4] = {};
#pragma unroll
    for (int k0 = 0; k0 < 4; ++k0) {
        shortx8 bx = *(const shortx8*)&Xs[wid * 16 + lrow][k0 * 32 + kg * 8];
#pragma unroll
        for (int mi = 0; mi < 4; ++mi) {
            shortx8 aw = *(const shortx8*)&twf[(size_t)(mi * 16 + lrow) * 128 + k0 * 32 + kg * 8];
            acc[mi] = __builtin_amdgcn_mfma_f32_16x16x32_bf16(aw, bx, acc[mi], 0, 0, 0);
        }
    }
    int e = wid * 16 + lrow;
#pragma unroll
    for (int mi = 0; mi < 2; ++mi)
#pragma unroll
        for (int r = 0; r < 4; ++r) {
            int m = mi * 16 + kg * 4 + r;
            xf[((size_t)(h * MODES + m) * B + b) * E + e] = make_float2(acc[mi][r], acc[mi + 2][r]);
        }
}

// ---------------- MFMA iDFT: C[t][o] = twi[t][m'] * S[o][m'] per (b,h), scaled, bf16 out ----------------
__global__ __launch_bounds__(256) void idft_mfma(const float2* __restrict__ sel,
                                                 const unsigned short* __restrict__ twi,
                                                 unsigned short* __restrict__ out, float scale)
{
    int b = blockIdx.x / H, h = blockIdx.x % H;
    __shared__ unsigned short Ss[64][72];    // [o][m'], m' = 32 re + 32 im
    int tid = threadIdx.x;
    for (int i = tid; i < MODES * E; i += 256) {
        int m = i >> 6, o = i & 63;
        float2 v = sel[((size_t)(h * MODES + m) * B + b) * E + o];
        Ss[o][m] = f2bf_n(v.x);
        Ss[o][m + 32] = f2bf_n(v.y);
    }
    __syncthreads();
    int wid = tid >> 6, lane = tid & 63;
    int lrow = lane & 15, kg = lane >> 4;
    f32x4 acc[2][4] = {};
#pragma unroll
    for (int k0 = 0; k0 < 2; ++k0) {
        shortx8 bs[4];
#pragma unroll
        for (int ni = 0; ni < 4; ++ni)
            bs[ni] = *(const shortx8*)&Ss[ni * 16 + lrow][k0 * 32 + kg * 8];
#pragma unroll
        for (int ti = 0; ti < 2; ++ti) {
            shortx8 at = *(const shortx8*)&twi[(size_t)((wid * 2 + ti) * 16 + lrow) * 64 + k0 * 32 + kg * 8];
#pragma unroll
            for (int ni = 0; ni < 4; ++ni)
                acc[ti][ni] = __builtin_amdgcn_mfma_f32_16x16x32_bf16(at, bs[ni], acc[ti][ni], 0, 0, 0);
        }
    }
#pragma unroll
    for (int ti = 0; ti < 2; ++ti)
#pragma unroll
        for (int ni = 0; ni < 4; ++ni)
#pragma unroll
            for (int r = 0; r < 4; ++r) {
                int t = (wid * 2 + ti) * 16 + kg * 4 + r;
                if (t < L) {
                    int o = ni * 16 + lrow;
                    out[((size_t)b * L + t) * D + h * E + o] = f2bf_n(acc[ti][ni][r] * scale);
                }
            }
}

// ---------------- per-(h,m) complex GEMM, in place ----------------
__global__ __launch_bounds__(256) void mode_gemm2(float2* __restrict__ xf, const float2* __restrict__ wt)
{
    int hm = blockIdx.x;
    int bt = blockIdx.y;
    __shared__ float2 Wc[E][E];
    __shared__ float2 Ac[32][E];
    for (int i = threadIdx.x; i < E * E; i += 256) Wc[i / E][i % E] = wt[(size_t)hm * (E * E) + i];
    for (int i = threadIdx.x; i < 32 * E; i += 256)
        Ac[i / E][i % E] = xf[((size_t)hm * B + bt * 32 + i / E) * E + i % E];
    __syncthreads();
    int o = threadIdx.x & 63, bb = threadIdx.x >> 6;
    float2 acc[8];
#pragma unroll
    for (int j = 0; j < 8; ++j) acc[j] = make_float2(0.f, 0.f);
    for (int e = 0; e < E; ++e) {
        float2 w = Wc[e][o];
#pragma unroll
        for (int j = 0; j < 8; ++j) {
            float2 a = Ac[bb * 8 + j][e];
            acc[j].x += a.x * w.x - a.y * w.y;
            acc[j].y += a.x * w.y + a.y * w.x;
        }
    }
#pragma unroll
    for (int j = 0; j < 8; ++j)
        xf[((size_t)hm * B + bt * 32 + bb * 8 + j) * E + o] = acc[j];
}

// FourierCross steps 1-2 (fp32 freq domain)
__global__ __launch_bounds__(256) void fourier_qk(const float2* __restrict__ qf, float2* __restrict__ kf)
{
    int b = blockIdx.x / H, h = blockIdx.x % H;
    __shared__ float2 qm[MODES][E + 1], km[MODES][E + 1], vm[MODES][E + 1];
    __shared__ float tr[MODES][MODES + 1], ti[MODES][MODES + 1];
    for (int i = threadIdx.x; i < MODES * E; i += 256) {
        int m = i / E, e = i % E;
        size_t idx = ((size_t)(h * MODES + m) * B + b) * E + e;
        qm[m][e] = qf[idx];
        km[m][e] = kf[idx];
    }
    __syncthreads();
    for (int i = threadIdx.x; i < MODES * MODES; i += 256) {
        int x = i / MODES, y = i % MODES;
        float re = 0.f, im = 0.f;
        for (int e = 0; e < E; ++e) {
            float2 a = qm[x][e], k2 = km[y][e];
            re += a.x * k2.x - a.y * k2.y;
            im += a.x * k2.y + a.y * k2.x;
        }
        float aa = fminf(fmaxf(2.f * re, -30.f), 30.f);
        float b2 = 2.f * im;
        float den = coshf(aa) + cosf(b2);
        tr[x][y] = sinhf(aa) / den;
        ti[x][y] = sinf(b2) / den;
    }
    __syncthreads();
    for (int i = threadIdx.x; i < MODES * E; i += 256) {
        int x = i / E, e = i % E;
        float re = 0.f, im = 0.f;
        for (int y = 0; y < MODES; ++y) {
            float ar = tr[x][y], ai = ti[x][y];
            float2 kk = km[y][e];
            re += ar * kk.x - ai * kk.y;
            im += ar * kk.y + ai * kk.x;
        }
        vm[x][e] = make_float2(re, im);
    }
    __syncthreads();
    for (int i = threadIdx.x; i < MODES * E; i += 256) {
        int m = i / E, e = i % E;
        kf[((size_t)(h * MODES + m) * B + b) * E + e] = vm[m][e];
    }
}

// sigma + prior fused: per block 4 rows; each wave computes 8 head-sigmas for its row,
// writes sigma (B,H,L) and the 8 full prior rows (B,H,L,L).
__global__ __launch_bounds__(256) void sigma_prior(const unsigned short* __restrict__ enc,
                                                   const float* __restrict__ w,
                                                   const float* __restrict__ bias,
                                                   float* __restrict__ sig_out, float* __restrict__ prior)
{
    __shared__ float wsh[H][D];
    for (int i = threadIdx.x; i < H * D; i += 256) wsh[i / D][i % D] = w[i];
    __syncthreads();
    int wid = threadIdx.x / 64, lane = threadIdx.x % 64;
    int row = blockIdx.x * 4 + wid;
    const unsigned short* p = enc + (size_t)row * D;
    float xv[8];
#pragma unroll
    for (int i = 0; i < 8; ++i) xv[i] = bf2f(p[lane + i * 64]);
    int b = row / L, l = row % L;
#pragma unroll
    for (int h = 0; h < H; ++h) {
        float s = 0.f;
#pragma unroll
        for (int i = 0; i < 8; ++i) s += xv[i] * wsh[h][lane + i * 64];
        for (int off = 32; off; off >>= 1) s += __shfl_xor(s, off);
        float acc = s + bias[h];
        float sg = 1.f / (1.f + expf(-5.f * acc));
        float val = expf((sg + 1e-5f) * 1.0986122886681098f) - 1.f; // 3^u - 1
        if (lane == 0) sig_out[((size_t)b * H + h) * L + l] = val;
        float inv2 = 1.f / (2.f * val * val);
        float coef = INV_SQRT_2PI / val;
        float* pr = prior + (((size_t)b * H + h) * L + l) * L;
        for (int sc = lane; sc < L; sc += 64) {
            float d = (float)abs(l - sc);
            pr[sc] = expf(-d * d * inv2) * coef;
        }
    }
}

// series_decomp_multi via replicate-padded prefix sum (bf16 in/out, fp32 trend acc,
// optional bf16 trend copy for the trailing trend GEMM)
__global__ __launch_bounds__(256) void decomp_kernel(const unsigned short* __restrict__ in1,
                                                     const unsigned short* __restrict__ in2,
                                                     const float* __restrict__ w, const float* __restrict__ bc,
                                                     unsigned short* __restrict__ res, float* __restrict__ trend,
                                                     unsigned short* __restrict__ trend16, int tmode)
{
    int b = blockIdx.x / (D / 64);
    int d0 = (blockIdx.x % (D / 64)) * 64;
    __shared__ float P[125][65];
    __shared__ float qtot[4][64];
    int tid = threadIdx.x;
    int dd = tid & 63, q = tid >> 6;
    int p0 = q * 31;
    float run = 0.f;
#pragma unroll
    for (int i = 0; i < 31; ++i) {
        int p = p0 + i;
        int j = min(max(p - 12, 0), L - 1);
        size_t g = ((size_t)b * L + j) * D + d0 + dd;
        float v = bf2f(in1[g]);
        if (in2) v += bf2f(in2[g]);
        run += v;
        P[p + 1][dd] = run;
    }
    qtot[q][dd] = run;
    if (tid < 64) P[0][dd] = 0.f;
    __syncthreads();
    if (q > 0) {
        float off = qtot[0][dd];
        if (q > 1) off += qtot[1][dd];
        if (q > 2) off += qtot[2][dd];
#pragma unroll
        for (int i = 0; i < 31; ++i)
            P[p0 + i + 1][dd] += off;
    }
    __syncthreads();
    float w0 = w[0], w1 = w[1], b0 = bc[0], b1 = bc[1];
    for (int i = tid; i < L * 64; i += 256) {
        int l = i >> 6, d2 = i & 63;
        float s12 = P[l + 19][d2] - P[l + 7][d2];
        float s24 = P[l + 25][d2] - P[l + 1][d2];
        float x = P[l + 13][d2] - P[l + 12][d2];
        float m0 = s12 * (1.f / 12.f), m1 = s24 * (1.f / 24.f);
        float z0 = x * w0 + b0, z1 = x * w1 + b1;
        float zm = fmaxf(z0, z1);
        float e0 = expf(z0 - zm), e1 = expf(z1 - zm);
        float p0f = e0 / (e0 + e1);
        float mean = m0 * p0f + m1 * (1.f - p0f);
        size_t g = ((size_t)b * L + l) * D + d0 + d2;
        res[g] = f2bf_n(x - mean);
        if (tmode == 1) trend[g] = mean;
        else if (tmode == 2) {
            float tv = trend[g] + mean;
            trend[g] = tv;
            if (trend16) trend16[g] = f2bf_n(tv);
        }
    }
}

// fused my_layernorm: per-row LN then per-column mean subtract; one block per batch b.
// in/out bf16 (may alias).
__global__ __launch_bounds__(256) void ln_colsub(const unsigned short* __restrict__ x,
                                                 const float* __restrict__ g, const float* __restrict__ bb,
                                                 unsigned short* __restrict__ out)
{
    int b = blockIdx.x;
    __shared__ unsigned short xs[L][D];      // 100*512*2 = 102,400 B
    __shared__ float colmean[D];
    __shared__ float gs[D], bs2[D];
    int tid = threadIdx.x;
    for (int i = tid; i < L * D / 8; i += 256) {
        int l = i / 64, c8 = (i % 64) * 8;
        *(shortx8*)&xs[l][c8] = *(const shortx8*)&x[((size_t)b * L + l) * D + c8];
    }
    for (int i = tid; i < D; i += 256) { gs[i] = g[i]; bs2[i] = bb[i]; }
    __syncthreads();
    int wid = tid >> 6, lane = tid & 63;
    for (int l = wid; l < L; l += 4) {
        float v[8];
        float s = 0.f, s2 = 0.f;
#pragma unroll
        for (int i = 0; i < 8; ++i) {
            v[i] = bf2f(xs[l][lane + i * 64]);
            s += v[i]; s2 += v[i] * v[i];
        }
        for (int off = 32; off; off >>= 1) { s += __shfl_xor(s, off); s2 += __shfl_xor(s2, off); }
        float mu = s / (float)D;
        float var = s2 / (float)D - mu * mu;
        float rstd = rsqrtf(var + 1e-5f);
#pragma unroll
        for (int i = 0; i < 8; ++i) {
            int d = lane + i * 64;
            xs[l][d] = f2bf_n((v[i] - mu) * rstd * gs[d] + bs2[d]);
        }
    }
    __syncthreads();
    for (int c = tid; c < D; c += 256) {
        float s = 0.f;
        for (int l = 0; l < L; ++l) s += bf2f(xs[l][c]);
        colmean[c] = s * (1.f / (float)L);
    }
    __syncthreads();
    for (int i = tid; i < L * D; i += 256) {
        int l = i / D, c = i % D;
        out[((size_t)b * L + l) * D + c] = f2bf_n(bf2f(xs[l][c]) - colmean[c]);
    }
}

extern "C" void kernel_launch(void* const* d_in, const int* in_sizes, int n_in,
                              void* d_out, int out_size, void* d_ws, size_t ws_size,
                              hipStream_t stream)
{
    const float* x           = (const float*)d_in[0];
    const float* emb_enc_w   = (const float*)d_in[1];
    const float* emb_dec_w   = (const float*)d_in[2];
    const float* enc_proj_w  = (const float*)d_in[3];
    const float* enc_proj_b  = (const float*)d_in[4];
    const float* enc_sig_w   = (const float*)d_in[5];
    const float* enc_sig_b   = (const float*)d_in[6];
    const float* enc_four_wr = (const float*)d_in[7];
    const float* enc_four_wi = (const float*)d_in[8];
    const float* enc_ffn_w1  = (const float*)d_in[9];
    const float* enc_ffn_w2  = (const float*)d_in[10];
    const float* enc_dcmp_w  = (const float*)d_in[11];
    const float* enc_dcmp_b  = (const float*)d_in[12];
    const float* enc_norm_g  = (const float*)d_in[13];
    const float* enc_norm_b  = (const float*)d_in[14];
    const float* dec_proj_w  = (const float*)d_in[15];
    const float* dec_proj_b  = (const float*)d_in[16];
    const float* dec_four_wr = (const float*)d_in[17];
    const float* dec_four_wi = (const float*)d_in[18];
    const float* crs_proj_w  = (const float*)d_in[19];
    const float* crs_proj_b  = (const float*)d_in[20];
    const float* crs_four_wr = (const float*)d_in[21];
    const float* crs_four_wi = (const float*)d_in[22];
    const float* dec_ffn_w1  = (const float*)d_in[23];
    const float* dec_ffn_w2  = (const float*)d_in[24];
    const float* dec_dcmp_w  = (const float*)d_in[25];
    const float* dec_dcmp_b  = (const float*)d_in[26];
    const float* dec_trend_w = (const float*)d_in[27];
    const float* dec_norm_g  = (const float*)d_in[28];
    const float* dec_norm_b  = (const float*)d_in[29];
    const float* out_proj_w  = (const float*)d_in[30];
    const float* out_proj_b  = (const float*)d_in[31];

    float* ws = (float*)d_ws;
    size_t off = 0;
    float* pe    = ws + off; off += (size_t)L * D;
    float* xmean = ws + off; off += (size_t)B * CIN;
    float* bufF  = ws + off; off += BLD;           // fp32 scratch (trend Y)
    float* tacc  = ws + off; off += BLD;           // fp32 trend accumulator
    float2* xfc  = (float2*)(ws + off); off += 2 * BHEM;
    float2* kfc  = (float2*)(ws + off); off += 2 * BHEM;
    float2* wtb  = (float2*)(ws + off); off += 2 * (size_t)H * MODES * E * E;
    // bf16 activation buffers
    unsigned short* qk16 = (unsigned short*)(ws + off); off += BLD;        // 2*BLD shorts (q|k fused, stride 1024)
    unsigned short* e16  = (unsigned short*)(ws + off); off += BLD / 2;
    unsigned short* c16  = (unsigned short*)(ws + off); off += BLD / 2;
    unsigned short* d16  = (unsigned short*)(ws + off); off += BLD / 2;
    unsigned short* h16  = (unsigned short*)(ws + off); off += BLD / 2;
    unsigned short* t16  = (unsigned short*)(ws + off); off += BLD / 2;
    unsigned short* im16 = (unsigned short*)(ws + off); off += (size_t)M_ROWS * KEMB / 2;
    // bf16 weights + twiddle tables
    unsigned short* wbf_encproj = (unsigned short*)(ws + off); off += (size_t)2 * 4 * D * D / 2;
    unsigned short* wbf_ffn1    = (unsigned short*)(ws + off); off += (size_t)2 * DFF * D / 2;
    unsigned short* wbf_ffn2    = (unsigned short*)(ws + off); off += (size_t)2 * D * DFF / 2;
    unsigned short* wbf_decproj = (unsigned short*)(ws + off); off += (size_t)4 * D * D / 2;
    unsigned short* wbf_crsproj = (unsigned short*)(ws + off); off += (size_t)4 * D * D / 2;
    unsigned short* wbf_dffn1   = (unsigned short*)(ws + off); off += (size_t)DFF * D / 2;
    unsigned short* wbf_dffn2   = (unsigned short*)(ws + off); off += (size_t)D * DFF / 2;
    unsigned short* wbf_embenc  = (unsigned short*)(ws + off); off += (size_t)D * KEMB / 2;
    unsigned short* wbf_embdec  = (unsigned short*)(ws + off); off += (size_t)D * KEMB / 2;
    unsigned short* wbf_trd     = (unsigned short*)(ws + off); off += (size_t)192 * D / 2;
    unsigned short* wbf_seas    = (unsigned short*)(ws + off); off += (size_t)64 * D / 2;
    unsigned short* twf         = (unsigned short*)(ws + off); off += (size_t)64 * 128 / 2;
    unsigned short* twi         = (unsigned short*)(ws + off); off += (size_t)128 * 64 / 2;
    unsigned short* a16 = qk16;               // decoder reuse of qk region
    unsigned short* b16 = qk16 + BLD;

    float* out       = (float*)d_out;
    float* dec_out   = out;
    float* series_out= out + (size_t)B * L * COUT;
    float* prior_out = series_out + 2 * BHLL;
    float* sigma_out = prior_out + 2 * BHLL;

    const int BH = B * H;

    init_consts<<<200, 256, 0, stream>>>(pe);
    init_tw<<<32, 256, 0, stream>>>(twf, twi);
    xmean_kernel<<<cdiv(B * CIN, 256), 256, 0, stream>>>(x, xmean);
    to_bf16<<<cdiv(2 * 4 * D * D / 4, 256), 256, 0, stream>>>(enc_proj_w, wbf_encproj, 2 * 4 * D * D / 4);
    to_bf16<<<cdiv(2 * DFF * D / 4, 256), 256, 0, stream>>>(enc_ffn_w1, wbf_ffn1, 2 * DFF * D / 4);
    to_bf16<<<cdiv(2 * D * DFF / 4, 256), 256, 0, stream>>>(enc_ffn_w2, wbf_ffn2, 2 * D * DFF / 4);
    to_bf16<<<cdiv(4 * D * D / 4, 256), 256, 0, stream>>>(dec_proj_w, wbf_decproj, 4 * D * D / 4);
    to_bf16<<<cdiv(4 * D * D / 4, 256), 256, 0, stream>>>(crs_proj_w, wbf_crsproj, 4 * D * D / 4);
    to_bf16<<<cdiv(DFF * D / 4, 256), 256, 0, stream>>>(dec_ffn_w1, wbf_dffn1, DFF * D / 4);
    to_bf16<<<cdiv(D * DFF / 4, 256), 256, 0, stream>>>(dec_ffn_w2, wbf_dffn2, D * DFF / 4);
    pad_rows_bf<<<cdiv(D * KEMB, 256), 256, 0, stream>>>(emb_enc_w, wbf_embenc, D, D, CIN * 3, KEMB);
    pad_rows_bf<<<cdiv(D * KEMB, 256), 256, 0, stream>>>(emb_dec_w, wbf_embdec, D, D, CIN * 3, KEMB);
    pad_trend_w2_bf<<<cdiv(192 * D, 256), 256, 0, stream>>>(dec_trend_w, wbf_trd);
    pad_rows_bf<<<cdiv(64 * D, 256), 256, 0, stream>>>(out_proj_w, wbf_seas, COUT, 64, D, D);
    transpose_w<<<H * E, 256, 0, stream>>>(enc_four_wr, enc_four_wi, wtb);

    auto gemm = [&](const unsigned short* A, const unsigned short* Wb, const float* bias, const float* pe_,
                    float* C, unsigned short* Cb, int N, int Nout, int K, int act, int accum) {
        if (N % 128 == 0) {
            dim3 grid(N / 128, M_ROWS / 128);
            gemm_mfma<128><<<grid, 256, 0, stream>>>(A, Wb, bias, pe_, C, Cb, Nout, K, act, accum);
        } else {
            dim3 grid(N / 64, M_ROWS / 128);
            gemm_mfma<64><<<grid, 256, 0, stream>>>(A, Wb, bias, pe_, C, Cb, Nout, K, act, accum);
        }
    };
    dim3 mg_grid(H * MODES, B / 32);
    dim3 sc_grid(BH, 2);

    // encoder embedding
    im2col_emb<<<cdiv(M_ROWS * KEMB, 256), 256, 0, stream>>>(x, nullptr, im16);
    gemm(im16, wbf_embenc, nullptr, pe, nullptr, e16, D, D, KEMB, 0, 0);

    for (int i = 0; i < 2; ++i) {
        const unsigned short* Wp = wbf_encproj + (size_t)i * 4 * D * D;
        const float* bp = enc_proj_b + (size_t)i * 4 * D;
        float* series_i = series_out + (size_t)i * BHLL;
        float* prior_i  = prior_out  + (size_t)i * BHLL;
        float* sigma_i  = sigma_out  + (size_t)i * B * H * L;

        gemm(e16, Wp, bp, nullptr, nullptr, qk16, 1024, 1024, D, 0, 0);       // fused q+k
        dft_mfma<<<BH, 256, 0, stream>>>(qk16, twf, xfc, 1024);
        mode_gemm2<<<mg_grid, 256, 0, stream>>>(xfc, wtb);
        idft_mfma<<<BH, 256, 0, stream>>>(xfc, twi, c16, 1.f / (float)L);
        gemm(c16, Wp + (size_t)3 * D * D, bp + 3 * D, nullptr, nullptr, d16, D, D, D, 0, 0); // attn_out
        scores_softmax<<<sc_grid, 256, 0, stream>>>(qk16, series_i);
        sigma_prior<<<M_ROWS / 4, 256, 0, stream>>>(e16, enc_sig_w + (size_t)i * H * D,
                                                    enc_sig_b + (size_t)i * H, sigma_i, prior_i);
        decomp_kernel<<<B * (D / 64), 256, 0, stream>>>(e16, d16, enc_dcmp_w + (size_t)(i * 2 + 0) * NK,
                                                        enc_dcmp_b + (size_t)(i * 2 + 0) * NK, h16, nullptr, nullptr, 0);
        gemm(h16, wbf_ffn1 + (size_t)i * DFF * D, nullptr, nullptr, nullptr, c16, DFF, DFF, D, 1, 0);
        gemm(c16, wbf_ffn2 + (size_t)i * D * DFF, nullptr, nullptr, nullptr, d16, D, D, DFF, 0, 0);
        decomp_kernel<<<B * (D / 64), 256, 0, stream>>>(h16, d16, enc_dcmp_w + (size_t)(i * 2 + 1) * NK,
                                                        enc_dcmp_b + (size_t)(i * 2 + 1) * NK, e16, nullptr, nullptr, 0);
    }
    // encoder final my_layernorm (fused LN + column-mean subtract), in place on e16
    ln_colsub<<<B, 256, 0, stream>>>(e16, enc_norm_g, enc_norm_b, e16);

    // ---------------- decoder ----------------
    transpose_w<<<H * E, 256, 0, stream>>>(dec_four_wr, dec_four_wi, wtb);
    im2col_emb<<<cdiv(M_ROWS * KEMB, 256), 256, 0, stream>>>(x, xmean, im16);
    gemm(im16, wbf_embdec, nullptr, pe, nullptr, a16, D, D, KEMB, 0, 0);           // dec
    gemm(a16, wbf_decproj, dec_proj_b, nullptr, nullptr, b16, D, D, D, 0, 0);      // q
    dft_mfma<<<BH, 256, 0, stream>>>(b16, twf, xfc, D);
    mode_gemm2<<<mg_grid, 256, 0, stream>>>(xfc, wtb);
    idft_mfma<<<BH, 256, 0, stream>>>(xfc, twi, c16, 1.f / (float)L);
    gemm(c16, wbf_decproj + (size_t)3 * D * D, dec_proj_b + 3 * D, nullptr, nullptr, d16, D, D, D, 0, 0); // sa
    decomp_kernel<<<B * (D / 64), 256, 0, stream>>>(a16, d16, dec_dcmp_w, dec_dcmp_b, h16, tacc, nullptr, 1); // h, t1

    gemm(h16, wbf_crsproj, crs_proj_b, nullptr, nullptr, b16, D, D, D, 0, 0);      // qc
    dft_mfma<<<BH, 256, 0, stream>>>(b16, twf, xfc, D);                            // qf
    gemm(e16, wbf_crsproj + (size_t)D * D, crs_proj_b + D, nullptr, nullptr, b16, D, D, D, 0, 0); // kc
    dft_mfma<<<BH, 256, 0, stream>>>(b16, twf, kfc, D);                            // kf
    transpose_w<<<H * E, 256, 0, stream>>>(crs_four_wr, crs_four_wi, wtb);
    fourier_qk<<<BH, 256, 0, stream>>>(xfc, kfc);                                  // kfc := qkv
    mode_gemm2<<<mg_grid, 256, 0, stream>>>(kfc, wtb);
    idft_mfma<<<BH, 256, 0, stream>>>(kfc, twi, c16, 1.f / ((float)L * (float)D * (float)D));
    gemm(c16, wbf_crsproj + (size_t)3 * D * D, crs_proj_b + 3 * D, nullptr, nullptr, d16, D, D, D, 0, 0); // ca
    decomp_kernel<<<B * (D / 64), 256, 0, stream>>>(h16, d16, dec_dcmp_w + NK, dec_dcmp_b + NK, a16, tacc, nullptr, 2); // h2, t2

    gemm(a16, wbf_dffn1, nullptr, nullptr, nullptr, c16, DFF, DFF, D, 1, 0);
    gemm(c16, wbf_dffn2, nullptr, nullptr, nullptr, d16, D, D, DFF, 0, 0);
    decomp_kernel<<<B * (D / 64), 256, 0, stream>>>(a16, d16, dec_dcmp_w + 2 * NK, dec_dcmp_b + 2 * NK, b16, tacc, t16, 2); // h3, t3 (+bf16 trend)

    // trend conv: stacked-tap GEMM (K=512, N=192, fp32 out) -> combine with trend_init (xmean)
    gemm(t16, wbf_trd, nullptr, nullptr, bufF, nullptr, 192, 192, D, 0, 0);
    trend_combine<<<cdiv(B * L * COUT, 256), 256, 0, stream>>>(bufF, xmean, dec_out);

    // final layernorm (fused) + seasonal projection accumulated into dec_out
    ln_colsub<<<B, 256, 0, stream>>>(b16, dec_norm_g, dec_norm_b, d16);
    gemm(d16, wbf_seas, out_proj_b, nullptr, dec_out, nullptr, 64, COUT, D, 0, 1);
}